// Round 1
// baseline (1258.062 us; speedup 1.0000x reference)
//
#include <hip/hip_runtime.h>
#include <hip/hip_bf16.h>
#include <math.h>

// Problem constants: B=8, C=256, H=W=64, J=17, Hd=4, dim=3
#define HH 64
#define WW 64
#define HW 4096
#define CC 256
#define BB 8
#define JJ 17

struct Bil { int i00,i01,i10,i11; float w00,w01,w10,w11; };

__device__ inline Bil bilin(float sx, float sy) {
    float x0f = floorf(sx), y0f = floorf(sy);
    float wx1 = sx - x0f, wy1 = sy - y0f;
    float wx0 = 1.f - wx1, wy0 = 1.f - wy1;
    int x0 = (int)x0f, y0 = (int)y0f;
    int x1 = x0 + 1, y1 = y0 + 1;
    bool vx0 = (unsigned)x0 < (unsigned)WW;
    bool vx1 = (unsigned)x1 < (unsigned)WW;
    bool vy0 = (unsigned)y0 < (unsigned)HH;
    bool vy1 = (unsigned)y1 < (unsigned)HH;
    int x0c = min(max(x0,0),WW-1), x1c = min(max(x1,0),WW-1);
    int y0c = min(max(y0,0),HH-1), y1c = min(max(y1,0),HH-1);
    Bil b;
    b.i00 = y0c*WW + x0c; b.i01 = y0c*WW + x1c;
    b.i10 = y1c*WW + x0c; b.i11 = y1c*WW + x1c;
    b.w00 = wx0*wy0*((vx0&&vy0)?1.f:0.f);
    b.w01 = wx1*wy0*((vx1&&vy0)?1.f:0.f);
    b.w10 = wx0*wy1*((vx0&&vy1)?1.f:0.f);
    b.w11 = wx1*wy1*((vx1&&vy1)?1.f:0.f);
    return b;
}

// K1: 3x3 conv feat(256) -> off27. block=256 px-tile, one oc per block.
__global__ __launch_bounds__(256) void conv3x3_kernel(
        const float* __restrict__ feat, const float* __restrict__ w,
        const float* __restrict__ bias, float* __restrict__ off27) {
    int blk = blockIdx.x;                 // ((b*27 + oc)*16 + tile)
    int tile = blk & 15;
    int oc = (blk >> 4) % 27;
    int b  = blk / (16*27);
    __shared__ float wl[2304];
    for (int i = threadIdx.x; i < 2304; i += 256) wl[i] = w[oc*2304 + i];
    __syncthreads();
    int p = tile*256 + threadIdx.x;
    int y = p >> 6, x = p & 63;
    const float* fb = feat + (size_t)b*CC*HW;
    float acc = bias[oc];
    for (int c = 0; c < CC; c++) {
        const float* f1 = fb + (size_t)c*HW;
        const float* wc = wl + c*9;
        #pragma unroll
        for (int ky = 0; ky < 3; ky++) {
            int yy = y + ky - 1;
            bool vy = (unsigned)yy < (unsigned)HH;
            #pragma unroll
            for (int kx = 0; kx < 3; kx++) {
                int xx = x + kx - 1;
                float fv = (vy && ((unsigned)xx < (unsigned)WW)) ? f1[yy*WW+xx] : 0.f;
                acc += fv * wc[ky*3+kx];
            }
        }
    }
    off27[((size_t)b*27 + oc)*HW + p] = acc;
}

// K1b: transpose dcn_w (oc,c,ky,kx) -> Wt (k,c,oc)
__global__ void wt_kernel(const float* __restrict__ w, float* __restrict__ Wt) {
    int idx = blockIdx.x*256 + threadIdx.x;  // 9*256*256
    if (idx >= 9*256*256) return;
    int oc = idx & 255;
    int c  = (idx >> 8) & 255;
    int k  = idx >> 16;
    Wt[idx] = w[((oc*256 + c)*3 + k/3)*3 + (k%3)];
}

// K2: fused DCNv2: bilinear sample -> LDS, fp32 register-tiled GEMM.
// block = 256 threads; tile = one image row (64 px) x 256 oc.
__global__ __launch_bounds__(256) void dcn_kernel(
        const float* __restrict__ feat, const float* __restrict__ off27,
        const float* __restrict__ Wt, float* __restrict__ dcn_out) {
    __shared__ float S[256*64];
    int blk = blockIdx.x;          // b*64 + row
    int b = blk >> 6, row = blk & 63;
    int t = threadIdx.x;
    int px = t & 63, cq = t >> 6;  // sampling mapping
    int ocq = t & 63, wq = t >> 6; // gemm mapping: oc=ocq*4, pxb=wq*16
    float acc[4][16];
    #pragma unroll
    for (int i=0;i<4;i++)
        #pragma unroll
        for (int j=0;j<16;j++) acc[i][j]=0.f;
    const float* fb = feat + (size_t)b*CC*HW;
    int p = row*WW + px;
    for (int k = 0; k < 9; k++) {
        float dyv = off27[((size_t)b*27 + k)*HW + p];
        float dxv = off27[((size_t)b*27 + 9 + k)*HW + p];
        float mk  = off27[((size_t)b*27 + 18 + k)*HW + p];
        float m = 1.f/(1.f + expf(-mk));
        float sx = (float)px  + (float)(k%3 - 1) + dxv;
        float sy = (float)row + (float)(k/3 - 1) + dyv;
        Bil bl = bilin(sx, sy);
        float w00=bl.w00*m, w01=bl.w01*m, w10=bl.w10*m, w11=bl.w11*m;
        const float* fc = fb + (size_t)cq*64*HW;
        #pragma unroll 4
        for (int c = 0; c < 64; c++) {
            const float* f1 = fc + (size_t)c*HW;
            float v = w00*f1[bl.i00] + w01*f1[bl.i01]
                    + w10*f1[bl.i10] + w11*f1[bl.i11];
            S[(cq*64 + c)*64 + px] = v;
        }
        __syncthreads();
        const float* wk = Wt + (size_t)k*256*256;
        for (int c = 0; c < 256; c++) {
            float4 wv = *(const float4*)(wk + (size_t)c*256 + ocq*4);
            const float* sp = S + c*64 + wq*16;
            #pragma unroll
            for (int j = 0; j < 16; j++) {
                float sv = sp[j];
                acc[0][j] += wv.x*sv; acc[1][j] += wv.y*sv;
                acc[2][j] += wv.z*sv; acc[3][j] += wv.w*sv;
            }
        }
        __syncthreads();
    }
    #pragma unroll
    for (int i = 0; i < 4; i++) {
        float* op = dcn_out + ((size_t)b*CC + ocq*4 + i)*HW + row*WW + wq*16;
        #pragma unroll
        for (int j = 0; j < 16; j++) op[j] = acc[i][j];
    }
}

// K3: GroupNorm stats (32 groups of 8 channels) -> mu, rstd
__global__ __launch_bounds__(256) void gn_stats_kernel(
        const float* __restrict__ dcn, float* __restrict__ stats) {
    int b = blockIdx.x >> 5, g = blockIdx.x & 31;
    const float* base = dcn + ((size_t)b*CC + g*8)*HW;
    float s=0.f, s2=0.f;
    for (int i = threadIdx.x; i < 8*HW; i += 256) {
        float v = base[i]; s += v; s2 += v*v;
    }
    __shared__ float rs[256], rs2[256];
    rs[threadIdx.x]=s; rs2[threadIdx.x]=s2; __syncthreads();
    for (int o=128;o>0;o>>=1){
        if (threadIdx.x<o){ rs[threadIdx.x]+=rs[threadIdx.x+o]; rs2[threadIdx.x]+=rs2[threadIdx.x+o]; }
        __syncthreads();
    }
    if (threadIdx.x==0) {
        float inv = 1.f/(8.f*HW);
        float mu = rs[0]*inv;
        float var = rs2[0]*inv - mu*mu;
        stats[blockIdx.x*2]   = mu;
        stats[blockIdx.x*2+1] = rsqrtf(var + 1e-5f);
    }
}

// K4: feat_new = feat + relu(gn(dcn)) -> d_out (output 0)
__global__ void gn_apply_kernel(
        const float* __restrict__ feat, const float* __restrict__ dcn,
        const float* __restrict__ stats, const float* __restrict__ gamma,
        const float* __restrict__ beta, float* __restrict__ out) {
    size_t idx = (size_t)blockIdx.x*256 + threadIdx.x;   // 8388608 total
    int c = (int)((idx >> 12) & 255);
    int b = (int)(idx >> 20);
    int g = c >> 3;
    float mu = stats[(b*32+g)*2], rstd = stats[(b*32+g)*2+1];
    float v = (dcn[idx]-mu)*rstd*gamma[c] + beta[c];
    out[idx] = feat[idx] + fmaxf(v, 0.f);
}

// K5: 1x1 conv featn(256) -> N channels. grid (128, ceil(N/32))
__global__ __launch_bounds__(256) void conv1x1_kernel(
        const float* __restrict__ featn, const float* __restrict__ w,
        const float* __restrict__ bias, float* __restrict__ out, int N) {
    __shared__ float lw[256][32];
    int n0 = blockIdx.y*32;
    for (int i = threadIdx.x; i < 256*32; i += 256) {
        int c = i >> 5, n = i & 31;
        lw[c][n] = (n0+n < N) ? w[(size_t)(n0+n)*256 + c] : 0.f;
    }
    __syncthreads();
    int b = blockIdx.x >> 4, tile = blockIdx.x & 15;
    int p = tile*256 + threadIdx.x;
    const float* fb = featn + (size_t)b*CC*HW + p;
    float acc[32];
    #pragma unroll
    for (int i=0;i<32;i++) acc[i]=0.f;
    for (int c = 0; c < 256; c++) {
        float v = fb[(size_t)c*HW];
        #pragma unroll
        for (int i=0;i<32;i++) acc[i] += lw[c][i]*v;
    }
    for (int i = 0; i < 32; i++) {
        int n = n0 + i;
        if (n < N) out[((size_t)b*N + n)*HW + p] = acc[i] + bias[n];
    }
}

// K6: offset = (1-sig(uw))*prev + sig(uw)*uo
__global__ void offset_kernel(
        const float* __restrict__ prev, const float* __restrict__ lin_uw,
        const float* __restrict__ lin_uo, float* __restrict__ uvd) {
    size_t idx = (size_t)blockIdx.x*256 + threadIdx.x;  // 1671168
    float owv = 1.f/(1.f+expf(-lin_uw[idx]));
    uvd[idx] = (1.f-owv)*prev[idx] + owv*lin_uo[idx];
}

// K7: fused sampling + softmax-weighted sum -> new_off (output 1)
__global__ __launch_bounds__(256) void final_kernel(
        const float* __restrict__ uvd, const float* __restrict__ sconf,
        const float* __restrict__ soff, float* __restrict__ out_off) {
    int bj = blockIdx.x;            // 0..135
    int b = bj / JJ, j = bj % JJ;
    int p = blockIdx.y*256 + threadIdx.x;
    int y = p >> 6, x = p & 63;
    const float* u0 = uvd   + ((size_t)b*51  + j*3)*HW;
    const float* c0 = sconf + ((size_t)b*51  + j*3)*HW;
    const float* s0 = soff  + ((size_t)b*136 + j*8)*HW;
    float offx = u0[p], offy = u0[HW+p];
    Bil bl = bilin((float)x + offx, (float)y + offy);
    float sall[8][2];
    #pragma unroll
    for (int h = 0; h < 4; h++) {
        const float* se = s0 + (size_t)(2*h)*HW;
        const float* so2 = s0 + (size_t)(2*h+1)*HW;
        sall[h][0] = bl.w00*se[bl.i00]+bl.w01*se[bl.i01]+bl.w10*se[bl.i10]+bl.w11*se[bl.i11] + offx;
        sall[h][1] = bl.w00*so2[bl.i00]+bl.w01*so2[bl.i01]+bl.w10*so2[bl.i10]+bl.w11*so2[bl.i11] + offy;
        sall[4+h][0] = se[p];
        sall[4+h][1] = so2[p];
    }
    float sv[8][3], lg[8][3];
    #pragma unroll
    for (int n = 0; n < 8; n++) {
        Bil b2 = bilin((float)x + sall[n][0], (float)y + sall[n][1]);
        #pragma unroll
        for (int d = 0; d < 3; d++) {
            const float* ud = u0 + (size_t)d*HW;
            const float* cd = c0 + (size_t)d*HW;
            sv[n][d] = b2.w00*ud[b2.i00]+b2.w01*ud[b2.i01]+b2.w10*ud[b2.i10]+b2.w11*ud[b2.i11];
            lg[n][d] = b2.w00*cd[b2.i00]+b2.w01*cd[b2.i01]+b2.w10*cd[b2.i10]+b2.w11*cd[b2.i11];
        }
        sv[n][0] += sall[n][0];
        sv[n][1] += sall[n][1];
    }
    #pragma unroll
    for (int d = 0; d < 3; d++) {
        float m = lg[0][d];
        #pragma unroll
        for (int n = 1; n < 8; n++) m = fmaxf(m, lg[n][d]);
        float den = 0.f, num = 0.f;
        #pragma unroll
        for (int n = 0; n < 8; n++) {
            float e = expf(lg[n][d]-m);
            den += e; num += e*sv[n][d];
        }
        out_off[((size_t)b*51 + j*3 + d)*HW + p] = num/den;
    }
}

extern "C" void kernel_launch(void* const* d_in, const int* in_sizes, int n_in,
                              void* d_out, int out_size, void* d_ws, size_t ws_size,
                              hipStream_t stream) {
    const float* feat       = (const float*)d_in[0];
    const float* prev_off   = (const float*)d_in[1];
    const float* dcn_off_w  = (const float*)d_in[2];
    const float* dcn_off_b  = (const float*)d_in[3];
    const float* dcn_w      = (const float*)d_in[4];
    const float* gn_g       = (const float*)d_in[5];
    const float* gn_b       = (const float*)d_in[6];
    const float* so_w       = (const float*)d_in[7];
    const float* so_b       = (const float*)d_in[8];
    const float* sc_w       = (const float*)d_in[9];
    const float* sc_b       = (const float*)d_in[10];
    const float* uw_w       = (const float*)d_in[11];
    const float* uw_b       = (const float*)d_in[12];
    const float* uo_w       = (const float*)d_in[13];
    const float* uo_b       = (const float*)d_in[14];

    float* ws = (float*)d_ws;
    float* off27     = ws;                       // 884736
    float* Wt        = off27 + 884736;           // 589824
    float* dcn       = Wt + 589824;              // 8388608
    float* stats     = dcn + 8388608;            // 512
    float* samp_off  = stats + 512;              // 4456448
    float* samp_conf = samp_off + 4456448;       // 1671168
    float* lin_uw    = samp_conf + 1671168;      // 1671168
    float* lin_uo    = lin_uw + 1671168;         // 1671168
    float* uvd       = lin_uo + 1671168;         // 1671168

    float* out_feat = (float*)d_out;             // 8388608
    float* out_off  = out_feat + 8388608;        // 1671168

    // K1: offset conv (3x3)
    conv3x3_kernel<<<dim3(BB*27*16), dim3(256), 0, stream>>>(feat, dcn_off_w, dcn_off_b, off27);
    // K1b: transpose dcn_w
    wt_kernel<<<dim3((9*256*256)/256), dim3(256), 0, stream>>>(dcn_w, Wt);
    // K2: DCN
    dcn_kernel<<<dim3(BB*64), dim3(256), 0, stream>>>(feat, off27, Wt, dcn);
    // K3/K4: GroupNorm + residual
    gn_stats_kernel<<<dim3(BB*32), dim3(256), 0, stream>>>(dcn, stats);
    gn_apply_kernel<<<dim3(8388608/256), dim3(256), 0, stream>>>(feat, dcn, stats, gn_g, gn_b, out_feat);
    // K5: 1x1 convs on updated feat
    conv1x1_kernel<<<dim3(128, 5), dim3(256), 0, stream>>>(out_feat, so_w, so_b, samp_off, 136);
    conv1x1_kernel<<<dim3(128, 2), dim3(256), 0, stream>>>(out_feat, sc_w, sc_b, samp_conf, 51);
    conv1x1_kernel<<<dim3(128, 2), dim3(256), 0, stream>>>(out_feat, uw_w, uw_b, lin_uw, 51);
    conv1x1_kernel<<<dim3(128, 2), dim3(256), 0, stream>>>(out_feat, uo_w, uo_b, lin_uo, 51);
    // K6: offset blend
    offset_kernel<<<dim3(1671168/256), dim3(256), 0, stream>>>(prev_off, lin_uw, lin_uo, uvd);
    // K7: fused double grid-sample + softmax reduction
    final_kernel<<<dim3(BB*JJ, 16), dim3(256), 0, stream>>>(uvd, samp_conf, samp_off, out_off);
}

// Round 2
// 876.716 us; speedup vs baseline: 1.4350x; 1.4350x over previous
//
#include <hip/hip_runtime.h>
#include <hip/hip_bf16.h>
#include <math.h>

// Problem constants: B=8, C=256, H=W=64, J=17, Hd=4, dim=3
#define HH 64
#define WW 64
#define HW 4096
#define CC 256
#define BB 8
#define JJ 17

typedef __attribute__((ext_vector_type(8))) short bf16x8;
typedef __attribute__((ext_vector_type(4))) float f32x4;

#define SLD 264   // padded LDS row stride in shorts (32px x 264)

struct Bil { int i00,i01,i10,i11; float w00,w01,w10,w11; };

__device__ inline Bil bilin(float sx, float sy) {
    float x0f = floorf(sx), y0f = floorf(sy);
    float wx1 = sx - x0f, wy1 = sy - y0f;
    float wx0 = 1.f - wx1, wy0 = 1.f - wy1;
    int x0 = (int)x0f, y0 = (int)y0f;
    int x1 = x0 + 1, y1 = y0 + 1;
    bool vx0 = (unsigned)x0 < (unsigned)WW;
    bool vx1 = (unsigned)x1 < (unsigned)WW;
    bool vy0 = (unsigned)y0 < (unsigned)HH;
    bool vy1 = (unsigned)y1 < (unsigned)HH;
    int x0c = min(max(x0,0),WW-1), x1c = min(max(x1,0),WW-1);
    int y0c = min(max(y0,0),HH-1), y1c = min(max(y1,0),HH-1);
    Bil b;
    b.i00 = y0c*WW + x0c; b.i01 = y0c*WW + x1c;
    b.i10 = y1c*WW + x0c; b.i11 = y1c*WW + x1c;
    b.w00 = wx0*wy0*((vx0&&vy0)?1.f:0.f);
    b.w01 = wx1*wy0*((vx1&&vy0)?1.f:0.f);
    b.w10 = wx0*wy1*((vx0&&vy1)?1.f:0.f);
    b.w11 = wx1*wy1*((vx1&&vy1)?1.f:0.f);
    return b;
}

__device__ inline unsigned short f2bf(float f) {
    unsigned u = __float_as_uint(f);
    unsigned r = (u + 0x7fffu + ((u >> 16) & 1u)) >> 16;
    return (unsigned short)r;
}

// K1: 3x3 conv feat(256) -> off27. block=256 px-tile, one oc per block.
__global__ __launch_bounds__(256) void conv3x3_kernel(
        const float* __restrict__ feat, const float* __restrict__ w,
        const float* __restrict__ bias, float* __restrict__ off27) {
    int blk = blockIdx.x;                 // ((b*27 + oc)*16 + tile)
    int tile = blk & 15;
    int oc = (blk >> 4) % 27;
    int b  = blk / (16*27);
    __shared__ float wl[2304];
    for (int i = threadIdx.x; i < 2304; i += 256) wl[i] = w[oc*2304 + i];
    __syncthreads();
    int p = tile*256 + threadIdx.x;
    int y = p >> 6, x = p & 63;
    const float* fb = feat + (size_t)b*CC*HW;
    float acc = bias[oc];
    for (int c = 0; c < CC; c++) {
        const float* f1 = fb + (size_t)c*HW;
        const float* wc = wl + c*9;
        #pragma unroll
        for (int ky = 0; ky < 3; ky++) {
            int yy = y + ky - 1;
            bool vy = (unsigned)yy < (unsigned)HH;
            #pragma unroll
            for (int kx = 0; kx < 3; kx++) {
                int xx = x + kx - 1;
                float fv = (vy && ((unsigned)xx < (unsigned)WW)) ? f1[yy*WW+xx] : 0.f;
                acc += fv * wc[ky*3+kx];
            }
        }
    }
    off27[((size_t)b*27 + oc)*HW + p] = acc;
}

// K1b: pack dcn_w into MFMA B-fragment order, bf16.
// Wp[(((k*8 + cs)*16 + ocTile)*64 + lane)*8 + i] =
//     bf16( w[oc = ocTile*16 + (lane&15)][c = cs*32 + (lane>>4)*8 + i][k/3][k%3] )
__global__ void wpack_kernel(const float* __restrict__ w, short* __restrict__ Wp) {
    int idx = blockIdx.x*256 + threadIdx.x;   // 9*8*16*64 = 73728
    if (idx >= 9*8*16*64) return;
    int l  = idx & 63;
    int ot = (idx >> 6) & 15;
    int cs = (idx >> 10) & 7;
    int k  = idx >> 13;
    int oc = ot*16 + (l & 15);
    int c0 = cs*32 + (l >> 4)*8;
    short* dst = Wp + (size_t)idx*8;
    #pragma unroll
    for (int i = 0; i < 8; i++) {
        float v = w[((size_t)(oc*256 + c0 + i)*3 + k/3)*3 + (k % 3)];
        dst[i] = (short)f2bf(v);
    }
}

// K2: fused DCNv2: bilinear sample -> LDS (bf16), MFMA GEMM over (k,c).
// block = 256 threads (4 waves); tile = 32 px x 256 oc. grid = 8*64*2 = 1024.
__global__ __launch_bounds__(256, 4) void dcn_kernel(
        const float* __restrict__ feat, const float* __restrict__ off27,
        const short* __restrict__ Wp, float* __restrict__ dcn_out) {
    __shared__ __align__(16) char LDSBUF[17536];
    short* S  = (short*)LDSBUF;       // [32 px][SLD=264] bf16 sample tile
    float* Sf = (float*)LDSBUF;       // epilogue overlay: per-wave [64 oc][17]

    int blk = blockIdx.x;             // b*128 + row*2 + half
    int b   = blk >> 7;
    int rh  = blk & 127;
    int row = rh >> 1;
    int px0 = (rh & 1) * 32;

    int t   = threadIdx.x;
    int pxl = t & 31, cq = t >> 5;    // sampling: 32 px x 8 c-chunks(32)
    int l   = t & 63, wv = t >> 6;    // gemm: wave wv handles oc [wv*64, wv*64+64)

    f32x4 acc[2][4];
    #pragma unroll
    for (int i = 0; i < 2; i++)
        #pragma unroll
        for (int j = 0; j < 4; j++) acc[i][j] = (f32x4){0.f,0.f,0.f,0.f};

    const float* fb = feat + (size_t)b*CC*HW;
    int px = px0 + pxl;
    int p  = row*WW + px;

    for (int k = 0; k < 9; k++) {
        // ---- sampling phase: fill S[pxl][cq*32 .. cq*32+31] ----
        float dyv = off27[((size_t)b*27 + k)*HW + p];
        float dxv = off27[((size_t)b*27 + 9 + k)*HW + p];
        float mk  = off27[((size_t)b*27 + 18 + k)*HW + p];
        float m = 1.f/(1.f + expf(-mk));
        Bil bl = bilin((float)px + (float)(k%3 - 1) + dxv,
                       (float)row + (float)(k/3 - 1) + dyv);
        float w00 = bl.w00*m, w01 = bl.w01*m, w10 = bl.w10*m, w11 = bl.w11*m;
        const float* fc = fb + (size_t)cq*32*HW;
        short* srow = S + pxl*SLD + cq*32;
        #pragma unroll 2
        for (int c4 = 0; c4 < 32; c4 += 4) {
            float v[4];
            #pragma unroll
            for (int j = 0; j < 4; j++) {
                const float* f1 = fc + (size_t)(c4 + j)*HW;
                v[j] = w00*f1[bl.i00] + w01*f1[bl.i01]
                     + w10*f1[bl.i10] + w11*f1[bl.i11];
            }
            uint2 pk;
            pk.x = (unsigned)f2bf(v[0]) | ((unsigned)f2bf(v[1]) << 16);
            pk.y = (unsigned)f2bf(v[2]) | ((unsigned)f2bf(v[3]) << 16);
            *(uint2*)(srow + c4) = pk;
        }
        __syncthreads();

        // ---- GEMM phase: acc[pt][ot] += S_tile * W_tile ----
        const short* wpk = Wp + (size_t)k*8*16*64*8;
        for (int cs = 0; cs < 8; cs++) {
            bf16x8 af[2];
            #pragma unroll
            for (int pt = 0; pt < 2; pt++)
                af[pt] = *(const bf16x8*)(S + (pt*16 + (l & 15))*SLD
                                            + cs*32 + (l >> 4)*8);
            bf16x8 bg[4];
            #pragma unroll
            for (int ot = 0; ot < 4; ot++)
                bg[ot] = *(const bf16x8*)(wpk + ((size_t)((cs*16 + (wv*4 + ot))*64 + l))*8);
            #pragma unroll
            for (int pt = 0; pt < 2; pt++)
                #pragma unroll
                for (int ot = 0; ot < 4; ot++)
                    acc[pt][ot] = __builtin_amdgcn_mfma_f32_16x16x32_bf16(
                        af[pt], bg[ot], acc[pt][ot], 0, 0, 0);
        }
        __syncthreads();
    }

    // ---- epilogue: transpose through LDS for coalesced stores ----
    float* myS = Sf + wv*(64*17);
    #pragma unroll
    for (int pt = 0; pt < 2; pt++) {
        #pragma unroll
        for (int ot = 0; ot < 4; ot++)
            #pragma unroll
            for (int r = 0; r < 4; r++)
                myS[(ot*16 + (l & 15))*17 + (l >> 4)*4 + r] = acc[pt][ot][r];
        __syncthreads();
        #pragma unroll
        for (int i = 0; i < 16; i++) {
            int ocl = i*4 + (l >> 4);
            dcn_out[((size_t)(b*256 + wv*64 + ocl))*HW + row*WW + px0 + pt*16 + (l & 15)]
                = myS[ocl*17 + (l & 15)];
        }
        __syncthreads();
    }
}

// K3: GroupNorm stats (32 groups of 8 channels) -> mu, rstd
__global__ __launch_bounds__(256) void gn_stats_kernel(
        const float* __restrict__ dcn, float* __restrict__ stats) {
    int b = blockIdx.x >> 5, g = blockIdx.x & 31;
    const float* base = dcn + ((size_t)b*CC + g*8)*HW;
    float s=0.f, s2=0.f;
    for (int i = threadIdx.x; i < 8*HW; i += 256) {
        float v = base[i]; s += v; s2 += v*v;
    }
    __shared__ float rs[256], rs2[256];
    rs[threadIdx.x]=s; rs2[threadIdx.x]=s2; __syncthreads();
    for (int o=128;o>0;o>>=1){
        if (threadIdx.x<o){ rs[threadIdx.x]+=rs[threadIdx.x+o]; rs2[threadIdx.x]+=rs2[threadIdx.x+o]; }
        __syncthreads();
    }
    if (threadIdx.x==0) {
        float inv = 1.f/(8.f*HW);
        float mu = rs[0]*inv;
        float var = rs2[0]*inv - mu*mu;
        stats[blockIdx.x*2]   = mu;
        stats[blockIdx.x*2+1] = rsqrtf(var + 1e-5f);
    }
}

// K4: feat_new = feat + relu(gn(dcn)) -> d_out (output 0)
__global__ void gn_apply_kernel(
        const float* __restrict__ feat, const float* __restrict__ dcn,
        const float* __restrict__ stats, const float* __restrict__ gamma,
        const float* __restrict__ beta, float* __restrict__ out) {
    size_t idx = (size_t)blockIdx.x*256 + threadIdx.x;   // 8388608 total
    int c = (int)((idx >> 12) & 255);
    int b = (int)(idx >> 20);
    int g = c >> 3;
    float mu = stats[(b*32+g)*2], rstd = stats[(b*32+g)*2+1];
    float v = (dcn[idx]-mu)*rstd*gamma[c] + beta[c];
    out[idx] = feat[idx] + fmaxf(v, 0.f);
}

// K5: 1x1 conv featn(256) -> N channels. grid (128, ceil(N/32))
__global__ __launch_bounds__(256) void conv1x1_kernel(
        const float* __restrict__ featn, const float* __restrict__ w,
        const float* __restrict__ bias, float* __restrict__ out, int N) {
    __shared__ float lw[256][32];
    int n0 = blockIdx.y*32;
    for (int i = threadIdx.x; i < 256*32; i += 256) {
        int c = i >> 5, n = i & 31;
        lw[c][n] = (n0+n < N) ? w[(size_t)(n0+n)*256 + c] : 0.f;
    }
    __syncthreads();
    int b = blockIdx.x >> 4, tile = blockIdx.x & 15;
    int p = tile*256 + threadIdx.x;
    const float* fb = featn + (size_t)b*CC*HW + p;
    float acc[32];
    #pragma unroll
    for (int i=0;i<32;i++) acc[i]=0.f;
    for (int c = 0; c < 256; c++) {
        float v = fb[(size_t)c*HW];
        #pragma unroll
        for (int i=0;i<32;i++) acc[i] += lw[c][i]*v;
    }
    for (int i = 0; i < 32; i++) {
        int n = n0 + i;
        if (n < N) out[((size_t)b*N + n)*HW + p] = acc[i] + bias[n];
    }
}

// K6: offset = (1-sig(uw))*prev + sig(uw)*uo
__global__ void offset_kernel(
        const float* __restrict__ prev, const float* __restrict__ lin_uw,
        const float* __restrict__ lin_uo, float* __restrict__ uvd) {
    size_t idx = (size_t)blockIdx.x*256 + threadIdx.x;  // 1671168
    float owv = 1.f/(1.f+expf(-lin_uw[idx]));
    uvd[idx] = (1.f-owv)*prev[idx] + owv*lin_uo[idx];
}

// K7: fused sampling + softmax-weighted sum -> new_off (output 1)
__global__ __launch_bounds__(256) void final_kernel(
        const float* __restrict__ uvd, const float* __restrict__ sconf,
        const float* __restrict__ soff, float* __restrict__ out_off) {
    int bj = blockIdx.x;            // 0..135
    int b = bj / JJ, j = bj % JJ;
    int p = blockIdx.y*256 + threadIdx.x;
    int y = p >> 6, x = p & 63;
    const float* u0 = uvd   + ((size_t)b*51  + j*3)*HW;
    const float* c0 = sconf + ((size_t)b*51  + j*3)*HW;
    const float* s0 = soff  + ((size_t)b*136 + j*8)*HW;
    float offx = u0[p], offy = u0[HW+p];
    Bil bl = bilin((float)x + offx, (float)y + offy);
    float sall[8][2];
    #pragma unroll
    for (int h = 0; h < 4; h++) {
        const float* se = s0 + (size_t)(2*h)*HW;
        const float* so2 = s0 + (size_t)(2*h+1)*HW;
        sall[h][0] = bl.w00*se[bl.i00]+bl.w01*se[bl.i01]+bl.w10*se[bl.i10]+bl.w11*se[bl.i11] + offx;
        sall[h][1] = bl.w00*so2[bl.i00]+bl.w01*so2[bl.i01]+bl.w10*so2[bl.i10]+bl.w11*so2[bl.i11] + offy;
        sall[4+h][0] = se[p];
        sall[4+h][1] = so2[p];
    }
    float sv[8][3], lg[8][3];
    #pragma unroll
    for (int n = 0; n < 8; n++) {
        Bil b2 = bilin((float)x + sall[n][0], (float)y + sall[n][1]);
        #pragma unroll
        for (int d = 0; d < 3; d++) {
            const float* ud = u0 + (size_t)d*HW;
            const float* cd = c0 + (size_t)d*HW;
            sv[n][d] = b2.w00*ud[b2.i00]+b2.w01*ud[b2.i01]+b2.w10*ud[b2.i10]+b2.w11*ud[b2.i11];
            lg[n][d] = b2.w00*cd[b2.i00]+b2.w01*cd[b2.i01]+b2.w10*cd[b2.i10]+b2.w11*cd[b2.i11];
        }
        sv[n][0] += sall[n][0];
        sv[n][1] += sall[n][1];
    }
    #pragma unroll
    for (int d = 0; d < 3; d++) {
        float m = lg[0][d];
        #pragma unroll
        for (int n = 1; n < 8; n++) m = fmaxf(m, lg[n][d]);
        float den = 0.f, num = 0.f;
        #pragma unroll
        for (int n = 0; n < 8; n++) {
            float e = expf(lg[n][d]-m);
            den += e; num += e*sv[n][d];
        }
        out_off[((size_t)b*51 + j*3 + d)*HW + p] = num/den;
    }
}

extern "C" void kernel_launch(void* const* d_in, const int* in_sizes, int n_in,
                              void* d_out, int out_size, void* d_ws, size_t ws_size,
                              hipStream_t stream) {
    const float* feat       = (const float*)d_in[0];
    const float* prev_off   = (const float*)d_in[1];
    const float* dcn_off_w  = (const float*)d_in[2];
    const float* dcn_off_b  = (const float*)d_in[3];
    const float* dcn_w      = (const float*)d_in[4];
    const float* gn_g       = (const float*)d_in[5];
    const float* gn_b       = (const float*)d_in[6];
    const float* so_w       = (const float*)d_in[7];
    const float* so_b       = (const float*)d_in[8];
    const float* sc_w       = (const float*)d_in[9];
    const float* sc_b       = (const float*)d_in[10];
    const float* uw_w       = (const float*)d_in[11];
    const float* uw_b       = (const float*)d_in[12];
    const float* uo_w       = (const float*)d_in[13];
    const float* uo_b       = (const float*)d_in[14];

    float* ws = (float*)d_ws;
    float* off27     = ws;                       // 884736 floats
    float* Wt        = off27 + 884736;           // 589824 floats (Wp uses half as bf16)
    short* Wp        = (short*)Wt;               // 589824 shorts
    float* dcn       = Wt + 589824;              // 8388608
    float* stats     = dcn + 8388608;            // 512
    float* samp_off  = stats + 512;              // 4456448
    float* samp_conf = samp_off + 4456448;       // 1671168
    float* lin_uw    = samp_conf + 1671168;      // 1671168
    float* lin_uo    = lin_uw + 1671168;         // 1671168
    float* uvd       = lin_uo + 1671168;         // 1671168

    float* out_feat = (float*)d_out;             // 8388608
    float* out_off  = out_feat + 8388608;        // 1671168

    // K1: offset conv (3x3)
    conv3x3_kernel<<<dim3(BB*27*16), dim3(256), 0, stream>>>(feat, dcn_off_w, dcn_off_b, off27);
    // K1b: pack dcn_w into MFMA fragment order (bf16)
    wpack_kernel<<<dim3(288), dim3(256), 0, stream>>>(dcn_w, Wp);
    // K2: DCN (MFMA)
    dcn_kernel<<<dim3(BB*64*2), dim3(256), 0, stream>>>(feat, off27, Wp, dcn);
    // K3/K4: GroupNorm + residual
    gn_stats_kernel<<<dim3(BB*32), dim3(256), 0, stream>>>(dcn, stats);
    gn_apply_kernel<<<dim3(8388608/256), dim3(256), 0, stream>>>(feat, dcn, stats, gn_g, gn_b, out_feat);
    // K5: 1x1 convs on updated feat
    conv1x1_kernel<<<dim3(128, 5), dim3(256), 0, stream>>>(out_feat, so_w, so_b, samp_off, 136);
    conv1x1_kernel<<<dim3(128, 2), dim3(256), 0, stream>>>(out_feat, sc_w, sc_b, samp_conf, 51);
    conv1x1_kernel<<<dim3(128, 2), dim3(256), 0, stream>>>(out_feat, uw_w, uw_b, lin_uw, 51);
    conv1x1_kernel<<<dim3(128, 2), dim3(256), 0, stream>>>(out_feat, uo_w, uo_b, lin_uo, 51);
    // K6: offset blend
    offset_kernel<<<dim3(1671168/256), dim3(256), 0, stream>>>(prev_off, lin_uw, lin_uo, uvd);
    // K7: fused double grid-sample + softmax reduction
    final_kernel<<<dim3(BB*JJ, 16), dim3(256), 0, stream>>>(uvd, samp_conf, samp_off, out_off);
}

// Round 3
// 679.228 us; speedup vs baseline: 1.8522x; 1.2908x over previous
//
#include <hip/hip_runtime.h>
#include <hip/hip_bf16.h>
#include <math.h>

// Problem constants: B=8, C=256, H=W=64, J=17, Hd=4, dim=3
#define HH 64
#define WW 64
#define HW 4096
#define CC 256
#define BB 8
#define JJ 17

typedef __attribute__((ext_vector_type(8))) short bf16x8;
typedef __attribute__((ext_vector_type(4))) float f32x4;

#define SLD 264    // dcn: padded LDS row stride in shorts (32px x 264)
#define CST 136    // conv3x3: strip c-stride in shorts (128 c + 8 pad)

struct Bil { int i00,i01,i10,i11; float w00,w01,w10,w11; };

__device__ inline Bil bilin(float sx, float sy) {
    float x0f = floorf(sx), y0f = floorf(sy);
    float wx1 = sx - x0f, wy1 = sy - y0f;
    float wx0 = 1.f - wx1, wy0 = 1.f - wy1;
    int x0 = (int)x0f, y0 = (int)y0f;
    int x1 = x0 + 1, y1 = y0 + 1;
    bool vx0 = (unsigned)x0 < (unsigned)WW;
    bool vx1 = (unsigned)x1 < (unsigned)WW;
    bool vy0 = (unsigned)y0 < (unsigned)HH;
    bool vy1 = (unsigned)y1 < (unsigned)HH;
    int x0c = min(max(x0,0),WW-1), x1c = min(max(x1,0),WW-1);
    int y0c = min(max(y0,0),HH-1), y1c = min(max(y1,0),HH-1);
    Bil b;
    b.i00 = y0c*WW + x0c; b.i01 = y0c*WW + x1c;
    b.i10 = y1c*WW + x0c; b.i11 = y1c*WW + x1c;
    b.w00 = wx0*wy0*((vx0&&vy0)?1.f:0.f);
    b.w01 = wx1*wy0*((vx1&&vy0)?1.f:0.f);
    b.w10 = wx0*wy1*((vx0&&vy1)?1.f:0.f);
    b.w11 = wx1*wy1*((vx1&&vy1)?1.f:0.f);
    return b;
}

__device__ inline unsigned short f2bf(float f) {
    unsigned u = __float_as_uint(f);
    unsigned r = (u + 0x7fffu + ((u >> 16) & 1u)) >> 16;
    return (unsigned short)r;
}

// K1a: pack dcn_off_w (27,256,3,3) into MFMA A-fragment order, bf16.
// Ap[(((k*2 + mt)*8 + cs)*64 + l)*8 + i] =
//   bf16( w[oc = mt*16 + (l&15)][c = cs*32 + (l>>4)*8 + i][k/3][k%3] ), 0 if oc>=27
__global__ void cpack_kernel(const float* __restrict__ w, short* __restrict__ Ap) {
    int idx = blockIdx.x*256 + threadIdx.x;   // 9*2*8*64 = 9216
    if (idx >= 9*2*8*64) return;
    int l  = idx & 63;
    int cs = (idx >> 6) & 7;
    int mt = (idx >> 9) & 1;
    int k  = idx >> 10;
    int oc = mt*16 + (l & 15);
    int c0 = cs*32 + (l >> 4)*8;
    short* dst = Ap + (size_t)idx*8;
    #pragma unroll
    for (int i = 0; i < 8; i++) {
        float v = (oc < 27) ? w[((size_t)(oc*256 + c0 + i)*3 + k/3)*3 + (k % 3)] : 0.f;
        dst[i] = (short)f2bf(v);
    }
}

// K1: 3x3 conv feat(256) -> off27 via MFMA on a 3-row bf16 strip.
// block = 256 thr (4 waves = 4 px-tiles of 16); grid = 8*64 (one image row each).
__global__ __launch_bounds__(256, 2) void conv3x3_kernel(
        const float* __restrict__ feat, const short* __restrict__ Ap,
        const float* __restrict__ bias, float* __restrict__ off27) {
    __shared__ __align__(16) short S[3*66*CST];   // 52.6 KB: [row r][px_s 0..65][c 0..127]
    int blk = blockIdx.x;          // b*64 + row
    int b = blk >> 6, row = blk & 63;
    int t = threadIdx.x;
    int l = t & 63, wv = t >> 6;

    f32x4 acc[2];
    acc[0] = (f32x4){0.f,0.f,0.f,0.f};
    acc[1] = (f32x4){0.f,0.f,0.f,0.f};
    const float* fb = feat + (size_t)b*CC*HW;

    for (int ch = 0; ch < 2; ch++) {
        // stage strip: rows row-1..row+1, channels ch*128..+128, x halo -1..64
        for (int i = t; i < 3*128*66; i += 256) {
            int px_s = i % 66;
            int rc   = i / 66;
            int r = rc >> 7, c = rc & 127;
            int yy = row + r - 1;
            int xx = px_s - 1;
            float v = 0.f;
            if ((unsigned)yy < 64u && (unsigned)xx < 64u)
                v = fb[(size_t)(ch*128 + c)*HW + yy*64 + xx];
            S[(r*66 + px_s)*CST + c] = (short)f2bf(v);
        }
        __syncthreads();
        #pragma unroll
        for (int k = 0; k < 9; k++) {
            int ky = k/3, kx = k%3;
            const short* srow = S + (ky*66 + wv*16 + (l & 15) + kx)*CST + (l >> 4)*8;
            #pragma unroll
            for (int csl = 0; csl < 4; csl++) {
                bf16x8 bfrag = *(const bf16x8*)(srow + csl*32);
                int cs = ch*4 + csl;
                const short* ap = Ap + ((size_t)((k*2)*8 + cs)*64 + l)*8;
                bf16x8 a0 = *(const bf16x8*)ap;
                bf16x8 a1 = *(const bf16x8*)(ap + 8*64*8);
                acc[0] = __builtin_amdgcn_mfma_f32_16x16x32_bf16(a0, bfrag, acc[0], 0, 0, 0);
                acc[1] = __builtin_amdgcn_mfma_f32_16x16x32_bf16(a1, bfrag, acc[1], 0, 0, 0);
            }
        }
        __syncthreads();
    }
    // store: D col (l&15) = px-in-tile, row = oc
    #pragma unroll
    for (int mt = 0; mt < 2; mt++)
        #pragma unroll
        for (int r = 0; r < 4; r++) {
            int oc = mt*16 + (l >> 4)*4 + r;
            if (oc < 27)
                off27[((size_t)(b*27 + oc))*HW + row*64 + wv*16 + (l & 15)]
                    = acc[mt][r] + bias[oc];
        }
}

// K1b: pack dcn_w into MFMA B-fragment order, bf16.
__global__ void wpack_kernel(const float* __restrict__ w, short* __restrict__ Wp) {
    int idx = blockIdx.x*256 + threadIdx.x;   // 9*8*16*64 = 73728
    if (idx >= 9*8*16*64) return;
    int l  = idx & 63;
    int ot = (idx >> 6) & 15;
    int cs = (idx >> 10) & 7;
    int k  = idx >> 13;
    int oc = ot*16 + (l & 15);
    int c0 = cs*32 + (l >> 4)*8;
    short* dst = Wp + (size_t)idx*8;
    #pragma unroll
    for (int i = 0; i < 8; i++) {
        float v = w[((size_t)(oc*256 + c0 + i)*3 + k/3)*3 + (k % 3)];
        dst[i] = (short)f2bf(v);
    }
}

// K2: fused DCNv2: bilinear sample -> LDS (bf16), MFMA GEMM over (k,c).
__global__ __launch_bounds__(256, 4) void dcn_kernel(
        const float* __restrict__ feat, const float* __restrict__ off27,
        const short* __restrict__ Wp, float* __restrict__ dcn_out) {
    __shared__ __align__(16) char LDSBUF[17536];
    short* S  = (short*)LDSBUF;       // [32 px][SLD=264] bf16 sample tile
    float* Sf = (float*)LDSBUF;       // epilogue overlay: per-wave [64 oc][17]

    int blk = blockIdx.x;             // b*128 + row*2 + half
    int b   = blk >> 7;
    int rh  = blk & 127;
    int row = rh >> 1;
    int px0 = (rh & 1) * 32;

    int t   = threadIdx.x;
    int pxl = t & 31, cq = t >> 5;
    int l   = t & 63, wv = t >> 6;

    f32x4 acc[2][4];
    #pragma unroll
    for (int i = 0; i < 2; i++)
        #pragma unroll
        for (int j = 0; j < 4; j++) acc[i][j] = (f32x4){0.f,0.f,0.f,0.f};

    const float* fb = feat + (size_t)b*CC*HW;
    int px = px0 + pxl;
    int p  = row*WW + px;

    for (int k = 0; k < 9; k++) {
        float dyv = off27[((size_t)b*27 + k)*HW + p];
        float dxv = off27[((size_t)b*27 + 9 + k)*HW + p];
        float mk  = off27[((size_t)b*27 + 18 + k)*HW + p];
        float m = 1.f/(1.f + expf(-mk));
        Bil bl = bilin((float)px + (float)(k%3 - 1) + dxv,
                       (float)row + (float)(k/3 - 1) + dyv);
        float w00 = bl.w00*m, w01 = bl.w01*m, w10 = bl.w10*m, w11 = bl.w11*m;
        const float* fc = fb + (size_t)cq*32*HW;
        short* srow = S + pxl*SLD + cq*32;
        #pragma unroll 2
        for (int c4 = 0; c4 < 32; c4 += 4) {
            float v[4];
            #pragma unroll
            for (int j = 0; j < 4; j++) {
                const float* f1 = fc + (size_t)(c4 + j)*HW;
                v[j] = w00*f1[bl.i00] + w01*f1[bl.i01]
                     + w10*f1[bl.i10] + w11*f1[bl.i11];
            }
            uint2 pk;
            pk.x = (unsigned)f2bf(v[0]) | ((unsigned)f2bf(v[1]) << 16);
            pk.y = (unsigned)f2bf(v[2]) | ((unsigned)f2bf(v[3]) << 16);
            *(uint2*)(srow + c4) = pk;
        }
        __syncthreads();

        const short* wpk = Wp + (size_t)k*8*16*64*8;
        for (int cs = 0; cs < 8; cs++) {
            bf16x8 af[2];
            #pragma unroll
            for (int pt = 0; pt < 2; pt++)
                af[pt] = *(const bf16x8*)(S + (pt*16 + (l & 15))*SLD
                                            + cs*32 + (l >> 4)*8);
            bf16x8 bg[4];
            #pragma unroll
            for (int ot = 0; ot < 4; ot++)
                bg[ot] = *(const bf16x8*)(wpk + ((size_t)((cs*16 + (wv*4 + ot))*64 + l))*8);
            #pragma unroll
            for (int pt = 0; pt < 2; pt++)
                #pragma unroll
                for (int ot = 0; ot < 4; ot++)
                    acc[pt][ot] = __builtin_amdgcn_mfma_f32_16x16x32_bf16(
                        af[pt], bg[ot], acc[pt][ot], 0, 0, 0);
        }
        __syncthreads();
    }

    float* myS = Sf + wv*(64*17);
    #pragma unroll
    for (int pt = 0; pt < 2; pt++) {
        #pragma unroll
        for (int ot = 0; ot < 4; ot++)
            #pragma unroll
            for (int r = 0; r < 4; r++)
                myS[(ot*16 + (l & 15))*17 + (l >> 4)*4 + r] = acc[pt][ot][r];
        __syncthreads();
        #pragma unroll
        for (int i = 0; i < 16; i++) {
            int ocl = i*4 + (l >> 4);
            dcn_out[((size_t)(b*256 + wv*64 + ocl))*HW + row*WW + px0 + pt*16 + (l & 15)]
                = myS[ocl*17 + (l & 15)];
        }
        __syncthreads();
    }
}

// K3: GroupNorm stats (32 groups of 8 channels) -> mu, rstd
__global__ __launch_bounds__(256) void gn_stats_kernel(
        const float* __restrict__ dcn, float* __restrict__ stats) {
    int b = blockIdx.x >> 5, g = blockIdx.x & 31;
    const float* base = dcn + ((size_t)b*CC + g*8)*HW;
    float s=0.f, s2=0.f;
    for (int i = threadIdx.x; i < 8*HW; i += 256) {
        float v = base[i]; s += v; s2 += v*v;
    }
    __shared__ float rs[256], rs2[256];
    rs[threadIdx.x]=s; rs2[threadIdx.x]=s2; __syncthreads();
    for (int o=128;o>0;o>>=1){
        if (threadIdx.x<o){ rs[threadIdx.x]+=rs[threadIdx.x+o]; rs2[threadIdx.x]+=rs2[threadIdx.x+o]; }
        __syncthreads();
    }
    if (threadIdx.x==0) {
        float inv = 1.f/(8.f*HW);
        float mu = rs[0]*inv;
        float var = rs2[0]*inv - mu*mu;
        stats[blockIdx.x*2]   = mu;
        stats[blockIdx.x*2+1] = rsqrtf(var + 1e-5f);
    }
}

// K4: feat_new = feat + relu(gn(dcn)) -> d_out (output 0)
__global__ void gn_apply_kernel(
        const float* __restrict__ feat, const float* __restrict__ dcn,
        const float* __restrict__ stats, const float* __restrict__ gamma,
        const float* __restrict__ beta, float* __restrict__ out) {
    size_t idx = (size_t)blockIdx.x*256 + threadIdx.x;   // 8388608 total
    int c = (int)((idx >> 12) & 255);
    int b = (int)(idx >> 20);
    int g = c >> 3;
    float mu = stats[(b*32+g)*2], rstd = stats[(b*32+g)*2+1];
    float v = (dcn[idx]-mu)*rstd*gamma[c] + beta[c];
    out[idx] = feat[idx] + fmaxf(v, 0.f);
}

// K5: 1x1 conv featn(256) -> N channels. grid (128, ceil(N/32))
__global__ __launch_bounds__(256) void conv1x1_kernel(
        const float* __restrict__ featn, const float* __restrict__ w,
        const float* __restrict__ bias, float* __restrict__ out, int N) {
    __shared__ float lw[256][32];
    int n0 = blockIdx.y*32;
    for (int i = threadIdx.x; i < 256*32; i += 256) {
        int c = i >> 5, n = i & 31;
        lw[c][n] = (n0+n < N) ? w[(size_t)(n0+n)*256 + c] : 0.f;
    }
    __syncthreads();
    int b = blockIdx.x >> 4, tile = blockIdx.x & 15;
    int p = tile*256 + threadIdx.x;
    const float* fb = featn + (size_t)b*CC*HW + p;
    float acc[32];
    #pragma unroll
    for (int i=0;i<32;i++) acc[i]=0.f;
    for (int c = 0; c < 256; c++) {
        float v = fb[(size_t)c*HW];
        #pragma unroll
        for (int i=0;i<32;i++) acc[i] += lw[c][i]*v;
    }
    for (int i = 0; i < 32; i++) {
        int n = n0 + i;
        if (n < N) out[((size_t)b*N + n)*HW + p] = acc[i] + bias[n];
    }
}

// K6: offset = (1-sig(uw))*prev + sig(uw)*uo
__global__ void offset_kernel(
        const float* __restrict__ prev, const float* __restrict__ lin_uw,
        const float* __restrict__ lin_uo, float* __restrict__ uvd) {
    size_t idx = (size_t)blockIdx.x*256 + threadIdx.x;  // 1671168
    float owv = 1.f/(1.f+expf(-lin_uw[idx]));
    uvd[idx] = (1.f-owv)*prev[idx] + owv*lin_uo[idx];
}

// K7: fused sampling + softmax-weighted sum -> new_off (output 1)
__global__ __launch_bounds__(256) void final_kernel(
        const float* __restrict__ uvd, const float* __restrict__ sconf,
        const float* __restrict__ soff, float* __restrict__ out_off) {
    int bj = blockIdx.x;            // 0..135
    int b = bj / JJ, j = bj % JJ;
    int p = blockIdx.y*256 + threadIdx.x;
    int y = p >> 6, x = p & 63;
    const float* u0 = uvd   + ((size_t)b*51  + j*3)*HW;
    const float* c0 = sconf + ((size_t)b*51  + j*3)*HW;
    const float* s0 = soff  + ((size_t)b*136 + j*8)*HW;
    float offx = u0[p], offy = u0[HW+p];
    Bil bl = bilin((float)x + offx, (float)y + offy);
    float sall[8][2];
    #pragma unroll
    for (int h = 0; h < 4; h++) {
        const float* se = s0 + (size_t)(2*h)*HW;
        const float* so2 = s0 + (size_t)(2*h+1)*HW;
        sall[h][0] = bl.w00*se[bl.i00]+bl.w01*se[bl.i01]+bl.w10*se[bl.i10]+bl.w11*se[bl.i11] + offx;
        sall[h][1] = bl.w00*so2[bl.i00]+bl.w01*so2[bl.i01]+bl.w10*so2[bl.i10]+bl.w11*so2[bl.i11] + offy;
        sall[4+h][0] = se[p];
        sall[4+h][1] = so2[p];
    }
    float sv[8][3], lg[8][3];
    #pragma unroll
    for (int n = 0; n < 8; n++) {
        Bil b2 = bilin((float)x + sall[n][0], (float)y + sall[n][1]);
        #pragma unroll
        for (int d = 0; d < 3; d++) {
            const float* ud = u0 + (size_t)d*HW;
            const float* cd = c0 + (size_t)d*HW;
            sv[n][d] = b2.w00*ud[b2.i00]+b2.w01*ud[b2.i01]+b2.w10*ud[b2.i10]+b2.w11*ud[b2.i11];
            lg[n][d] = b2.w00*cd[b2.i00]+b2.w01*cd[b2.i01]+b2.w10*cd[b2.i10]+b2.w11*cd[b2.i11];
        }
        sv[n][0] += sall[n][0];
        sv[n][1] += sall[n][1];
    }
    #pragma unroll
    for (int d = 0; d < 3; d++) {
        float m = lg[0][d];
        #pragma unroll
        for (int n = 1; n < 8; n++) m = fmaxf(m, lg[n][d]);
        float den = 0.f, num = 0.f;
        #pragma unroll
        for (int n = 0; n < 8; n++) {
            float e = expf(lg[n][d]-m);
            den += e; num += e*sv[n][d];
        }
        out_off[((size_t)b*51 + j*3 + d)*HW + p] = num/den;
    }
}

extern "C" void kernel_launch(void* const* d_in, const int* in_sizes, int n_in,
                              void* d_out, int out_size, void* d_ws, size_t ws_size,
                              hipStream_t stream) {
    const float* feat       = (const float*)d_in[0];
    const float* prev_off   = (const float*)d_in[1];
    const float* dcn_off_w  = (const float*)d_in[2];
    const float* dcn_off_b  = (const float*)d_in[3];
    const float* dcn_w      = (const float*)d_in[4];
    const float* gn_g       = (const float*)d_in[5];
    const float* gn_b       = (const float*)d_in[6];
    const float* so_w       = (const float*)d_in[7];
    const float* so_b       = (const float*)d_in[8];
    const float* sc_w       = (const float*)d_in[9];
    const float* sc_b       = (const float*)d_in[10];
    const float* uw_w       = (const float*)d_in[11];
    const float* uw_b       = (const float*)d_in[12];
    const float* uo_w       = (const float*)d_in[13];
    const float* uo_b       = (const float*)d_in[14];

    float* ws = (float*)d_ws;
    float* off27     = ws;                       // 884736 floats
    float* Wt        = off27 + 884736;           // 589824 floats region
    short* Wp        = (short*)Wt;               // 589824 shorts (dcn weights)
    short* Ap        = Wp + 589824;              // 73728 shorts (conv3x3 weights)
    float* dcn       = Wt + 589824;              // 8388608
    float* stats     = dcn + 8388608;            // 512
    float* samp_off  = stats + 512;              // 4456448
    float* samp_conf = samp_off + 4456448;       // 1671168
    float* lin_uw    = samp_conf + 1671168;      // 1671168
    float* lin_uo    = lin_uw + 1671168;         // 1671168
    float* uvd       = lin_uo + 1671168;         // 1671168

    float* out_feat = (float*)d_out;             // 8388608
    float* out_off  = out_feat + 8388608;        // 1671168

    // packs
    cpack_kernel<<<dim3(36), dim3(256), 0, stream>>>(dcn_off_w, Ap);
    wpack_kernel<<<dim3(288), dim3(256), 0, stream>>>(dcn_w, Wp);
    // K1: offset conv (3x3, MFMA)
    conv3x3_kernel<<<dim3(BB*64), dim3(256), 0, stream>>>(feat, Ap, dcn_off_b, off27);
    // K2: DCN (MFMA)
    dcn_kernel<<<dim3(BB*64*2), dim3(256), 0, stream>>>(feat, off27, Wp, dcn);
    // K3/K4: GroupNorm + residual
    gn_stats_kernel<<<dim3(BB*32), dim3(256), 0, stream>>>(dcn, stats);
    gn_apply_kernel<<<dim3(8388608/256), dim3(256), 0, stream>>>(feat, dcn, stats, gn_g, gn_b, out_feat);
    // K5: 1x1 convs on updated feat
    conv1x1_kernel<<<dim3(128, 5), dim3(256), 0, stream>>>(out_feat, so_w, so_b, samp_off, 136);
    conv1x1_kernel<<<dim3(128, 2), dim3(256), 0, stream>>>(out_feat, sc_w, sc_b, samp_conf, 51);
    conv1x1_kernel<<<dim3(128, 2), dim3(256), 0, stream>>>(out_feat, uw_w, uw_b, lin_uw, 51);
    conv1x1_kernel<<<dim3(128, 2), dim3(256), 0, stream>>>(out_feat, uo_w, uo_b, lin_uo, 51);
    // K6: offset blend
    offset_kernel<<<dim3(1671168/256), dim3(256), 0, stream>>>(prev_off, lin_uw, lin_uo, uvd);
    // K7: fused double grid-sample + softmax reduction
    final_kernel<<<dim3(BB*JJ, 16), dim3(256), 0, stream>>>(uvd, samp_conf, samp_off, out_off);
}

// Round 4
// 485.404 us; speedup vs baseline: 2.5918x; 1.3993x over previous
//
#include <hip/hip_runtime.h>
#include <hip/hip_bf16.h>
#include <math.h>

// Problem constants: B=8, C=256, H=W=64, J=17, Hd=4, dim=3
#define HH 64
#define WW 64
#define HW 4096
#define CC 256
#define BB 8
#define JJ 17

typedef __attribute__((ext_vector_type(8))) short bf16x8;
typedef __attribute__((ext_vector_type(4))) float f32x4;

#define SLD 264    // dcn/conv1x1: padded LDS row stride in shorts
#define CST 136    // conv3x3: strip c-stride in shorts (128 c + 8 pad)

struct Bil { int i00,i01,i10,i11; float w00,w01,w10,w11; };

__device__ inline Bil bilin(float sx, float sy) {
    float x0f = floorf(sx), y0f = floorf(sy);
    float wx1 = sx - x0f, wy1 = sy - y0f;
    float wx0 = 1.f - wx1, wy0 = 1.f - wy1;
    int x0 = (int)x0f, y0 = (int)y0f;
    int x1 = x0 + 1, y1 = y0 + 1;
    bool vx0 = (unsigned)x0 < (unsigned)WW;
    bool vx1 = (unsigned)x1 < (unsigned)WW;
    bool vy0 = (unsigned)y0 < (unsigned)HH;
    bool vy1 = (unsigned)y1 < (unsigned)HH;
    int x0c = min(max(x0,0),WW-1), x1c = min(max(x1,0),WW-1);
    int y0c = min(max(y0,0),HH-1), y1c = min(max(y1,0),HH-1);
    Bil b;
    b.i00 = y0c*WW + x0c; b.i01 = y0c*WW + x1c;
    b.i10 = y1c*WW + x0c; b.i11 = y1c*WW + x1c;
    b.w00 = wx0*wy0*((vx0&&vy0)?1.f:0.f);
    b.w01 = wx1*wy0*((vx1&&vy0)?1.f:0.f);
    b.w10 = wx0*wy1*((vx0&&vy1)?1.f:0.f);
    b.w11 = wx1*wy1*((vx1&&vy1)?1.f:0.f);
    return b;
}

__device__ inline unsigned short f2bf(float f) {
    unsigned u = __float_as_uint(f);
    unsigned r = (u + 0x7fffu + ((u >> 16) & 1u)) >> 16;
    return (unsigned short)r;
}

// K1a: pack dcn_off_w (27,256,3,3) into MFMA A-fragment order, bf16.
__global__ void cpack_kernel(const float* __restrict__ w, short* __restrict__ Ap) {
    int idx = blockIdx.x*256 + threadIdx.x;   // 9*2*8*64 = 9216
    if (idx >= 9*2*8*64) return;
    int l  = idx & 63;
    int cs = (idx >> 6) & 7;
    int mt = (idx >> 9) & 1;
    int k  = idx >> 10;
    int oc = mt*16 + (l & 15);
    int c0 = cs*32 + (l >> 4)*8;
    short* dst = Ap + (size_t)idx*8;
    #pragma unroll
    for (int i = 0; i < 8; i++) {
        float v = (oc < 27) ? w[((size_t)(oc*256 + c0 + i)*3 + k/3)*3 + (k % 3)] : 0.f;
        dst[i] = (short)f2bf(v);
    }
}

// K1: 3x3 conv feat(256) -> off27 via MFMA on a 3-row bf16 strip.
__global__ __launch_bounds__(256, 3) void conv3x3_kernel(
        const float* __restrict__ feat, const short* __restrict__ Ap,
        const float* __restrict__ bias, float* __restrict__ off27) {
    __shared__ __align__(16) short S[3*66*CST];   // 52.6 KB
    int orig = blockIdx.x;                        // 512 blocks
    int blk = (orig & 7)*64 + (orig >> 3);        // XCD swizzle: xcd == batch
    int b = blk >> 6, row = blk & 63;
    int t = threadIdx.x;
    int l = t & 63, wv = t >> 6;

    f32x4 acc[2];
    acc[0] = (f32x4){0.f,0.f,0.f,0.f};
    acc[1] = (f32x4){0.f,0.f,0.f,0.f};
    const float* fb = feat + (size_t)b*CC*HW;

    for (int ch = 0; ch < 2; ch++) {
        for (int i = t; i < 3*128*66; i += 256) {
            int px_s = i % 66;
            int rc   = i / 66;
            int r = rc >> 7, c = rc & 127;
            int yy = row + r - 1;
            int xx = px_s - 1;
            float v = 0.f;
            if ((unsigned)yy < 64u && (unsigned)xx < 64u)
                v = fb[(size_t)(ch*128 + c)*HW + yy*64 + xx];
            S[(r*66 + px_s)*CST + c] = (short)f2bf(v);
        }
        __syncthreads();
        #pragma unroll
        for (int k = 0; k < 9; k++) {
            int ky = k/3, kx = k%3;
            const short* srow = S + (ky*66 + wv*16 + (l & 15) + kx)*CST + (l >> 4)*8;
            #pragma unroll
            for (int csl = 0; csl < 4; csl++) {
                bf16x8 bfrag = *(const bf16x8*)(srow + csl*32);
                int cs = ch*4 + csl;
                const short* ap = Ap + ((size_t)((k*2)*8 + cs)*64 + l)*8;
                bf16x8 a0 = *(const bf16x8*)ap;
                bf16x8 a1 = *(const bf16x8*)(ap + 8*64*8);
                acc[0] = __builtin_amdgcn_mfma_f32_16x16x32_bf16(a0, bfrag, acc[0], 0, 0, 0);
                acc[1] = __builtin_amdgcn_mfma_f32_16x16x32_bf16(a1, bfrag, acc[1], 0, 0, 0);
            }
        }
        __syncthreads();
    }
    #pragma unroll
    for (int mt = 0; mt < 2; mt++)
        #pragma unroll
        for (int r = 0; r < 4; r++) {
            int oc = mt*16 + (l >> 4)*4 + r;
            if (oc < 27)
                off27[((size_t)(b*27 + oc))*HW + row*64 + wv*16 + (l & 15)]
                    = acc[mt][r] + bias[oc];
        }
}

// K1b: pack dcn_w into MFMA B-fragment order, bf16.
__global__ void wpack_kernel(const float* __restrict__ w, short* __restrict__ Wp) {
    int idx = blockIdx.x*256 + threadIdx.x;   // 9*8*16*64 = 73728
    if (idx >= 9*8*16*64) return;
    int l  = idx & 63;
    int ot = (idx >> 6) & 15;
    int cs = (idx >> 10) & 7;
    int k  = idx >> 13;
    int oc = ot*16 + (l & 15);
    int c0 = cs*32 + (l >> 4)*8;
    short* dst = Wp + (size_t)idx*8;
    #pragma unroll
    for (int i = 0; i < 8; i++) {
        float v = w[((size_t)(oc*256 + c0 + i)*3 + k/3)*3 + (k % 3)];
        dst[i] = (short)f2bf(v);
    }
}

// K1c: pack the four 1x1-conv weights into MFMA A-fragment order (320 oc).
__global__ void wpack4_kernel(const float* __restrict__ so_w, const float* __restrict__ sc_w,
        const float* __restrict__ uw_w, const float* __restrict__ uo_w,
        short* __restrict__ Wc) {
    int idx = blockIdx.x*256 + threadIdx.x;   // 8*20*64 = 10240
    if (idx >= 8*20*64) return;
    int l  = idx & 63;
    int ot = (idx >> 6) % 20;
    int cs = idx / (64*20);
    int g  = ot*16 + (l & 15);
    int c0 = cs*32 + (l >> 4)*8;
    const float* src = nullptr; int oc = 0;
    if (g < 136)      { src = so_w; oc = g; }
    else if (g < 187) { src = sc_w; oc = g - 136; }
    else if (g < 238) { src = uw_w; oc = g - 187; }
    else if (g < 289) { src = uo_w; oc = g - 238; }
    short* dst = Wc + (size_t)idx*8;
    #pragma unroll
    for (int i = 0; i < 8; i++)
        dst[i] = src ? (short)f2bf(src[(size_t)oc*256 + c0 + i]) : (short)0;
}

// K2: fused DCNv2: bilinear sample -> LDS (bf16), MFMA GEMM over (k,c).
__global__ __launch_bounds__(256, 6) void dcn_kernel(
        const float* __restrict__ feat, const float* __restrict__ off27,
        const short* __restrict__ Wp, float* __restrict__ dcn_out) {
    __shared__ __align__(16) char LDSBUF[17536];
    short* S  = (short*)LDSBUF;
    float* Sf = (float*)LDSBUF;

    int orig = blockIdx.x;                 // 1024 blocks
    int blk  = (orig & 7)*128 + (orig >> 3);  // XCD swizzle: xcd == batch
    int b   = blk >> 7;
    int rh  = blk & 127;
    int row = rh >> 1;
    int px0 = (rh & 1) * 32;

    int t   = threadIdx.x;
    int pxl = t & 31, cq = t >> 5;
    int l   = t & 63, wv = t >> 6;

    f32x4 acc[2][4];
    #pragma unroll
    for (int i = 0; i < 2; i++)
        #pragma unroll
        for (int j = 0; j < 4; j++) acc[i][j] = (f32x4){0.f,0.f,0.f,0.f};

    const float* fb = feat + (size_t)b*CC*HW;
    int px = px0 + pxl;
    int p  = row*WW + px;

    for (int k = 0; k < 9; k++) {
        float dyv = off27[((size_t)b*27 + k)*HW + p];
        float dxv = off27[((size_t)b*27 + 9 + k)*HW + p];
        float mk  = off27[((size_t)b*27 + 18 + k)*HW + p];
        float m = 1.f/(1.f + expf(-mk));
        Bil bl = bilin((float)px + (float)(k%3 - 1) + dxv,
                       (float)row + (float)(k/3 - 1) + dyv);
        float w00 = bl.w00*m, w01 = bl.w01*m, w10 = bl.w10*m, w11 = bl.w11*m;
        const float* fc = fb + (size_t)cq*32*HW;
        short* srow = S + pxl*SLD + cq*32;
        #pragma unroll 2
        for (int c4 = 0; c4 < 32; c4 += 4) {
            float v[4];
            #pragma unroll
            for (int j = 0; j < 4; j++) {
                const float* f1 = fc + (size_t)(c4 + j)*HW;
                v[j] = w00*f1[bl.i00] + w01*f1[bl.i01]
                     + w10*f1[bl.i10] + w11*f1[bl.i11];
            }
            uint2 pk;
            pk.x = (unsigned)f2bf(v[0]) | ((unsigned)f2bf(v[1]) << 16);
            pk.y = (unsigned)f2bf(v[2]) | ((unsigned)f2bf(v[3]) << 16);
            *(uint2*)(srow + c4) = pk;
        }
        __syncthreads();

        const short* wpk = Wp + (size_t)k*8*16*64*8;
        for (int cs = 0; cs < 8; cs++) {
            bf16x8 af[2];
            #pragma unroll
            for (int pt = 0; pt < 2; pt++)
                af[pt] = *(const bf16x8*)(S + (pt*16 + (l & 15))*SLD
                                            + cs*32 + (l >> 4)*8);
            bf16x8 bg[4];
            #pragma unroll
            for (int ot = 0; ot < 4; ot++)
                bg[ot] = *(const bf16x8*)(wpk + ((size_t)((cs*16 + (wv*4 + ot))*64 + l))*8);
            #pragma unroll
            for (int pt = 0; pt < 2; pt++)
                #pragma unroll
                for (int ot = 0; ot < 4; ot++)
                    acc[pt][ot] = __builtin_amdgcn_mfma_f32_16x16x32_bf16(
                        af[pt], bg[ot], acc[pt][ot], 0, 0, 0);
        }
        __syncthreads();
    }

    float* myS = Sf + wv*(64*17);
    #pragma unroll
    for (int pt = 0; pt < 2; pt++) {
        #pragma unroll
        for (int ot = 0; ot < 4; ot++)
            #pragma unroll
            for (int r = 0; r < 4; r++)
                myS[(ot*16 + (l & 15))*17 + (l >> 4)*4 + r] = acc[pt][ot][r];
        __syncthreads();
        #pragma unroll
        for (int i = 0; i < 16; i++) {
            int ocl = i*4 + (l >> 4);
            dcn_out[((size_t)(b*256 + wv*64 + ocl))*HW + row*WW + px0 + pt*16 + (l & 15)]
                = myS[ocl*17 + (l & 15)];
        }
        __syncthreads();
    }
}

// K3: GroupNorm stats (32 groups of 8 channels) -> mu, rstd
__global__ __launch_bounds__(256) void gn_stats_kernel(
        const float* __restrict__ dcn, float* __restrict__ stats) {
    int b = blockIdx.x >> 5, g = blockIdx.x & 31;
    const float* base = dcn + ((size_t)b*CC + g*8)*HW;
    float s=0.f, s2=0.f;
    for (int i = threadIdx.x; i < 8*HW; i += 256) {
        float v = base[i]; s += v; s2 += v*v;
    }
    __shared__ float rs[256], rs2[256];
    rs[threadIdx.x]=s; rs2[threadIdx.x]=s2; __syncthreads();
    for (int o=128;o>0;o>>=1){
        if (threadIdx.x<o){ rs[threadIdx.x]+=rs[threadIdx.x+o]; rs2[threadIdx.x]+=rs2[threadIdx.x+o]; }
        __syncthreads();
    }
    if (threadIdx.x==0) {
        float inv = 1.f/(8.f*HW);
        float mu = rs[0]*inv;
        float var = rs2[0]*inv - mu*mu;
        stats[blockIdx.x*2]   = mu;
        stats[blockIdx.x*2+1] = rsqrtf(var + 1e-5f);
    }
}

// K4: feat_new = feat + relu(gn(dcn)) -> d_out (output 0)
__global__ void gn_apply_kernel(
        const float* __restrict__ feat, const float* __restrict__ dcn,
        const float* __restrict__ stats, const float* __restrict__ gamma,
        const float* __restrict__ beta, float* __restrict__ out) {
    size_t idx = (size_t)blockIdx.x*256 + threadIdx.x;   // 8388608 total
    int c = (int)((idx >> 12) & 255);
    int b = (int)(idx >> 20);
    int g = c >> 3;
    float mu = stats[(b*32+g)*2], rstd = stats[(b*32+g)*2+1];
    float v = (dcn[idx]-mu)*rstd*gamma[c] + beta[c];
    out[idx] = feat[idx] + fmaxf(v, 0.f);
}

// K5: fused 1x1 convs (289 oc padded to 320) via MFMA.
// block = 256 thr (4 waves); tile = 64 px (one image row) x 320 oc; grid 512.
__global__ __launch_bounds__(256, 2) void conv1x1_fused_kernel(
        const float* __restrict__ featn, const short* __restrict__ Wc,
        const float* __restrict__ so_b, const float* __restrict__ sc_b,
        const float* __restrict__ uw_b, const float* __restrict__ uo_b,
        float* __restrict__ samp_off, float* __restrict__ samp_conf,
        float* __restrict__ lin_uw, float* __restrict__ lin_uo) {
    __shared__ __align__(16) short S[64*SLD];   // 33.8 KB
    int blk = blockIdx.x;          // b*64 + row
    int b = blk >> 6, row = blk & 63;
    int t = threadIdx.x;
    int x = t & 63, cq = t >> 6;
    int l = t & 63, wv = t >> 6;

    const float* fb = featn + (size_t)b*CC*HW + row*64;
    #pragma unroll
    for (int j = 0; j < 16; j++) {
        int c0 = cq*64 + j*4;
        float v0 = fb[(size_t)(c0+0)*HW + x];
        float v1 = fb[(size_t)(c0+1)*HW + x];
        float v2 = fb[(size_t)(c0+2)*HW + x];
        float v3 = fb[(size_t)(c0+3)*HW + x];
        uint2 pk;
        pk.x = (unsigned)f2bf(v0) | ((unsigned)f2bf(v1) << 16);
        pk.y = (unsigned)f2bf(v2) | ((unsigned)f2bf(v3) << 16);
        *(uint2*)(S + x*SLD + c0) = pk;
    }
    __syncthreads();

    f32x4 acc[5][4];
    #pragma unroll
    for (int j = 0; j < 5; j++)
        #pragma unroll
        for (int pt = 0; pt < 4; pt++) acc[j][pt] = (f32x4){0.f,0.f,0.f,0.f};

    for (int cs = 0; cs < 8; cs++) {
        bf16x8 bg[4];
        #pragma unroll
        for (int pt = 0; pt < 4; pt++)
            bg[pt] = *(const bf16x8*)(S + (pt*16 + (l & 15))*SLD
                                        + cs*32 + (l >> 4)*8);
        #pragma unroll
        for (int j = 0; j < 5; j++) {
            bf16x8 a = *(const bf16x8*)(Wc + ((size_t)(cs*20 + wv*5 + j)*64 + l)*8);
            #pragma unroll
            for (int pt = 0; pt < 4; pt++)
                acc[j][pt] = __builtin_amdgcn_mfma_f32_16x16x32_bf16(
                    a, bg[pt], acc[j][pt], 0, 0, 0);
        }
    }

    // D: col (l&15) = px-in-tile, row = oc-in-tile. Coalesced 64B stores per row.
    #pragma unroll
    for (int j = 0; j < 5; j++) {
        #pragma unroll
        for (int pt = 0; pt < 4; pt++) {
            int p = row*64 + pt*16 + (l & 15);
            #pragma unroll
            for (int r = 0; r < 4; r++) {
                int oc = (wv*5 + j)*16 + (l >> 4)*4 + r;
                float v = acc[j][pt][r];
                if (oc < 136)
                    samp_off[((size_t)(b*136 + oc))*HW + p] = v + so_b[oc];
                else if (oc < 187)
                    samp_conf[((size_t)(b*51 + oc-136))*HW + p] = v + sc_b[oc-136];
                else if (oc < 238)
                    lin_uw[((size_t)(b*51 + oc-187))*HW + p] = v + uw_b[oc-187];
                else if (oc < 289)
                    lin_uo[((size_t)(b*51 + oc-238))*HW + p] = v + uo_b[oc-238];
            }
        }
    }
}

// K6: offset = (1-sig(uw))*prev + sig(uw)*uo
__global__ void offset_kernel(
        const float* __restrict__ prev, const float* __restrict__ lin_uw,
        const float* __restrict__ lin_uo, float* __restrict__ uvd) {
    size_t idx = (size_t)blockIdx.x*256 + threadIdx.x;  // 1671168
    float owv = 1.f/(1.f+expf(-lin_uw[idx]));
    uvd[idx] = (1.f-owv)*prev[idx] + owv*lin_uo[idx];
}

// K7: fused sampling + softmax-weighted sum -> new_off (output 1)
__global__ __launch_bounds__(256) void final_kernel(
        const float* __restrict__ uvd, const float* __restrict__ sconf,
        const float* __restrict__ soff, float* __restrict__ out_off) {
    int bj = blockIdx.x;            // 0..135
    int b = bj / JJ, j = bj % JJ;
    int p = blockIdx.y*256 + threadIdx.x;
    int y = p >> 6, x = p & 63;
    const float* u0 = uvd   + ((size_t)b*51  + j*3)*HW;
    const float* c0 = sconf + ((size_t)b*51  + j*3)*HW;
    const float* s0 = soff  + ((size_t)b*136 + j*8)*HW;
    float offx = u0[p], offy = u0[HW+p];
    Bil bl = bilin((float)x + offx, (float)y + offy);
    float sall[8][2];
    #pragma unroll
    for (int h = 0; h < 4; h++) {
        const float* se = s0 + (size_t)(2*h)*HW;
        const float* so2 = s0 + (size_t)(2*h+1)*HW;
        sall[h][0] = bl.w00*se[bl.i00]+bl.w01*se[bl.i01]+bl.w10*se[bl.i10]+bl.w11*se[bl.i11] + offx;
        sall[h][1] = bl.w00*so2[bl.i00]+bl.w01*so2[bl.i01]+bl.w10*so2[bl.i10]+bl.w11*so2[bl.i11] + offy;
        sall[4+h][0] = se[p];
        sall[4+h][1] = so2[p];
    }
    float sv[8][3], lg[8][3];
    #pragma unroll
    for (int n = 0; n < 8; n++) {
        Bil b2 = bilin((float)x + sall[n][0], (float)y + sall[n][1]);
        #pragma unroll
        for (int d = 0; d < 3; d++) {
            const float* ud = u0 + (size_t)d*HW;
            const float* cd = c0 + (size_t)d*HW;
            sv[n][d] = b2.w00*ud[b2.i00]+b2.w01*ud[b2.i01]+b2.w10*ud[b2.i10]+b2.w11*ud[b2.i11];
            lg[n][d] = b2.w00*cd[b2.i00]+b2.w01*cd[b2.i01]+b2.w10*cd[b2.i10]+b2.w11*cd[b2.i11];
        }
        sv[n][0] += sall[n][0];
        sv[n][1] += sall[n][1];
    }
    #pragma unroll
    for (int d = 0; d < 3; d++) {
        float m = lg[0][d];
        #pragma unroll
        for (int n = 1; n < 8; n++) m = fmaxf(m, lg[n][d]);
        float den = 0.f, num = 0.f;
        #pragma unroll
        for (int n = 0; n < 8; n++) {
            float e = expf(lg[n][d]-m);
            den += e; num += e*sv[n][d];
        }
        out_off[((size_t)b*51 + j*3 + d)*HW + p] = num/den;
    }
}

extern "C" void kernel_launch(void* const* d_in, const int* in_sizes, int n_in,
                              void* d_out, int out_size, void* d_ws, size_t ws_size,
                              hipStream_t stream) {
    const float* feat       = (const float*)d_in[0];
    const float* prev_off   = (const float*)d_in[1];
    const float* dcn_off_w  = (const float*)d_in[2];
    const float* dcn_off_b  = (const float*)d_in[3];
    const float* dcn_w      = (const float*)d_in[4];
    const float* gn_g       = (const float*)d_in[5];
    const float* gn_b       = (const float*)d_in[6];
    const float* so_w       = (const float*)d_in[7];
    const float* so_b       = (const float*)d_in[8];
    const float* sc_w       = (const float*)d_in[9];
    const float* sc_b       = (const float*)d_in[10];
    const float* uw_w       = (const float*)d_in[11];
    const float* uw_b       = (const float*)d_in[12];
    const float* uo_w       = (const float*)d_in[13];
    const float* uo_b       = (const float*)d_in[14];

    float* ws = (float*)d_ws;
    float* off27     = ws;                       // 884736 floats
    float* Wt        = off27 + 884736;           // 589824-float region for packs
    short* Wp        = (short*)Wt;               // 589824 shorts (dcn weights)
    short* Ap        = Wp + 589824;              // 73728 shorts (conv3x3 weights)
    short* Wc        = Ap + 73728;               // 81920 shorts (1x1 weights)
    float* dcn       = Wt + 589824;              // 8388608
    float* stats     = dcn + 8388608;            // 512
    float* samp_off  = stats + 512;              // 4456448
    float* samp_conf = samp_off + 4456448;       // 1671168
    float* lin_uw    = samp_conf + 1671168;      // 1671168
    float* lin_uo    = lin_uw + 1671168;         // 1671168
    float* uvd       = lin_uo + 1671168;         // 1671168

    float* out_feat = (float*)d_out;             // 8388608
    float* out_off  = out_feat + 8388608;        // 1671168

    // packs
    cpack_kernel<<<dim3(36), dim3(256), 0, stream>>>(dcn_off_w, Ap);
    wpack_kernel<<<dim3(288), dim3(256), 0, stream>>>(dcn_w, Wp);
    wpack4_kernel<<<dim3(40), dim3(256), 0, stream>>>(so_w, sc_w, uw_w, uo_w, Wc);
    // K1: offset conv (3x3, MFMA, XCD-swizzled)
    conv3x3_kernel<<<dim3(BB*64), dim3(256), 0, stream>>>(feat, Ap, dcn_off_b, off27);
    // K2: DCN (MFMA, XCD-swizzled)
    dcn_kernel<<<dim3(BB*64*2), dim3(256), 0, stream>>>(feat, off27, Wp, dcn);
    // K3/K4: GroupNorm + residual
    gn_stats_kernel<<<dim3(BB*32), dim3(256), 0, stream>>>(dcn, stats);
    gn_apply_kernel<<<dim3(8388608/256), dim3(256), 0, stream>>>(feat, dcn, stats, gn_g, gn_b, out_feat);
    // K5: fused 1x1 convs (MFMA)
    conv1x1_fused_kernel<<<dim3(512), dim3(256), 0, stream>>>(out_feat, Wc,
        so_b, sc_b, uw_b, uo_b, samp_off, samp_conf, lin_uw, lin_uo);
    // K6: offset blend
    offset_kernel<<<dim3(1671168/256), dim3(256), 0, stream>>>(prev_off, lin_uw, lin_uo, uvd);
    // K7: fused double grid-sample + softmax reduction
    final_kernel<<<dim3(BB*JJ, 16), dim3(256), 0, stream>>>(uvd, samp_conf, samp_off, out_off);
}

// Round 5
// 290.697 us; speedup vs baseline: 4.3277x; 1.6698x over previous
//
#include <hip/hip_runtime.h>
#include <hip/hip_bf16.h>
#include <math.h>

// Problem constants: B=8, C=256, H=W=64, J=17, Hd=4, dim=3
#define HH 64
#define WW 64
#define HW 4096
#define CC 256
#define BB 8
#define JJ 17

typedef __attribute__((ext_vector_type(8))) short bf16x8;
typedef __attribute__((ext_vector_type(4))) float f32x4;

#define SLD 264    // dcn/conv1x1: padded LDS row stride in shorts
#define CST 136    // conv3x3: strip c-stride in shorts (128 c + 8 pad)
#define TLD 266    // transpose LDS stride in shorts (stride%32 dwords = 5, conflict-free)

struct Bil { int i00,i01,i10,i11; float w00,w01,w10,w11; };

__device__ inline Bil bilin(float sx, float sy) {
    float x0f = floorf(sx), y0f = floorf(sy);
    float wx1 = sx - x0f, wy1 = sy - y0f;
    float wx0 = 1.f - wx1, wy0 = 1.f - wy1;
    int x0 = (int)x0f, y0 = (int)y0f;
    int x1 = x0 + 1, y1 = y0 + 1;
    bool vx0 = (unsigned)x0 < (unsigned)WW;
    bool vx1 = (unsigned)x1 < (unsigned)WW;
    bool vy0 = (unsigned)y0 < (unsigned)HH;
    bool vy1 = (unsigned)y1 < (unsigned)HH;
    int x0c = min(max(x0,0),WW-1), x1c = min(max(x1,0),WW-1);
    int y0c = min(max(y0,0),HH-1), y1c = min(max(y1,0),HH-1);
    Bil b;
    b.i00 = y0c*WW + x0c; b.i01 = y0c*WW + x1c;
    b.i10 = y1c*WW + x0c; b.i11 = y1c*WW + x1c;
    b.w00 = wx0*wy0*((vx0&&vy0)?1.f:0.f);
    b.w01 = wx1*wy0*((vx1&&vy0)?1.f:0.f);
    b.w10 = wx0*wy1*((vx0&&vy1)?1.f:0.f);
    b.w11 = wx1*wy1*((vx1&&vy1)?1.f:0.f);
    return b;
}

__device__ inline unsigned short f2bf(float f) {
    unsigned u = __float_as_uint(f);
    unsigned r = (u + 0x7fffu + ((u >> 16) & 1u)) >> 16;
    return (unsigned short)r;
}
__device__ inline float bflo(unsigned u) { return __uint_as_float(u << 16); }
__device__ inline float bfhi(unsigned u) { return __uint_as_float(u & 0xFFFF0000u); }

// K0: transpose feat (NCHW f32) -> featT (N,px,c) bf16. grid 8*64 blocks.
__global__ __launch_bounds__(256) void nhwc_kernel(
        const float* __restrict__ feat, unsigned short* __restrict__ featT) {
    __shared__ unsigned short T[64*TLD];   // 34 KB
    int b = blockIdx.x >> 6, p0 = (blockIdx.x & 63)*64;
    int t = threadIdx.x;
    int x = t & 63, c4 = t >> 6;
    const float* fb = feat + (size_t)b*CC*HW + p0;
    #pragma unroll 4
    for (int cp = 0; cp < 256; cp += 4) {
        int c = cp + c4;
        T[x*TLD + c] = f2bf(fb[(size_t)c*HW + x]);
    }
    __syncthreads();
    int xq = t >> 5, cl = t & 31;           // write: 32 lanes cover 256 c
    unsigned short* dst = featT + ((size_t)b*HW + p0)*256;
    #pragma unroll
    for (int w = 0; w < 8; w++) {
        int xr = w*8 + xq;
        *(uint4*)(dst + (size_t)xr*256 + cl*8) = *(const uint4*)(T + xr*TLD + cl*8);
    }
}

// K1a: pack dcn_off_w (27,256,3,3) into MFMA A-fragment order, bf16.
__global__ void cpack_kernel(const float* __restrict__ w, short* __restrict__ Ap) {
    int idx = blockIdx.x*256 + threadIdx.x;   // 9*2*8*64 = 9216
    if (idx >= 9*2*8*64) return;
    int l  = idx & 63;
    int cs = (idx >> 6) & 7;
    int mt = (idx >> 9) & 1;
    int k  = idx >> 10;
    int oc = mt*16 + (l & 15);
    int c0 = cs*32 + (l >> 4)*8;
    short* dst = Ap + (size_t)idx*8;
    #pragma unroll
    for (int i = 0; i < 8; i++) {
        float v = (oc < 27) ? w[((size_t)(oc*256 + c0 + i)*3 + k/3)*3 + (k % 3)] : 0.f;
        dst[i] = (short)f2bf(v);
    }
}

// K1: 3x3 conv featT(256, bf16 NHWC) -> off27 via MFMA on a 3-row strip.
__global__ __launch_bounds__(256, 3) void conv3x3_kernel(
        const unsigned short* __restrict__ featT, const short* __restrict__ Ap,
        const float* __restrict__ bias, float* __restrict__ off27) {
    __shared__ __align__(16) short S[3*66*CST];   // 52.6 KB
    int orig = blockIdx.x;                        // 512 blocks
    int blk = (orig & 7)*64 + (orig >> 3);        // XCD swizzle: xcd == batch
    int b = blk >> 6, row = blk & 63;
    int t = threadIdx.x;
    int l = t & 63, wv = t >> 6;

    f32x4 acc[2];
    acc[0] = (f32x4){0.f,0.f,0.f,0.f};
    acc[1] = (f32x4){0.f,0.f,0.f,0.f};
    const unsigned short* fb = featT + (size_t)b*HW*256;

    for (int ch = 0; ch < 2; ch++) {
        // stage strip: rows row-1..row+1, channels ch*128..+128, x halo -1..64
        for (int i = t; i < 3*66*16; i += 256) {
            int cc = i & 15;
            int rp = i >> 4;
            int r = rp / 66, px_s = rp - r*66;
            int yy = row + r - 1;
            int xx = px_s - 1;
            uint4 v = (uint4){0u,0u,0u,0u};
            if ((unsigned)yy < 64u && (unsigned)xx < 64u)
                v = *(const uint4*)(fb + ((size_t)(yy*64 + xx))*256 + ch*128 + cc*8);
            *(uint4*)(&S[(r*66 + px_s)*CST + cc*8]) = v;
        }
        __syncthreads();
        #pragma unroll
        for (int k = 0; k < 9; k++) {
            int ky = k/3, kx = k%3;
            const short* srow = S + (ky*66 + wv*16 + (l & 15) + kx)*CST + (l >> 4)*8;
            #pragma unroll
            for (int csl = 0; csl < 4; csl++) {
                bf16x8 bfrag = *(const bf16x8*)(srow + csl*32);
                int cs = ch*4 + csl;
                const short* ap = Ap + ((size_t)((k*2)*8 + cs)*64 + l)*8;
                bf16x8 a0 = *(const bf16x8*)ap;
                bf16x8 a1 = *(const bf16x8*)(ap + 8*64*8);
                acc[0] = __builtin_amdgcn_mfma_f32_16x16x32_bf16(a0, bfrag, acc[0], 0, 0, 0);
                acc[1] = __builtin_amdgcn_mfma_f32_16x16x32_bf16(a1, bfrag, acc[1], 0, 0, 0);
            }
        }
        __syncthreads();
    }
    #pragma unroll
    for (int mt = 0; mt < 2; mt++)
        #pragma unroll
        for (int r = 0; r < 4; r++) {
            int oc = mt*16 + (l >> 4)*4 + r;
            if (oc < 27)
                off27[((size_t)(b*27 + oc))*HW + row*64 + wv*16 + (l & 15)]
                    = acc[mt][r] + bias[oc];
        }
}

// K1b: pack dcn_w into MFMA B-fragment order, bf16.
__global__ void wpack_kernel(const float* __restrict__ w, short* __restrict__ Wp) {
    int idx = blockIdx.x*256 + threadIdx.x;   // 9*8*16*64 = 73728
    if (idx >= 9*8*16*64) return;
    int l  = idx & 63;
    int ot = (idx >> 6) & 15;
    int cs = (idx >> 10) & 7;
    int k  = idx >> 13;
    int oc = ot*16 + (l & 15);
    int c0 = cs*32 + (l >> 4)*8;
    short* dst = Wp + (size_t)idx*8;
    #pragma unroll
    for (int i = 0; i < 8; i++) {
        float v = w[((size_t)(oc*256 + c0 + i)*3 + k/3)*3 + (k % 3)];
        dst[i] = (short)f2bf(v);
    }
}

// K1c: pack the four 1x1-conv weights into MFMA A-fragment order (320 oc).
__global__ void wpack4_kernel(const float* __restrict__ so_w, const float* __restrict__ sc_w,
        const float* __restrict__ uw_w, const float* __restrict__ uo_w,
        short* __restrict__ Wc) {
    int idx = blockIdx.x*256 + threadIdx.x;   // 8*20*64 = 10240
    if (idx >= 8*20*64) return;
    int l  = idx & 63;
    int ot = (idx >> 6) % 20;
    int cs = idx / (64*20);
    int g  = ot*16 + (l & 15);
    int c0 = cs*32 + (l >> 4)*8;
    const float* src = nullptr; int oc = 0;
    if (g < 136)      { src = so_w; oc = g; }
    else if (g < 187) { src = sc_w; oc = g - 136; }
    else if (g < 238) { src = uw_w; oc = g - 187; }
    else if (g < 289) { src = uo_w; oc = g - 238; }
    short* dst = Wc + (size_t)idx*8;
    #pragma unroll
    for (int i = 0; i < 8; i++)
        dst[i] = src ? (short)f2bf(src[(size_t)oc*256 + c0 + i]) : (short)0;
}

// K2: fused DCNv2 from featT (bf16 NHWC): coalesced corner-vector gather ->
// LDS (bf16), MFMA GEMM over (k,c). block 256 thr; tile 32 px x 256 oc.
__global__ __launch_bounds__(256, 4) void dcn_kernel(
        const unsigned short* __restrict__ featT, const float* __restrict__ off27,
        const short* __restrict__ Wp, float* __restrict__ dcn_out) {
    __shared__ __align__(16) char LDSBUF[17536];
    short* S  = (short*)LDSBUF;
    float* Sf = (float*)LDSBUF;

    int orig = blockIdx.x;                 // 1024 blocks
    int blk  = (orig & 7)*128 + (orig >> 3);  // XCD swizzle: xcd == batch
    int b   = blk >> 7;
    int rh  = blk & 127;
    int row = rh >> 1;
    int px0 = (rh & 1) * 32;

    int t   = threadIdx.x;
    int pxq = t >> 5, cl = t & 31;    // sampling: 8 px-slots x 32 c-chunks(8)
    int l   = t & 63, wv = t >> 6;    // gemm

    f32x4 acc[2][4];
    #pragma unroll
    for (int i = 0; i < 2; i++)
        #pragma unroll
        for (int j = 0; j < 4; j++) acc[i][j] = (f32x4){0.f,0.f,0.f,0.f};

    const unsigned short* fT = featT + (size_t)b*HW*256;
    const float* offb = off27 + (size_t)b*27*HW;

    for (int k = 0; k < 9; k++) {
        int kx = k % 3 - 1, ky = k / 3 - 1;
        // ---- sampling: 4 passes x (8 px x 32 c-chunks); lanes span channels ----
        #pragma unroll
        for (int pass = 0; pass < 4; pass++) {
            int pxl = pass*8 + pxq;
            int px  = px0 + pxl;
            int p   = row*64 + px;
            float dyv = offb[(size_t)k*HW + p];
            float dxv = offb[(size_t)(9 + k)*HW + p];
            float mk  = offb[(size_t)(18 + k)*HW + p];
            float m = 1.f/(1.f + expf(-mk));
            Bil bl = bilin((float)(px + kx) + dxv, (float)(row + ky) + dyv);
            float w00 = bl.w00*m, w01 = bl.w01*m, w10 = bl.w10*m, w11 = bl.w11*m;
            uint4 u00 = *(const uint4*)(fT + (size_t)bl.i00*256 + cl*8);
            uint4 u01 = *(const uint4*)(fT + (size_t)bl.i01*256 + cl*8);
            uint4 u10 = *(const uint4*)(fT + (size_t)bl.i10*256 + cl*8);
            uint4 u11 = *(const uint4*)(fT + (size_t)bl.i11*256 + cl*8);
            const unsigned* a00 = (const unsigned*)&u00;
            const unsigned* a01 = (const unsigned*)&u01;
            const unsigned* a10 = (const unsigned*)&u10;
            const unsigned* a11 = (const unsigned*)&u11;
            uint4 outp;
            unsigned* op = (unsigned*)&outp;
            #pragma unroll
            for (int q = 0; q < 4; q++) {
                float vlo = w00*bflo(a00[q]) + w01*bflo(a01[q])
                          + w10*bflo(a10[q]) + w11*bflo(a11[q]);
                float vhi = w00*bfhi(a00[q]) + w01*bfhi(a01[q])
                          + w10*bfhi(a10[q]) + w11*bfhi(a11[q]);
                op[q] = (unsigned)f2bf(vlo) | ((unsigned)f2bf(vhi) << 16);
            }
            *(uint4*)(S + pxl*SLD + cl*8) = outp;
        }
        __syncthreads();

        // ---- GEMM phase ----
        const short* wpk = Wp + (size_t)k*8*16*64*8;
        for (int cs = 0; cs < 8; cs++) {
            bf16x8 af[2];
            #pragma unroll
            for (int pt = 0; pt < 2; pt++)
                af[pt] = *(const bf16x8*)(S + (pt*16 + (l & 15))*SLD
                                            + cs*32 + (l >> 4)*8);
            bf16x8 bg[4];
            #pragma unroll
            for (int ot = 0; ot < 4; ot++)
                bg[ot] = *(const bf16x8*)(wpk + ((size_t)((cs*16 + (wv*4 + ot))*64 + l))*8);
            #pragma unroll
            for (int pt = 0; pt < 2; pt++)
                #pragma unroll
                for (int ot = 0; ot < 4; ot++)
                    acc[pt][ot] = __builtin_amdgcn_mfma_f32_16x16x32_bf16(
                        af[pt], bg[ot], acc[pt][ot], 0, 0, 0);
        }
        __syncthreads();
    }

    float* myS = Sf + wv*(64*17);
    #pragma unroll
    for (int pt = 0; pt < 2; pt++) {
        #pragma unroll
        for (int ot = 0; ot < 4; ot++)
            #pragma unroll
            for (int r = 0; r < 4; r++)
                myS[(ot*16 + (l & 15))*17 + (l >> 4)*4 + r] = acc[pt][ot][r];
        __syncthreads();
        #pragma unroll
        for (int i = 0; i < 16; i++) {
            int ocl = i*4 + (l >> 4);
            dcn_out[((size_t)(b*256 + wv*64 + ocl))*HW + row*WW + px0 + pt*16 + (l & 15)]
                = myS[ocl*17 + (l & 15)];
        }
        __syncthreads();
    }
}

// K3: GroupNorm stats (32 groups of 8 channels) -> mu, rstd
__global__ __launch_bounds__(256) void gn_stats_kernel(
        const float* __restrict__ dcn, float* __restrict__ stats) {
    int b = blockIdx.x >> 5, g = blockIdx.x & 31;
    const float* base = dcn + ((size_t)b*CC + g*8)*HW;
    float s=0.f, s2=0.f;
    for (int i = threadIdx.x; i < 8*HW; i += 256) {
        float v = base[i]; s += v; s2 += v*v;
    }
    __shared__ float rs[256], rs2[256];
    rs[threadIdx.x]=s; rs2[threadIdx.x]=s2; __syncthreads();
    for (int o=128;o>0;o>>=1){
        if (threadIdx.x<o){ rs[threadIdx.x]+=rs[threadIdx.x+o]; rs2[threadIdx.x]+=rs2[threadIdx.x+o]; }
        __syncthreads();
    }
    if (threadIdx.x==0) {
        float inv = 1.f/(8.f*HW);
        float mu = rs[0]*inv;
        float var = rs2[0]*inv - mu*mu;
        stats[blockIdx.x*2]   = mu;
        stats[blockIdx.x*2+1] = rsqrtf(var + 1e-5f);
    }
}

// K4: feat_new = feat + relu(gn(dcn)) -> d_out (output 0)
__global__ void gn_apply_kernel(
        const float* __restrict__ feat, const float* __restrict__ dcn,
        const float* __restrict__ stats, const float* __restrict__ gamma,
        const float* __restrict__ beta, float* __restrict__ out) {
    size_t idx = (size_t)blockIdx.x*256 + threadIdx.x;   // 8388608 total
    int c = (int)((idx >> 12) & 255);
    int b = (int)(idx >> 20);
    int g = c >> 3;
    float mu = stats[(b*32+g)*2], rstd = stats[(b*32+g)*2+1];
    float v = (dcn[idx]-mu)*rstd*gamma[c] + beta[c];
    out[idx] = feat[idx] + fmaxf(v, 0.f);
}

// K5: fused 1x1 convs (289 oc padded to 320) via MFMA.
__global__ __launch_bounds__(256, 2) void conv1x1_fused_kernel(
        const float* __restrict__ featn, const short* __restrict__ Wc,
        const float* __restrict__ so_b, const float* __restrict__ sc_b,
        const float* __restrict__ uw_b, const float* __restrict__ uo_b,
        float* __restrict__ samp_off, float* __restrict__ samp_conf,
        float* __restrict__ lin_uw, float* __restrict__ lin_uo) {
    __shared__ __align__(16) short S[64*SLD];   // 33.8 KB
    int blk = blockIdx.x;          // b*64 + row
    int b = blk >> 6, row = blk & 63;
    int t = threadIdx.x;
    int x = t & 63, cq = t >> 6;
    int l = t & 63, wv = t >> 6;

    const float* fb = featn + (size_t)b*CC*HW + row*64;
    #pragma unroll
    for (int j = 0; j < 16; j++) {
        int c0 = cq*64 + j*4;
        float v0 = fb[(size_t)(c0+0)*HW + x];
        float v1 = fb[(size_t)(c0+1)*HW + x];
        float v2 = fb[(size_t)(c0+2)*HW + x];
        float v3 = fb[(size_t)(c0+3)*HW + x];
        uint2 pk;
        pk.x = (unsigned)f2bf(v0) | ((unsigned)f2bf(v1) << 16);
        pk.y = (unsigned)f2bf(v2) | ((unsigned)f2bf(v3) << 16);
        *(uint2*)(S + x*SLD + c0) = pk;
    }
    __syncthreads();

    f32x4 acc[5][4];
    #pragma unroll
    for (int j = 0; j < 5; j++)
        #pragma unroll
        for (int pt = 0; pt < 4; pt++) acc[j][pt] = (f32x4){0.f,0.f,0.f,0.f};

    for (int cs = 0; cs < 8; cs++) {
        bf16x8 bg[4];
        #pragma unroll
        for (int pt = 0; pt < 4; pt++)
            bg[pt] = *(const bf16x8*)(S + (pt*16 + (l & 15))*SLD
                                        + cs*32 + (l >> 4)*8);
        #pragma unroll
        for (int j = 0; j < 5; j++) {
            bf16x8 a = *(const bf16x8*)(Wc + ((size_t)(cs*20 + wv*5 + j)*64 + l)*8);
            #pragma unroll
            for (int pt = 0; pt < 4; pt++)
                acc[j][pt] = __builtin_amdgcn_mfma_f32_16x16x32_bf16(
                    a, bg[pt], acc[j][pt], 0, 0, 0);
        }
    }

    #pragma unroll
    for (int j = 0; j < 5; j++) {
        #pragma unroll
        for (int pt = 0; pt < 4; pt++) {
            int p = row*64 + pt*16 + (l & 15);
            #pragma unroll
            for (int r = 0; r < 4; r++) {
                int oc = (wv*5 + j)*16 + (l >> 4)*4 + r;
                float v = acc[j][pt][r];
                if (oc < 136)
                    samp_off[((size_t)(b*136 + oc))*HW + p] = v + so_b[oc];
                else if (oc < 187)
                    samp_conf[((size_t)(b*51 + oc-136))*HW + p] = v + sc_b[oc-136];
                else if (oc < 238)
                    lin_uw[((size_t)(b*51 + oc-187))*HW + p] = v + uw_b[oc-187];
                else if (oc < 289)
                    lin_uo[((size_t)(b*51 + oc-238))*HW + p] = v + uo_b[oc-238];
            }
        }
    }
}

// K6: offset = (1-sig(uw))*prev + sig(uw)*uo
__global__ void offset_kernel(
        const float* __restrict__ prev, const float* __restrict__ lin_uw,
        const float* __restrict__ lin_uo, float* __restrict__ uvd) {
    size_t idx = (size_t)blockIdx.x*256 + threadIdx.x;  // 1671168
    float owv = 1.f/(1.f+expf(-lin_uw[idx]));
    uvd[idx] = (1.f-owv)*prev[idx] + owv*lin_uo[idx];
}

// K7: fused sampling + softmax-weighted sum -> new_off (output 1)
__global__ __launch_bounds__(256) void final_kernel(
        const float* __restrict__ uvd, const float* __restrict__ sconf,
        const float* __restrict__ soff, float* __restrict__ out_off) {
    int bj = blockIdx.x;            // 0..135
    int b = bj / JJ, j = bj % JJ;
    int p = blockIdx.y*256 + threadIdx.x;
    int y = p >> 6, x = p & 63;
    const float* u0 = uvd   + ((size_t)b*51  + j*3)*HW;
    const float* c0 = sconf + ((size_t)b*51  + j*3)*HW;
    const float* s0 = soff  + ((size_t)b*136 + j*8)*HW;
    float offx = u0[p], offy = u0[HW+p];
    Bil bl = bilin((float)x + offx, (float)y + offy);
    float sall[8][2];
    #pragma unroll
    for (int h = 0; h < 4; h++) {
        const float* se = s0 + (size_t)(2*h)*HW;
        const float* so2 = s0 + (size_t)(2*h+1)*HW;
        sall[h][0] = bl.w00*se[bl.i00]+bl.w01*se[bl.i01]+bl.w10*se[bl.i10]+bl.w11*se[bl.i11] + offx;
        sall[h][1] = bl.w00*so2[bl.i00]+bl.w01*so2[bl.i01]+bl.w10*so2[bl.i10]+bl.w11*so2[bl.i11] + offy;
        sall[4+h][0] = se[p];
        sall[4+h][1] = so2[p];
    }
    float sv[8][3], lg[8][3];
    #pragma unroll
    for (int n = 0; n < 8; n++) {
        Bil b2 = bilin((float)x + sall[n][0], (float)y + sall[n][1]);
        #pragma unroll
        for (int d = 0; d < 3; d++) {
            const float* ud = u0 + (size_t)d*HW;
            const float* cd = c0 + (size_t)d*HW;
            sv[n][d] = b2.w00*ud[b2.i00]+b2.w01*ud[b2.i01]+b2.w10*ud[b2.i10]+b2.w11*ud[b2.i11];
            lg[n][d] = b2.w00*cd[b2.i00]+b2.w01*cd[b2.i01]+b2.w10*cd[b2.i10]+b2.w11*cd[b2.i11];
        }
        sv[n][0] += sall[n][0];
        sv[n][1] += sall[n][1];
    }
    #pragma unroll
    for (int d = 0; d < 3; d++) {
        float m = lg[0][d];
        #pragma unroll
        for (int n = 1; n < 8; n++) m = fmaxf(m, lg[n][d]);
        float den = 0.f, num = 0.f;
        #pragma unroll
        for (int n = 0; n < 8; n++) {
            float e = expf(lg[n][d]-m);
            den += e; num += e*sv[n][d];
        }
        out_off[((size_t)b*51 + j*3 + d)*HW + p] = num/den;
    }
}

extern "C" void kernel_launch(void* const* d_in, const int* in_sizes, int n_in,
                              void* d_out, int out_size, void* d_ws, size_t ws_size,
                              hipStream_t stream) {
    const float* feat       = (const float*)d_in[0];
    const float* prev_off   = (const float*)d_in[1];
    const float* dcn_off_w  = (const float*)d_in[2];
    const float* dcn_off_b  = (const float*)d_in[3];
    const float* dcn_w      = (const float*)d_in[4];
    const float* gn_g       = (const float*)d_in[5];
    const float* gn_b       = (const float*)d_in[6];
    const float* so_w       = (const float*)d_in[7];
    const float* so_b       = (const float*)d_in[8];
    const float* sc_w       = (const float*)d_in[9];
    const float* sc_b       = (const float*)d_in[10];
    const float* uw_w       = (const float*)d_in[11];
    const float* uw_b       = (const float*)d_in[12];
    const float* uo_w       = (const float*)d_in[13];
    const float* uo_b       = (const float*)d_in[14];

    float* ws = (float*)d_ws;
    float* off27     = ws;                       // 884736 floats
    float* Wt        = off27 + 884736;           // pack region
    short* Wp        = (short*)Wt;               // 589824 shorts (dcn weights)
    short* Ap        = Wp + 589824;              // 73728 shorts (conv3x3 weights)
    short* Wc        = Ap + 73728;               // 81920 shorts (1x1 weights)
    float* dcn       = Wt + 589824;              // 8388608
    float* stats     = dcn + 8388608;            // 512
    float* samp_off  = stats + 512;              // 4456448
    float* samp_conf = samp_off + 4456448;       // 1671168
    float* lin_uw    = samp_conf + 1671168;      // 1671168
    float* lin_uo    = lin_uw + 1671168;         // 1671168
    float* uvd       = lin_uo + 1671168;         // 1671168

    // featT (8.4M ushorts = 16.8 MB) aliases samp_off (17.8 MB):
    // live only until dcn_kernel finishes; samp_off written later by conv1x1.
    unsigned short* featT = (unsigned short*)samp_off;

    float* out_feat = (float*)d_out;             // 8388608
    float* out_off  = out_feat + 8388608;        // 1671168

    // K0: NCHW f32 -> NHWC bf16 transpose
    nhwc_kernel<<<dim3(BB*64), dim3(256), 0, stream>>>(feat, featT);
    // packs
    cpack_kernel<<<dim3(36), dim3(256), 0, stream>>>(dcn_off_w, Ap);
    wpack_kernel<<<dim3(288), dim3(256), 0, stream>>>(dcn_w, Wp);
    wpack4_kernel<<<dim3(40), dim3(256), 0, stream>>>(so_w, sc_w, uw_w, uo_w, Wc);
    // K1: offset conv (3x3, MFMA, NHWC staging, XCD-swizzled)
    conv3x3_kernel<<<dim3(BB*64), dim3(256), 0, stream>>>(featT, Ap, dcn_off_b, off27);
    // K2: DCN (MFMA, NHWC coalesced gather, XCD-swizzled)
    dcn_kernel<<<dim3(BB*64*2), dim3(256), 0, stream>>>(featT, off27, Wp, dcn);
    // K3/K4: GroupNorm + residual
    gn_stats_kernel<<<dim3(BB*32), dim3(256), 0, stream>>>(dcn, stats);
    gn_apply_kernel<<<dim3(8388608/256), dim3(256), 0, stream>>>(feat, dcn, stats, gn_g, gn_b, out_feat);
    // K5: fused 1x1 convs (MFMA)
    conv1x1_fused_kernel<<<dim3(512), dim3(256), 0, stream>>>(out_feat, Wc,
        so_b, sc_b, uw_b, uo_b, samp_off, samp_conf, lin_uw, lin_uo);
    // K6: offset blend
    offset_kernel<<<dim3(1671168/256), dim3(256), 0, stream>>>(prev_off, lin_uw, lin_uo, uvd);
    // K7: fused double grid-sample + softmax reduction
    final_kernel<<<dim3(BB*JJ, 16), dim3(256), 0, stream>>>(uvd, samp_conf, samp_off, out_off);
}

// Round 6
// 257.908 us; speedup vs baseline: 4.8779x; 1.1271x over previous
//
#include <hip/hip_runtime.h>
#include <hip/hip_bf16.h>
#include <math.h>

// Problem constants: B=8, C=256, H=W=64, J=17, Hd=4, dim=3
#define HH 64
#define WW 64
#define HW 4096
#define CC 256
#define BB 8
#define JJ 17

typedef __attribute__((ext_vector_type(8))) short bf16x8;
typedef __attribute__((ext_vector_type(4))) float f32x4;

#define SLD 264    // padded LDS row stride in shorts
#define CST 136    // conv3x3: strip c-stride in shorts (128 c + 8 pad)
#define TLD 266    // transpose LDS stride in shorts

struct Bil { int i00,i01,i10,i11; float w00,w01,w10,w11; };

__device__ inline Bil bilin(float sx, float sy) {
    float x0f = floorf(sx), y0f = floorf(sy);
    float wx1 = sx - x0f, wy1 = sy - y0f;
    float wx0 = 1.f - wx1, wy0 = 1.f - wy1;
    int x0 = (int)x0f, y0 = (int)y0f;
    int x1 = x0 + 1, y1 = y0 + 1;
    bool vx0 = (unsigned)x0 < (unsigned)WW;
    bool vx1 = (unsigned)x1 < (unsigned)WW;
    bool vy0 = (unsigned)y0 < (unsigned)HH;
    bool vy1 = (unsigned)y1 < (unsigned)HH;
    int x0c = min(max(x0,0),WW-1), x1c = min(max(x1,0),WW-1);
    int y0c = min(max(y0,0),HH-1), y1c = min(max(y1,0),HH-1);
    Bil b;
    b.i00 = y0c*WW + x0c; b.i01 = y0c*WW + x1c;
    b.i10 = y1c*WW + x0c; b.i11 = y1c*WW + x1c;
    b.w00 = wx0*wy0*((vx0&&vy0)?1.f:0.f);
    b.w01 = wx1*wy0*((vx1&&vy0)?1.f:0.f);
    b.w10 = wx0*wy1*((vx0&&vy1)?1.f:0.f);
    b.w11 = wx1*wy1*((vx1&&vy1)?1.f:0.f);
    return b;
}

__device__ inline unsigned short f2bf(float f) {
    unsigned u = __float_as_uint(f);
    unsigned r = (u + 0x7fffu + ((u >> 16) & 1u)) >> 16;
    return (unsigned short)r;
}
__device__ inline unsigned cvt_pk_bf16(float lo, float hi) {
    unsigned r;
    asm("v_cvt_pk_bf16_f32 %0, %1, %2" : "=v"(r) : "v"(lo), "v"(hi));
    return r;
}
__device__ inline float bflo(unsigned u) { return __uint_as_float(u << 16); }
__device__ inline float bfhi(unsigned u) { return __uint_as_float(u & 0xFFFF0000u); }

// K0: transpose feat (NCHW f32) -> featT (N,px,c) bf16. grid 8*64 blocks.
__global__ __launch_bounds__(256) void nhwc_kernel(
        const float* __restrict__ feat, unsigned short* __restrict__ featT) {
    __shared__ unsigned short T[64*TLD];   // 34 KB
    int b = blockIdx.x >> 6, p0 = (blockIdx.x & 63)*64;
    int t = threadIdx.x;
    int x = t & 63, c4 = t >> 6;
    const float* fb = feat + (size_t)b*CC*HW + p0;
    #pragma unroll 4
    for (int cp = 0; cp < 256; cp += 4) {
        int c = cp + c4;
        T[x*TLD + c] = f2bf(fb[(size_t)c*HW + x]);
    }
    __syncthreads();
    int xq = t >> 5, cl = t & 31;
    unsigned short* dst = featT + ((size_t)b*HW + p0)*256;
    #pragma unroll
    for (int w = 0; w < 8; w++) {
        int xr = w*8 + xq;
        *(uint4*)(dst + (size_t)xr*256 + cl*8) = *(const uint4*)(T + xr*TLD + cl*8);
    }
}

// K1a: pack dcn_off_w into MFMA A-fragment order, bf16.
__global__ void cpack_kernel(const float* __restrict__ w, short* __restrict__ Ap) {
    int idx = blockIdx.x*256 + threadIdx.x;   // 9*2*8*64 = 9216
    if (idx >= 9*2*8*64) return;
    int l  = idx & 63;
    int cs = (idx >> 6) & 7;
    int mt = (idx >> 9) & 1;
    int k  = idx >> 10;
    int oc = mt*16 + (l & 15);
    int c0 = cs*32 + (l >> 4)*8;
    short* dst = Ap + (size_t)idx*8;
    #pragma unroll
    for (int i = 0; i < 8; i++) {
        float v = (oc < 27) ? w[((size_t)(oc*256 + c0 + i)*3 + k/3)*3 + (k % 3)] : 0.f;
        dst[i] = (short)f2bf(v);
    }
}

// K1: 3x3 conv featT -> off27 via MFMA on a 3-row strip.
__global__ __launch_bounds__(256, 3) void conv3x3_kernel(
        const unsigned short* __restrict__ featT, const short* __restrict__ Ap,
        const float* __restrict__ bias, float* __restrict__ off27) {
    __shared__ __align__(16) short S[3*66*CST];   // 52.6 KB
    int orig = blockIdx.x;                        // 512 blocks
    int blk = (orig & 7)*64 + (orig >> 3);        // XCD swizzle
    int b = blk >> 6, row = blk & 63;
    int t = threadIdx.x;
    int l = t & 63, wv = t >> 6;

    f32x4 acc[2];
    acc[0] = (f32x4){0.f,0.f,0.f,0.f};
    acc[1] = (f32x4){0.f,0.f,0.f,0.f};
    const unsigned short* fb = featT + (size_t)b*HW*256;

    for (int ch = 0; ch < 2; ch++) {
        for (int i = t; i < 3*66*16; i += 256) {
            int cc = i & 15;
            int rp = i >> 4;
            int r = rp / 66, px_s = rp - r*66;
            int yy = row + r - 1;
            int xx = px_s - 1;
            uint4 v = (uint4){0u,0u,0u,0u};
            if ((unsigned)yy < 64u && (unsigned)xx < 64u)
                v = *(const uint4*)(fb + ((size_t)(yy*64 + xx))*256 + ch*128 + cc*8);
            *(uint4*)(&S[(r*66 + px_s)*CST + cc*8]) = v;
        }
        __syncthreads();
        #pragma unroll
        for (int k = 0; k < 9; k++) {
            int ky = k/3, kx = k%3;
            const short* srow = S + (ky*66 + wv*16 + (l & 15) + kx)*CST + (l >> 4)*8;
            #pragma unroll
            for (int csl = 0; csl < 4; csl++) {
                bf16x8 bfrag = *(const bf16x8*)(srow + csl*32);
                int cs = ch*4 + csl;
                const short* ap = Ap + ((size_t)((k*2)*8 + cs)*64 + l)*8;
                bf16x8 a0 = *(const bf16x8*)ap;
                bf16x8 a1 = *(const bf16x8*)(ap + 8*64*8);
                acc[0] = __builtin_amdgcn_mfma_f32_16x16x32_bf16(a0, bfrag, acc[0], 0, 0, 0);
                acc[1] = __builtin_amdgcn_mfma_f32_16x16x32_bf16(a1, bfrag, acc[1], 0, 0, 0);
            }
        }
        __syncthreads();
    }
    #pragma unroll
    for (int mt = 0; mt < 2; mt++)
        #pragma unroll
        for (int r = 0; r < 4; r++) {
            int oc = mt*16 + (l >> 4)*4 + r;
            if (oc < 27)
                off27[((size_t)(b*27 + oc))*HW + row*64 + wv*16 + (l & 15)]
                    = acc[mt][r] + bias[oc];
        }
}

// K1b: pack dcn_w into MFMA fragment order, bf16 (used as A operand now).
__global__ void wpack_kernel(const float* __restrict__ w, short* __restrict__ Wp) {
    int idx = blockIdx.x*256 + threadIdx.x;   // 9*8*16*64 = 73728
    if (idx >= 9*8*16*64) return;
    int l  = idx & 63;
    int ot = (idx >> 6) & 15;
    int cs = (idx >> 10) & 7;
    int k  = idx >> 13;
    int oc = ot*16 + (l & 15);
    int c0 = cs*32 + (l >> 4)*8;
    short* dst = Wp + (size_t)idx*8;
    #pragma unroll
    for (int i = 0; i < 8; i++) {
        float v = w[((size_t)(oc*256 + c0 + i)*3 + k/3)*3 + (k % 3)];
        dst[i] = (short)f2bf(v);
    }
}

// K1c: pack the four 1x1-conv weights into MFMA A-fragment order (320 oc).
__global__ void wpack4_kernel(const float* __restrict__ so_w, const float* __restrict__ sc_w,
        const float* __restrict__ uw_w, const float* __restrict__ uo_w,
        short* __restrict__ Wc) {
    int idx = blockIdx.x*256 + threadIdx.x;   // 8*20*64 = 10240
    if (idx >= 8*20*64) return;
    int l  = idx & 63;
    int ot = (idx >> 6) % 20;
    int cs = idx / (64*20);
    int g  = ot*16 + (l & 15);
    int c0 = cs*32 + (l >> 4)*8;
    const float* src = nullptr; int oc = 0;
    if (g < 136)      { src = so_w; oc = g; }
    else if (g < 187) { src = sc_w; oc = g - 136; }
    else if (g < 238) { src = uw_w; oc = g - 187; }
    else if (g < 289) { src = uo_w; oc = g - 238; }
    short* dst = Wc + (size_t)idx*8;
    #pragma unroll
    for (int i = 0; i < 8; i++)
        dst[i] = src ? (short)f2bf(src[(size_t)oc*256 + c0 + i]) : (short)0;
}

// K2: fused DCNv2. BM=64 px (one row), 512 thr / 8 waves, grid 512.
// A=weights (M=oc), B=samples (N=px) -> D col = px, direct coalesced store.
__global__ __launch_bounds__(512, 4) void dcn_kernel(
        const unsigned short* __restrict__ featT, const float* __restrict__ off27,
        const short* __restrict__ Wp, float* __restrict__ dcn_out) {
    __shared__ __align__(16) short S[64*SLD];   // 33.8 KB

    int orig = blockIdx.x;                 // 512 blocks
    int blk  = (orig & 7)*64 + (orig >> 3);   // XCD swizzle: xcd == batch
    int b   = blk >> 6;
    int row = blk & 63;

    int t   = threadIdx.x;
    int pxh = t >> 4;          // 0..31
    int cl  = t & 15;          // c-chunk (8 ch)
    int l   = t & 63, wv = t >> 6;   // 8 waves: wv owns oc [wv*32, wv*32+32)

    f32x4 acc[2][4];
    #pragma unroll
    for (int i = 0; i < 2; i++)
        #pragma unroll
        for (int j = 0; j < 4; j++) acc[i][j] = (f32x4){0.f,0.f,0.f,0.f};

    const unsigned short* fT = featT + (size_t)b*HW*256;
    const float* offb = off27 + (size_t)b*27*HW;

    for (int k = 0; k < 9; k++) {
        int kx = k % 3 - 1, ky = k / 3 - 1;
        #pragma unroll
        for (int pp = 0; pp < 2; pp++) {       // px pass: 32 px each
            int px = pp*32 + pxh;
            int p  = row*64 + px;
            float dyv = offb[(size_t)k*HW + p];
            float dxv = offb[(size_t)(9 + k)*HW + p];
            float mk  = offb[(size_t)(18 + k)*HW + p];
            float m = 1.f/(1.f + expf(-mk));
            Bil bl = bilin((float)(px + kx) + dxv, (float)(row + ky) + dyv);
            float w00 = bl.w00*m, w01 = bl.w01*m, w10 = bl.w10*m, w11 = bl.w11*m;
            #pragma unroll
            for (int cp = 0; cp < 2; cp++) {   // c pass: 128 ch each
                int c0 = cp*128 + cl*8;
                uint4 u00 = *(const uint4*)(fT + (size_t)bl.i00*256 + c0);
                uint4 u01 = *(const uint4*)(fT + (size_t)bl.i01*256 + c0);
                uint4 u10 = *(const uint4*)(fT + (size_t)bl.i10*256 + c0);
                uint4 u11 = *(const uint4*)(fT + (size_t)bl.i11*256 + c0);
                const unsigned* a00 = (const unsigned*)&u00;
                const unsigned* a01 = (const unsigned*)&u01;
                const unsigned* a10 = (const unsigned*)&u10;
                const unsigned* a11 = (const unsigned*)&u11;
                uint4 outp;
                unsigned* op = (unsigned*)&outp;
                #pragma unroll
                for (int q = 0; q < 4; q++) {
                    float vlo = w00*bflo(a00[q]) + w01*bflo(a01[q])
                              + w10*bflo(a10[q]) + w11*bflo(a11[q]);
                    float vhi = w00*bfhi(a00[q]) + w01*bfhi(a01[q])
                              + w10*bfhi(a10[q]) + w11*bfhi(a11[q]);
                    op[q] = cvt_pk_bf16(vlo, vhi);
                }
                *(uint4*)(S + px*SLD + c0) = outp;
            }
        }
        __syncthreads();

        const short* wpk = Wp + (size_t)k*8*16*64*8;
        for (int cs = 0; cs < 8; cs++) {
            bf16x8 wa[2];
            #pragma unroll
            for (int mt = 0; mt < 2; mt++)
                wa[mt] = *(const bf16x8*)(wpk + ((size_t)((cs*16 + (wv*2 + mt))*64 + l))*8);
            bf16x8 sb[4];
            #pragma unroll
            for (int pt = 0; pt < 4; pt++)
                sb[pt] = *(const bf16x8*)(S + (pt*16 + (l & 15))*SLD
                                            + cs*32 + (l >> 4)*8);
            #pragma unroll
            for (int mt = 0; mt < 2; mt++)
                #pragma unroll
                for (int pt = 0; pt < 4; pt++)
                    acc[mt][pt] = __builtin_amdgcn_mfma_f32_16x16x32_bf16(
                        wa[mt], sb[pt], acc[mt][pt], 0, 0, 0);
        }
        __syncthreads();
    }

    // direct store: col(l&15)=px, row=(l>>4)*4+r=oc-in-tile
    #pragma unroll
    for (int mt = 0; mt < 2; mt++)
        #pragma unroll
        for (int pt = 0; pt < 4; pt++)
            #pragma unroll
            for (int r = 0; r < 4; r++) {
                int oc = wv*32 + mt*16 + (l >> 4)*4 + r;
                int px = pt*16 + (l & 15);
                dcn_out[((size_t)(b*256 + oc))*HW + row*64 + px] = acc[mt][pt][r];
            }
}

// K3: GroupNorm partial sums: 1024 blocks, 2 channels each.
__global__ __launch_bounds__(256) void gn_partial_kernel(
        const float* __restrict__ dcn, float* __restrict__ partial) {
    int blk = blockIdx.x;                 // (b*32+g)*4 + sub
    const float4* base = (const float4*)(dcn + (size_t)blk*2*HW);
    float s = 0.f, s2 = 0.f;
    #pragma unroll
    for (int j = 0; j < 8; j++) {
        float4 v = base[threadIdx.x + j*256];
        s  += v.x + v.y + v.z + v.w;
        s2 += v.x*v.x + v.y*v.y + v.z*v.z + v.w*v.w;
    }
    __shared__ float rs[256], rs2[256];
    rs[threadIdx.x] = s; rs2[threadIdx.x] = s2; __syncthreads();
    for (int o = 128; o > 0; o >>= 1) {
        if (threadIdx.x < o) { rs[threadIdx.x] += rs[threadIdx.x+o]; rs2[threadIdx.x] += rs2[threadIdx.x+o]; }
        __syncthreads();
    }
    if (threadIdx.x == 0) { partial[blk*2] = rs[0]; partial[blk*2+1] = rs2[0]; }
}

// K5: fused GN-apply + residual (-> out_feat) + 1x1 convs + offset blend (-> uvd).
__global__ __launch_bounds__(256, 2) void fused_tail_kernel(
        const float* __restrict__ feat, const float* __restrict__ dcn,
        const float* __restrict__ partial, const float* __restrict__ gn_g,
        const float* __restrict__ gn_b, const short* __restrict__ Wc,
        const float* __restrict__ so_b, const float* __restrict__ sc_b,
        const float* __restrict__ uw_b, const float* __restrict__ uo_b,
        const float* __restrict__ prev_off,
        float* __restrict__ out_feat, float* __restrict__ samp_off,
        float* __restrict__ samp_conf, float* __restrict__ uvd) {
    __shared__ __align__(16) short S[64*SLD];   // 33.8 KB; overlaid by U after GEMM
    __shared__ float gstat[32][2];
    float* U = (float*)S;                       // [102][64] floats (26.1 KB)

    int orig = blockIdx.x;                      // 512 blocks
    int blk = (orig & 7)*64 + (orig >> 3);      // XCD swizzle
    int b = blk >> 6, row = blk & 63;
    int t = threadIdx.x;

    if (t < 32) {
        const float* pp = partial + (size_t)(b*32 + t)*8;
        float s  = pp[0] + pp[2] + pp[4] + pp[6];
        float s2 = pp[1] + pp[3] + pp[5] + pp[7];
        float inv = 1.f/(8.f*HW);
        float mu = s*inv;
        float var = s2*inv - mu*mu;
        gstat[t][0] = mu;
        gstat[t][1] = rsqrtf(var + 1e-5f);
    }
    __syncthreads();

    int x = t & 63, cq = t >> 6;
    int l = t & 63, wv = t >> 6;
    const float* fb = feat + (size_t)b*CC*HW + row*64;
    const float* db = dcn  + (size_t)b*CC*HW + row*64;
    float* ob = out_feat + (size_t)b*CC*HW + row*64;
    #pragma unroll
    for (int j = 0; j < 16; j++) {
        int c0 = cq*64 + j*4;
        float fv[4];
        #pragma unroll
        for (int q = 0; q < 4; q++) {
            int c = c0 + q;
            float mu = gstat[c >> 3][0], rstd = gstat[c >> 3][1];
            float v = (db[(size_t)c*HW + x] - mu)*rstd*gn_g[c] + gn_b[c];
            fv[q] = fb[(size_t)c*HW + x] + fmaxf(v, 0.f);
            ob[(size_t)c*HW + x] = fv[q];
        }
        uint2 pk;
        pk.x = cvt_pk_bf16(fv[0], fv[1]);
        pk.y = cvt_pk_bf16(fv[2], fv[3]);
        *(uint2*)(S + x*SLD + c0) = pk;
    }
    __syncthreads();

    f32x4 acc[5][4];
    #pragma unroll
    for (int j = 0; j < 5; j++)
        #pragma unroll
        for (int pt = 0; pt < 4; pt++) acc[j][pt] = (f32x4){0.f,0.f,0.f,0.f};

    for (int cs = 0; cs < 8; cs++) {
        bf16x8 bg[4];
        #pragma unroll
        for (int pt = 0; pt < 4; pt++)
            bg[pt] = *(const bf16x8*)(S + (pt*16 + (l & 15))*SLD
                                        + cs*32 + (l >> 4)*8);
        #pragma unroll
        for (int j = 0; j < 5; j++) {
            bf16x8 a = *(const bf16x8*)(Wc + ((size_t)(cs*20 + wv*5 + j)*64 + l)*8);
            #pragma unroll
            for (int pt = 0; pt < 4; pt++)
                acc[j][pt] = __builtin_amdgcn_mfma_f32_16x16x32_bf16(
                    a, bg[pt], acc[j][pt], 0, 0, 0);
        }
    }
    __syncthreads();   // S dead; U live

    #pragma unroll
    for (int j = 0; j < 5; j++) {
        #pragma unroll
        for (int pt = 0; pt < 4; pt++) {
            int px = pt*16 + (l & 15);
            int p = row*64 + px;
            #pragma unroll
            for (int r = 0; r < 4; r++) {
                int oc = (wv*5 + j)*16 + (l >> 4)*4 + r;
                float v = acc[j][pt][r];
                if (oc < 136)
                    samp_off[((size_t)(b*136 + oc))*HW + p] = v + so_b[oc];
                else if (oc < 187)
                    samp_conf[((size_t)(b*51 + oc-136))*HW + p] = v + sc_b[oc-136];
                else if (oc < 238)
                    U[(oc-187)*64 + px] = v + uw_b[oc-187];
                else if (oc < 289)
                    U[(51 + oc-238)*64 + px] = v + uo_b[oc-238];
            }
        }
    }
    __syncthreads();

    const float* pb = prev_off + (size_t)b*51*HW + row*64;
    float* ub = uvd + (size_t)b*51*HW + row*64;
    for (int i = t; i < 51*64; i += 256) {
        int d = i >> 6, px = i & 63;
        float owv = 1.f/(1.f + expf(-U[d*64 + px]));
        ub[(size_t)d*HW + px] = (1.f - owv)*pb[(size_t)d*HW + px] + owv*U[(51 + d)*64 + px];
    }
}

// K7: fused sampling + softmax-weighted sum -> new_off (output 1)
__global__ __launch_bounds__(256) void final_kernel(
        const float* __restrict__ uvd, const float* __restrict__ sconf,
        const float* __restrict__ soff, float* __restrict__ out_off) {
    int bj = blockIdx.x;            // 0..135
    int b = bj / JJ, j = bj % JJ;
    int p = blockIdx.y*256 + threadIdx.x;
    int y = p >> 6, x = p & 63;
    const float* u0 = uvd   + ((size_t)b*51  + j*3)*HW;
    const float* c0 = sconf + ((size_t)b*51  + j*3)*HW;
    const float* s0 = soff  + ((size_t)b*136 + j*8)*HW;
    float offx = u0[p], offy = u0[HW+p];
    Bil bl = bilin((float)x + offx, (float)y + offy);
    float sall[8][2];
    #pragma unroll
    for (int h = 0; h < 4; h++) {
        const float* se = s0 + (size_t)(2*h)*HW;
        const float* so2 = s0 + (size_t)(2*h+1)*HW;
        sall[h][0] = bl.w00*se[bl.i00]+bl.w01*se[bl.i01]+bl.w10*se[bl.i10]+bl.w11*se[bl.i11] + offx;
        sall[h][1] = bl.w00*so2[bl.i00]+bl.w01*so2[bl.i01]+bl.w10*so2[bl.i10]+bl.w11*so2[bl.i11] + offy;
        sall[4+h][0] = se[p];
        sall[4+h][1] = so2[p];
    }
    float sv[8][3], lg[8][3];
    #pragma unroll
    for (int n = 0; n < 8; n++) {
        Bil b2 = bilin((float)x + sall[n][0], (float)y + sall[n][1]);
        #pragma unroll
        for (int d = 0; d < 3; d++) {
            const float* ud = u0 + (size_t)d*HW;
            const float* cd = c0 + (size_t)d*HW;
            sv[n][d] = b2.w00*ud[b2.i00]+b2.w01*ud[b2.i01]+b2.w10*ud[b2.i10]+b2.w11*ud[b2.i11];
            lg[n][d] = b2.w00*cd[b2.i00]+b2.w01*cd[b2.i01]+b2.w10*cd[b2.i10]+b2.w11*cd[b2.i11];
        }
        sv[n][0] += sall[n][0];
        sv[n][1] += sall[n][1];
    }
    #pragma unroll
    for (int d = 0; d < 3; d++) {
        float m = lg[0][d];
        #pragma unroll
        for (int n = 1; n < 8; n++) m = fmaxf(m, lg[n][d]);
        float den = 0.f, num = 0.f;
        #pragma unroll
        for (int n = 0; n < 8; n++) {
            float e = expf(lg[n][d]-m);
            den += e; num += e*sv[n][d];
        }
        out_off[((size_t)b*51 + j*3 + d)*HW + p] = num/den;
    }
}

extern "C" void kernel_launch(void* const* d_in, const int* in_sizes, int n_in,
                              void* d_out, int out_size, void* d_ws, size_t ws_size,
                              hipStream_t stream) {
    const float* feat       = (const float*)d_in[0];
    const float* prev_off   = (const float*)d_in[1];
    const float* dcn_off_w  = (const float*)d_in[2];
    const float* dcn_off_b  = (const float*)d_in[3];
    const float* dcn_w      = (const float*)d_in[4];
    const float* gn_g       = (const float*)d_in[5];
    const float* gn_b       = (const float*)d_in[6];
    const float* so_w       = (const float*)d_in[7];
    const float* so_b       = (const float*)d_in[8];
    const float* sc_w       = (const float*)d_in[9];
    const float* sc_b       = (const float*)d_in[10];
    const float* uw_w       = (const float*)d_in[11];
    const float* uw_b       = (const float*)d_in[12];
    const float* uo_w       = (const float*)d_in[13];
    const float* uo_b       = (const float*)d_in[14];

    float* ws = (float*)d_ws;
    float* off27     = ws;                       // 884736 floats
    float* Wt        = off27 + 884736;           // pack region
    short* Wp        = (short*)Wt;               // 589824 shorts (dcn weights)
    short* Ap        = Wp + 589824;              // 73728 shorts (conv3x3 weights)
    short* Wc        = Ap + 73728;               // 81920 shorts (1x1 weights)
    float* dcn       = Wt + 589824;              // 8388608
    float* partial   = dcn + 8388608;            // 2048
    float* samp_off  = partial + 2048;           // 4456448
    float* samp_conf = samp_off + 4456448;       // 1671168
    float* uvd       = samp_conf + 1671168;      // 1671168

    // featT (8.4M ushorts = 16.8 MB) aliases samp_off (17.8 MB):
    // dead after dcn_kernel; samp_off written later by fused_tail.
    unsigned short* featT = (unsigned short*)samp_off;

    float* out_feat = (float*)d_out;             // 8388608
    float* out_off  = out_feat + 8388608;        // 1671168

    // K0: NCHW f32 -> NHWC bf16 transpose
    nhwc_kernel<<<dim3(BB*64), dim3(256), 0, stream>>>(feat, featT);
    // packs
    cpack_kernel<<<dim3(36), dim3(256), 0, stream>>>(dcn_off_w, Ap);
    wpack_kernel<<<dim3(288), dim3(256), 0, stream>>>(dcn_w, Wp);
    wpack4_kernel<<<dim3(40), dim3(256), 0, stream>>>(so_w, sc_w, uw_w, uo_w, Wc);
    // K1: offset conv (3x3, MFMA)
    conv3x3_kernel<<<dim3(BB*64), dim3(256), 0, stream>>>(featT, Ap, dcn_off_b, off27);
    // K2: DCN (MFMA, 64px/512thr blocks, direct store)
    dcn_kernel<<<dim3(BB*64), dim3(512), 0, stream>>>(featT, off27, Wp, dcn);
    // K3: GroupNorm partials
    gn_partial_kernel<<<dim3(1024), dim3(256), 0, stream>>>(dcn, partial);
    // K5: fused GN + residual + 1x1 convs + offset blend
    fused_tail_kernel<<<dim3(512), dim3(256), 0, stream>>>(feat, dcn, partial,
        gn_g, gn_b, Wc, so_b, sc_b, uw_b, uo_b, prev_off,
        out_feat, samp_off, samp_conf, uvd);
    // K7: fused double grid-sample + softmax reduction
    final_kernel<<<dim3(BB*JJ, 16), dim3(256), 0, stream>>>(uvd, samp_conf, samp_off, out_off);
}

// Round 7
// 219.348 us; speedup vs baseline: 5.7355x; 1.1758x over previous
//
#include <hip/hip_runtime.h>
#include <hip/hip_bf16.h>
#include <math.h>

// Problem constants: B=8, C=256, H=W=64, J=17, Hd=4, dim=3
#define HH 64
#define WW 64
#define HW 4096
#define CC 256
#define BB 8
#define JJ 17

typedef __attribute__((ext_vector_type(8))) short bf16x8;
typedef __attribute__((ext_vector_type(4))) float f32x4;

#define SLD 264    // padded LDS row stride in shorts
#define CST 136    // conv3x3: strip c-stride in shorts (128 c + 8 pad)
#define TLD 266    // transpose LDS stride in shorts

struct Bil { int i00,i01,i10,i11; float w00,w01,w10,w11; };

__device__ inline Bil bilin(float sx, float sy) {
    float x0f = floorf(sx), y0f = floorf(sy);
    float wx1 = sx - x0f, wy1 = sy - y0f;
    float wx0 = 1.f - wx1, wy0 = 1.f - wy1;
    int x0 = (int)x0f, y0 = (int)y0f;
    int x1 = x0 + 1, y1 = y0 + 1;
    bool vx0 = (unsigned)x0 < (unsigned)WW;
    bool vx1 = (unsigned)x1 < (unsigned)WW;
    bool vy0 = (unsigned)y0 < (unsigned)HH;
    bool vy1 = (unsigned)y1 < (unsigned)HH;
    int x0c = min(max(x0,0),WW-1), x1c = min(max(x1,0),WW-1);
    int y0c = min(max(y0,0),HH-1), y1c = min(max(y1,0),HH-1);
    Bil b;
    b.i00 = y0c*WW + x0c; b.i01 = y0c*WW + x1c;
    b.i10 = y1c*WW + x0c; b.i11 = y1c*WW + x1c;
    b.w00 = wx0*wy0*((vx0&&vy0)?1.f:0.f);
    b.w01 = wx1*wy0*((vx1&&vy0)?1.f:0.f);
    b.w10 = wx0*wy1*((vx0&&vy1)?1.f:0.f);
    b.w11 = wx1*wy1*((vx1&&vy1)?1.f:0.f);
    return b;
}

__device__ inline unsigned short f2bf(float f) {
    unsigned u = __float_as_uint(f);
    unsigned r = (u + 0x7fffu + ((u >> 16) & 1u)) >> 16;
    return (unsigned short)r;
}
__device__ inline unsigned cvt_pk_bf16(float lo, float hi) {
    unsigned r;
    asm("v_cvt_pk_bf16_f32 %0, %1, %2" : "=v"(r) : "v"(lo), "v"(hi));
    return r;
}
__device__ inline float bflo(unsigned u) { return __uint_as_float(u << 16); }
__device__ inline float bfhi(unsigned u) { return __uint_as_float(u & 0xFFFF0000u); }

// K0: transpose feat (NCHW f32) -> featT (N,px,c) bf16. grid 8*64 blocks.
__global__ __launch_bounds__(256) void nhwc_kernel(
        const float* __restrict__ feat, unsigned short* __restrict__ featT) {
    __shared__ unsigned short T[64*TLD];   // 34 KB
    int b = blockIdx.x >> 6, p0 = (blockIdx.x & 63)*64;
    int t = threadIdx.x;
    int x = t & 63, c4 = t >> 6;
    const float* fb = feat + (size_t)b*CC*HW + p0;
    #pragma unroll 4
    for (int cp = 0; cp < 256; cp += 4) {
        int c = cp + c4;
        T[x*TLD + c] = f2bf(fb[(size_t)c*HW + x]);
    }
    __syncthreads();
    int xq = t >> 5, cl = t & 31;
    unsigned short* dst = featT + ((size_t)b*HW + p0)*256;
    #pragma unroll
    for (int w = 0; w < 8; w++) {
        int xr = w*8 + xq;
        *(uint4*)(dst + (size_t)xr*256 + cl*8) = *(const uint4*)(T + xr*TLD + cl*8);
    }
}

// K1a: pack dcn_off_w into MFMA A-fragment order, bf16.
__global__ void cpack_kernel(const float* __restrict__ w, short* __restrict__ Ap) {
    int idx = blockIdx.x*256 + threadIdx.x;   // 9*2*8*64 = 9216
    if (idx >= 9*2*8*64) return;
    int l  = idx & 63;
    int cs = (idx >> 6) & 7;
    int mt = (idx >> 9) & 1;
    int k  = idx >> 10;
    int oc = mt*16 + (l & 15);
    int c0 = cs*32 + (l >> 4)*8;
    short* dst = Ap + (size_t)idx*8;
    #pragma unroll
    for (int i = 0; i < 8; i++) {
        float v = (oc < 27) ? w[((size_t)(oc*256 + c0 + i)*3 + k/3)*3 + (k % 3)] : 0.f;
        dst[i] = (short)f2bf(v);
    }
}

// K1: 3x3 conv featT -> off27 via MFMA on a 3-row strip.
__global__ __launch_bounds__(256, 3) void conv3x3_kernel(
        const unsigned short* __restrict__ featT, const short* __restrict__ Ap,
        const float* __restrict__ bias, float* __restrict__ off27) {
    __shared__ __align__(16) short S[3*66*CST];   // 52.6 KB
    int orig = blockIdx.x;                        // 512 blocks
    int blk = (orig & 7)*64 + (orig >> 3);        // XCD swizzle
    int b = blk >> 6, row = blk & 63;
    int t = threadIdx.x;
    int l = t & 63, wv = t >> 6;

    f32x4 acc[2];
    acc[0] = (f32x4){0.f,0.f,0.f,0.f};
    acc[1] = (f32x4){0.f,0.f,0.f,0.f};
    const unsigned short* fb = featT + (size_t)b*HW*256;

    for (int ch = 0; ch < 2; ch++) {
        for (int i = t; i < 3*66*16; i += 256) {
            int cc = i & 15;
            int rp = i >> 4;
            int r = rp / 66, px_s = rp - r*66;
            int yy = row + r - 1;
            int xx = px_s - 1;
            uint4 v = (uint4){0u,0u,0u,0u};
            if ((unsigned)yy < 64u && (unsigned)xx < 64u)
                v = *(const uint4*)(fb + ((size_t)(yy*64 + xx))*256 + ch*128 + cc*8);
            *(uint4*)(&S[(r*66 + px_s)*CST + cc*8]) = v;
        }
        __syncthreads();
        #pragma unroll
        for (int k = 0; k < 9; k++) {
            int ky = k/3, kx = k%3;
            const short* srow = S + (ky*66 + wv*16 + (l & 15) + kx)*CST + (l >> 4)*8;
            #pragma unroll
            for (int csl = 0; csl < 4; csl++) {
                bf16x8 bfrag = *(const bf16x8*)(srow + csl*32);
                int cs = ch*4 + csl;
                const short* ap = Ap + ((size_t)((k*2)*8 + cs)*64 + l)*8;
                bf16x8 a0 = *(const bf16x8*)ap;
                bf16x8 a1 = *(const bf16x8*)(ap + 8*64*8);
                acc[0] = __builtin_amdgcn_mfma_f32_16x16x32_bf16(a0, bfrag, acc[0], 0, 0, 0);
                acc[1] = __builtin_amdgcn_mfma_f32_16x16x32_bf16(a1, bfrag, acc[1], 0, 0, 0);
            }
        }
        __syncthreads();
    }
    #pragma unroll
    for (int mt = 0; mt < 2; mt++)
        #pragma unroll
        for (int r = 0; r < 4; r++) {
            int oc = mt*16 + (l >> 4)*4 + r;
            if (oc < 27)
                off27[((size_t)(b*27 + oc))*HW + row*64 + wv*16 + (l & 15)]
                    = acc[mt][r] + bias[oc];
        }
}

// K1b: pack dcn_w into MFMA fragment order, bf16 (A operand).
__global__ void wpack_kernel(const float* __restrict__ w, short* __restrict__ Wp) {
    int idx = blockIdx.x*256 + threadIdx.x;   // 9*8*16*64 = 73728
    if (idx >= 9*8*16*64) return;
    int l  = idx & 63;
    int ot = (idx >> 6) & 15;
    int cs = (idx >> 10) & 7;
    int k  = idx >> 13;
    int oc = ot*16 + (l & 15);
    int c0 = cs*32 + (l >> 4)*8;
    short* dst = Wp + (size_t)idx*8;
    #pragma unroll
    for (int i = 0; i < 8; i++) {
        float v = w[((size_t)(oc*256 + c0 + i)*3 + k/3)*3 + (k % 3)];
        dst[i] = (short)f2bf(v);
    }
}

// K1c: pack the four 1x1-conv weights into MFMA A-fragment order (320 oc).
__global__ void wpack4_kernel(const float* __restrict__ so_w, const float* __restrict__ sc_w,
        const float* __restrict__ uw_w, const float* __restrict__ uo_w,
        short* __restrict__ Wc) {
    int idx = blockIdx.x*256 + threadIdx.x;   // 8*20*64 = 10240
    if (idx >= 8*20*64) return;
    int l  = idx & 63;
    int ot = (idx >> 6) % 20;
    int cs = idx / (64*20);
    int g  = ot*16 + (l & 15);
    int c0 = cs*32 + (l >> 4)*8;
    const float* src = nullptr; int oc = 0;
    if (g < 136)      { src = so_w; oc = g; }
    else if (g < 187) { src = sc_w; oc = g - 136; }
    else if (g < 238) { src = uw_w; oc = g - 187; }
    else if (g < 289) { src = uo_w; oc = g - 238; }
    short* dst = Wc + (size_t)idx*8;
    #pragma unroll
    for (int i = 0; i < 8; i++)
        dst[i] = src ? (short)f2bf(src[(size_t)oc*256 + c0 + i]) : (short)0;
}

// K2: fused DCNv2. BM=64 px (one row), 512 thr / 8 waves, grid 512.
__global__ __launch_bounds__(512, 4) void dcn_kernel(
        const unsigned short* __restrict__ featT, const float* __restrict__ off27,
        const short* __restrict__ Wp, float* __restrict__ dcn_out) {
    __shared__ __align__(16) short S[64*SLD];   // 33.8 KB

    int orig = blockIdx.x;                 // 512 blocks
    int blk  = (orig & 7)*64 + (orig >> 3);   // XCD swizzle: xcd == batch
    int b   = blk >> 6;
    int row = blk & 63;

    int t   = threadIdx.x;
    int pxh = t >> 4;          // 0..31
    int cl  = t & 15;          // c-chunk (8 ch)
    int l   = t & 63, wv = t >> 6;

    f32x4 acc[2][4];
    #pragma unroll
    for (int i = 0; i < 2; i++)
        #pragma unroll
        for (int j = 0; j < 4; j++) acc[i][j] = (f32x4){0.f,0.f,0.f,0.f};

    const unsigned short* fT = featT + (size_t)b*HW*256;
    const float* offb = off27 + (size_t)b*27*HW;

    for (int k = 0; k < 9; k++) {
        int kx = k % 3 - 1, ky = k / 3 - 1;
        #pragma unroll
        for (int pp = 0; pp < 2; pp++) {
            int px = pp*32 + pxh;
            int p  = row*64 + px;
            float dyv = offb[(size_t)k*HW + p];
            float dxv = offb[(size_t)(9 + k)*HW + p];
            float mk  = offb[(size_t)(18 + k)*HW + p];
            float m = 1.f/(1.f + expf(-mk));
            Bil bl = bilin((float)(px + kx) + dxv, (float)(row + ky) + dyv);
            float w00 = bl.w00*m, w01 = bl.w01*m, w10 = bl.w10*m, w11 = bl.w11*m;
            #pragma unroll
            for (int cp = 0; cp < 2; cp++) {
                int c0 = cp*128 + cl*8;
                uint4 u00 = *(const uint4*)(fT + (size_t)bl.i00*256 + c0);
                uint4 u01 = *(const uint4*)(fT + (size_t)bl.i01*256 + c0);
                uint4 u10 = *(const uint4*)(fT + (size_t)bl.i10*256 + c0);
                uint4 u11 = *(const uint4*)(fT + (size_t)bl.i11*256 + c0);
                const unsigned* a00 = (const unsigned*)&u00;
                const unsigned* a01 = (const unsigned*)&u01;
                const unsigned* a10 = (const unsigned*)&u10;
                const unsigned* a11 = (const unsigned*)&u11;
                uint4 outp;
                unsigned* op = (unsigned*)&outp;
                #pragma unroll
                for (int q = 0; q < 4; q++) {
                    float vlo = w00*bflo(a00[q]) + w01*bflo(a01[q])
                              + w10*bflo(a10[q]) + w11*bflo(a11[q]);
                    float vhi = w00*bfhi(a00[q]) + w01*bfhi(a01[q])
                              + w10*bfhi(a10[q]) + w11*bfhi(a11[q]);
                    op[q] = cvt_pk_bf16(vlo, vhi);
                }
                *(uint4*)(S + px*SLD + c0) = outp;
            }
        }
        __syncthreads();

        const short* wpk = Wp + (size_t)k*8*16*64*8;
        for (int cs = 0; cs < 8; cs++) {
            bf16x8 wa[2];
            #pragma unroll
            for (int mt = 0; mt < 2; mt++)
                wa[mt] = *(const bf16x8*)(wpk + ((size_t)((cs*16 + (wv*2 + mt))*64 + l))*8);
            bf16x8 sb[4];
            #pragma unroll
            for (int pt = 0; pt < 4; pt++)
                sb[pt] = *(const bf16x8*)(S + (pt*16 + (l & 15))*SLD
                                            + cs*32 + (l >> 4)*8);
            #pragma unroll
            for (int mt = 0; mt < 2; mt++)
                #pragma unroll
                for (int pt = 0; pt < 4; pt++)
                    acc[mt][pt] = __builtin_amdgcn_mfma_f32_16x16x32_bf16(
                        wa[mt], sb[pt], acc[mt][pt], 0, 0, 0);
        }
        __syncthreads();
    }

    #pragma unroll
    for (int mt = 0; mt < 2; mt++)
        #pragma unroll
        for (int pt = 0; pt < 4; pt++)
            #pragma unroll
            for (int r = 0; r < 4; r++) {
                int oc = wv*32 + mt*16 + (l >> 4)*4 + r;
                int px = pt*16 + (l & 15);
                dcn_out[((size_t)(b*256 + oc))*HW + row*64 + px] = acc[mt][pt][r];
            }
}

// K3: GroupNorm partial sums: 1024 blocks, 2 channels each.
__global__ __launch_bounds__(256) void gn_partial_kernel(
        const float* __restrict__ dcn, float* __restrict__ partial) {
    int blk = blockIdx.x;                 // (b*32+g)*4 + sub
    const float4* base = (const float4*)(dcn + (size_t)blk*2*HW);
    float s = 0.f, s2 = 0.f;
    #pragma unroll
    for (int j = 0; j < 8; j++) {
        float4 v = base[threadIdx.x + j*256];
        s  += v.x + v.y + v.z + v.w;
        s2 += v.x*v.x + v.y*v.y + v.z*v.z + v.w*v.w;
    }
    __shared__ float rs[256], rs2[256];
    rs[threadIdx.x] = s; rs2[threadIdx.x] = s2; __syncthreads();
    for (int o = 128; o > 0; o >>= 1) {
        if (threadIdx.x < o) { rs[threadIdx.x] += rs[threadIdx.x+o]; rs2[threadIdx.x] += rs2[threadIdx.x+o]; }
        __syncthreads();
    }
    if (threadIdx.x == 0) { partial[blk*2] = rs[0]; partial[blk*2+1] = rs2[0]; }
}

// K5: fused GN-apply + residual (-> out_feat) + 1x1 convs + offset blend (-> uvd).
// 512 thr / 8 waves, grid 512 -> 16 waves/CU.
__global__ __launch_bounds__(512, 2) void fused_tail_kernel(
        const float* __restrict__ feat, const float* __restrict__ dcn,
        const float* __restrict__ partial, const float* __restrict__ gn_g,
        const float* __restrict__ gn_b, const short* __restrict__ Wc,
        const float* __restrict__ so_b, const float* __restrict__ sc_b,
        const float* __restrict__ uw_b, const float* __restrict__ uo_b,
        const float* __restrict__ prev_off,
        float* __restrict__ out_feat, float* __restrict__ samp_off,
        float* __restrict__ samp_conf, float* __restrict__ uvd) {
    __shared__ __align__(16) short S[64*SLD];   // 33.8 KB; overlaid by U after GEMM
    __shared__ float gstat[32][2];
    float* U = (float*)S;                       // [102][64] floats (26.1 KB)

    int orig = blockIdx.x;                      // 512 blocks
    int blk = (orig & 7)*64 + (orig >> 3);      // XCD swizzle
    int b = blk >> 6, row = blk & 63;
    int t = threadIdx.x;

    if (t < 32) {
        const float* pp = partial + (size_t)(b*32 + t)*8;
        float s  = pp[0] + pp[2] + pp[4] + pp[6];
        float s2 = pp[1] + pp[3] + pp[5] + pp[7];
        float inv = 1.f/(8.f*HW);
        float mu = s*inv;
        float var = s2*inv - mu*mu;
        gstat[t][0] = mu;
        gstat[t][1] = rsqrtf(var + 1e-5f);
    }
    __syncthreads();

    int x = t & 63, cq = t >> 6;                // cq 0..7: 32 channels each
    int l = t & 63, wv = t >> 6;                // 8 waves
    const float* fb = feat + (size_t)b*CC*HW + row*64;
    const float* db = dcn  + (size_t)b*CC*HW + row*64;
    float* ob = out_feat + (size_t)b*CC*HW + row*64;
    #pragma unroll
    for (int j = 0; j < 8; j++) {
        int c0 = cq*32 + j*4;
        float fv[4];
        #pragma unroll
        for (int q = 0; q < 4; q++) {
            int c = c0 + q;
            float mu = gstat[c >> 3][0], rstd = gstat[c >> 3][1];
            float v = (db[(size_t)c*HW + x] - mu)*rstd*gn_g[c] + gn_b[c];
            fv[q] = fb[(size_t)c*HW + x] + fmaxf(v, 0.f);
            ob[(size_t)c*HW + x] = fv[q];
        }
        uint2 pk;
        pk.x = cvt_pk_bf16(fv[0], fv[1]);
        pk.y = cvt_pk_bf16(fv[2], fv[3]);
        *(uint2*)(S + x*SLD + c0) = pk;
    }
    __syncthreads();

    // GEMM: 20 oc-tiles over 8 waves (tiles wv, wv+8, wv+16<20)
    f32x4 acc[3][4];
    #pragma unroll
    for (int j = 0; j < 3; j++)
        #pragma unroll
        for (int pt = 0; pt < 4; pt++) acc[j][pt] = (f32x4){0.f,0.f,0.f,0.f};

    for (int cs = 0; cs < 8; cs++) {
        bf16x8 bg[4];
        #pragma unroll
        for (int pt = 0; pt < 4; pt++)
            bg[pt] = *(const bf16x8*)(S + (pt*16 + (l & 15))*SLD
                                        + cs*32 + (l >> 4)*8);
        #pragma unroll
        for (int j = 0; j < 3; j++) {
            int tile = wv + j*8;
            if (tile < 20) {
                bf16x8 a = *(const bf16x8*)(Wc + ((size_t)(cs*20 + tile)*64 + l)*8);
                #pragma unroll
                for (int pt = 0; pt < 4; pt++)
                    acc[j][pt] = __builtin_amdgcn_mfma_f32_16x16x32_bf16(
                        a, bg[pt], acc[j][pt], 0, 0, 0);
            }
        }
    }
    __syncthreads();   // S dead; U live

    #pragma unroll
    for (int j = 0; j < 3; j++) {
        int tile = wv + j*8;
        if (tile < 20) {
            #pragma unroll
            for (int pt = 0; pt < 4; pt++) {
                int px = pt*16 + (l & 15);
                int p = row*64 + px;
                #pragma unroll
                for (int r = 0; r < 4; r++) {
                    int oc = tile*16 + (l >> 4)*4 + r;
                    float v = acc[j][pt][r];
                    if (oc < 136)
                        samp_off[((size_t)(b*136 + oc))*HW + p] = v + so_b[oc];
                    else if (oc < 187)
                        samp_conf[((size_t)(b*51 + oc-136))*HW + p] = v + sc_b[oc-136];
                    else if (oc < 238)
                        U[(oc-187)*64 + px] = v + uw_b[oc-187];
                    else if (oc < 289)
                        U[(51 + oc-238)*64 + px] = v + uo_b[oc-238];
                }
            }
        }
    }
    __syncthreads();

    const float* pb = prev_off + (size_t)b*51*HW + row*64;
    float* ub = uvd + (size_t)b*51*HW + row*64;
    for (int i = t; i < 51*64; i += 512) {
        int d = i >> 6, px = i & 63;
        float owv = 1.f/(1.f + expf(-U[d*64 + px]));
        ub[(size_t)d*HW + px] = (1.f - owv)*pb[(size_t)d*HW + px] + owv*U[(51 + d)*64 + px];
    }
}

// K7: fused sampling + softmax-weighted sum -> new_off (output 1).
// 1D grid 2176, bijective XCD swizzle so each XCD owns one batch.
__global__ __launch_bounds__(256) void final_kernel(
        const float* __restrict__ uvd, const float* __restrict__ sconf,
        const float* __restrict__ soff, float* __restrict__ out_off) {
    int orig = blockIdx.x;                   // 0..2175 (= 8 b * 17 j * 16 tiles)
    int wg = (orig & 7)*272 + (orig >> 3);   // 272 = 17*16 per batch
    int b = wg / 272;
    int rem = wg - b*272;
    int j = rem >> 4;
    int p = (rem & 15)*256 + threadIdx.x;
    int y = p >> 6, x = p & 63;
    const float* u0 = uvd   + ((size_t)b*51  + j*3)*HW;
    const float* c0 = sconf + ((size_t)b*51  + j*3)*HW;
    const float* s0 = soff  + ((size_t)b*136 + j*8)*HW;
    float offx = u0[p], offy = u0[HW+p];
    Bil bl = bilin((float)x + offx, (float)y + offy);
    float sall[8][2];
    #pragma unroll
    for (int h = 0; h < 4; h++) {
        const float* se = s0 + (size_t)(2*h)*HW;
        const float* so2 = s0 + (size_t)(2*h+1)*HW;
        sall[h][0] = bl.w00*se[bl.i00]+bl.w01*se[bl.i01]+bl.w10*se[bl.i10]+bl.w11*se[bl.i11] + offx;
        sall[h][1] = bl.w00*so2[bl.i00]+bl.w01*so2[bl.i01]+bl.w10*so2[bl.i10]+bl.w11*so2[bl.i11] + offy;
        sall[4+h][0] = se[p];
        sall[4+h][1] = so2[p];
    }
    float sv[8][3], lg[8][3];
    #pragma unroll
    for (int n = 0; n < 8; n++) {
        Bil b2 = bilin((float)x + sall[n][0], (float)y + sall[n][1]);
        #pragma unroll
        for (int d = 0; d < 3; d++) {
            const float* ud = u0 + (size_t)d*HW;
            const float* cd = c0 + (size_t)d*HW;
            sv[n][d] = b2.w00*ud[b2.i00]+b2.w01*ud[b2.i01]+b2.w10*ud[b2.i10]+b2.w11*ud[b2.i11];
            lg[n][d] = b2.w00*cd[b2.i00]+b2.w01*cd[b2.i01]+b2.w10*cd[b2.i10]+b2.w11*cd[b2.i11];
        }
        sv[n][0] += sall[n][0];
        sv[n][1] += sall[n][1];
    }
    #pragma unroll
    for (int d = 0; d < 3; d++) {
        float m = lg[0][d];
        #pragma unroll
        for (int n = 1; n < 8; n++) m = fmaxf(m, lg[n][d]);
        float den = 0.f, num = 0.f;
        #pragma unroll
        for (int n = 0; n < 8; n++) {
            float e = expf(lg[n][d]-m);
            den += e; num += e*sv[n][d];
        }
        out_off[((size_t)b*51 + j*3 + d)*HW + p] = num/den;
    }
}

extern "C" void kernel_launch(void* const* d_in, const int* in_sizes, int n_in,
                              void* d_out, int out_size, void* d_ws, size_t ws_size,
                              hipStream_t stream) {
    const float* feat       = (const float*)d_in[0];
    const float* prev_off   = (const float*)d_in[1];
    const float* dcn_off_w  = (const float*)d_in[2];
    const float* dcn_off_b  = (const float*)d_in[3];
    const float* dcn_w      = (const float*)d_in[4];
    const float* gn_g       = (const float*)d_in[5];
    const float* gn_b       = (const float*)d_in[6];
    const float* so_w       = (const float*)d_in[7];
    const float* so_b       = (const float*)d_in[8];
    const float* sc_w       = (const float*)d_in[9];
    const float* sc_b       = (const float*)d_in[10];
    const float* uw_w       = (const float*)d_in[11];
    const float* uw_b       = (const float*)d_in[12];
    const float* uo_w       = (const float*)d_in[13];
    const float* uo_b       = (const float*)d_in[14];

    float* ws = (float*)d_ws;
    float* off27     = ws;                       // 884736 floats
    float* Wt        = off27 + 884736;           // pack region
    short* Wp        = (short*)Wt;               // 589824 shorts (dcn weights)
    short* Ap        = Wp + 589824;              // 73728 shorts (conv3x3 weights)
    short* Wc        = Ap + 73728;               // 81920 shorts (1x1 weights)
    float* dcn       = Wt + 589824;              // 8388608
    float* partial   = dcn + 8388608;            // 2048
    float* samp_off  = partial + 2048;           // 4456448
    float* samp_conf = samp_off + 4456448;       // 1671168
    float* uvd       = samp_conf + 1671168;      // 1671168

    // featT aliases samp_off (dead after dcn_kernel)
    unsigned short* featT = (unsigned short*)samp_off;

    float* out_feat = (float*)d_out;             // 8388608
    float* out_off  = out_feat + 8388608;        // 1671168

    // K0: NCHW f32 -> NHWC bf16 transpose
    nhwc_kernel<<<dim3(BB*64), dim3(256), 0, stream>>>(feat, featT);
    // packs
    cpack_kernel<<<dim3(36), dim3(256), 0, stream>>>(dcn_off_w, Ap);
    wpack_kernel<<<dim3(288), dim3(256), 0, stream>>>(dcn_w, Wp);
    wpack4_kernel<<<dim3(40), dim3(256), 0, stream>>>(so_w, sc_w, uw_w, uo_w, Wc);
    // K1: offset conv (3x3, MFMA)
    conv3x3_kernel<<<dim3(BB*64), dim3(256), 0, stream>>>(featT, Ap, dcn_off_b, off27);
    // K2: DCN (MFMA)
    dcn_kernel<<<dim3(BB*64), dim3(512), 0, stream>>>(featT, off27, Wp, dcn);
    // K3: GroupNorm partials
    gn_partial_kernel<<<dim3(1024), dim3(256), 0, stream>>>(dcn, partial);
    // K5: fused GN + residual + 1x1 convs + offset blend (512 thr)
    fused_tail_kernel<<<dim3(512), dim3(512), 0, stream>>>(feat, dcn, partial,
        gn_g, gn_b, Wc, so_b, sc_b, uw_b, uo_b, prev_off,
        out_feat, samp_off, samp_conf, uvd);
    // K7: fused double grid-sample + softmax reduction (XCD-swizzled)
    final_kernel<<<dim3(2176), dim3(256), 0, stream>>>(uvd, samp_conf, samp_off, out_off);
}

// Round 8
// 194.358 us; speedup vs baseline: 6.4729x; 1.1286x over previous
//
#include <hip/hip_runtime.h>
#include <hip/hip_bf16.h>
#include <math.h>

// Problem constants: B=8, C=256, H=W=64, J=17, Hd=4, dim=3
#define HH 64
#define WW 64
#define HW 4096
#define CC 256
#define BB 8
#define JJ 17

typedef __attribute__((ext_vector_type(8))) short bf16x8;
typedef __attribute__((ext_vector_type(4))) float f32x4;

#define SLD 264    // padded LDS row stride in shorts
#define CST 136    // conv3x3: strip c-stride in shorts (128 c + 8 pad)
#define TLD 266    // transpose LDS stride in shorts

struct Bil { int i00,i01,i10,i11; float w00,w01,w10,w11; };

__device__ inline Bil bilin(float sx, float sy) {
    float x0f = floorf(sx), y0f = floorf(sy);
    float wx1 = sx - x0f, wy1 = sy - y0f;
    float wx0 = 1.f - wx1, wy0 = 1.f - wy1;
    int x0 = (int)x0f, y0 = (int)y0f;
    int x1 = x0 + 1, y1 = y0 + 1;
    bool vx0 = (unsigned)x0 < (unsigned)WW;
    bool vx1 = (unsigned)x1 < (unsigned)WW;
    bool vy0 = (unsigned)y0 < (unsigned)HH;
    bool vy1 = (unsigned)y1 < (unsigned)HH;
    int x0c = min(max(x0,0),WW-1), x1c = min(max(x1,0),WW-1);
    int y0c = min(max(y0,0),HH-1), y1c = min(max(y1,0),HH-1);
    Bil b;
    b.i00 = y0c*WW + x0c; b.i01 = y0c*WW + x1c;
    b.i10 = y1c*WW + x0c; b.i11 = y1c*WW + x1c;
    b.w00 = wx0*wy0*((vx0&&vy0)?1.f:0.f);
    b.w01 = wx1*wy0*((vx1&&vy0)?1.f:0.f);
    b.w10 = wx0*wy1*((vx0&&vy1)?1.f:0.f);
    b.w11 = wx1*wy1*((vx1&&vy1)?1.f:0.f);
    return b;
}

__device__ inline unsigned short f2bf(float f) {
    unsigned u = __float_as_uint(f);
    unsigned r = (u + 0x7fffu + ((u >> 16) & 1u)) >> 16;
    return (unsigned short)r;
}
__device__ inline unsigned cvt_pk_bf16(float lo, float hi) {
    unsigned r;
    asm("v_cvt_pk_bf16_f32 %0, %1, %2" : "=v"(r) : "v"(lo), "v"(hi));
    return r;
}
__device__ inline float bflo(unsigned u) { return __uint_as_float(u << 16); }
__device__ inline float bfhi(unsigned u) { return __uint_as_float(u & 0xFFFF0000u); }

struct F8 { float4 a, b; };
__device__ inline F8 ld8(const float* p) {
    F8 r; r.a = *(const float4*)p; r.b = *(const float4*)(p + 4); return r;
}
// weighted 4-corner sample of an 8-float record array
__device__ inline void gsample8(const float* base, const Bil& bl, float out[8]) {
    F8 v00 = ld8(base + (size_t)bl.i00*8);
    F8 v01 = ld8(base + (size_t)bl.i01*8);
    F8 v10 = ld8(base + (size_t)bl.i10*8);
    F8 v11 = ld8(base + (size_t)bl.i11*8);
    const float* p00 = (const float*)&v00;
    const float* p01 = (const float*)&v01;
    const float* p10 = (const float*)&v10;
    const float* p11 = (const float*)&v11;
    #pragma unroll
    for (int i = 0; i < 8; i++)
        out[i] = bl.w00*p00[i] + bl.w01*p01[i] + bl.w10*p10[i] + bl.w11*p11[i];
}

// K0: transpose feat (NCHW f32) -> featT (N,px,c) bf16. grid 8*64 blocks.
__global__ __launch_bounds__(256) void nhwc_kernel(
        const float* __restrict__ feat, unsigned short* __restrict__ featT) {
    __shared__ unsigned short T[64*TLD];   // 34 KB
    int b = blockIdx.x >> 6, p0 = (blockIdx.x & 63)*64;
    int t = threadIdx.x;
    int x = t & 63, c4 = t >> 6;
    const float* fb = feat + (size_t)b*CC*HW + p0;
    #pragma unroll 4
    for (int cp = 0; cp < 256; cp += 4) {
        int c = cp + c4;
        T[x*TLD + c] = f2bf(fb[(size_t)c*HW + x]);
    }
    __syncthreads();
    int xq = t >> 5, cl = t & 31;
    unsigned short* dst = featT + ((size_t)b*HW + p0)*256;
    #pragma unroll
    for (int w = 0; w < 8; w++) {
        int xr = w*8 + xq;
        *(uint4*)(dst + (size_t)xr*256 + cl*8) = *(const uint4*)(T + xr*TLD + cl*8);
    }
}

// K1a: pack dcn_off_w into MFMA A-fragment order, bf16.
__global__ void cpack_kernel(const float* __restrict__ w, short* __restrict__ Ap) {
    int idx = blockIdx.x*256 + threadIdx.x;   // 9*2*8*64 = 9216
    if (idx >= 9*2*8*64) return;
    int l  = idx & 63;
    int cs = (idx >> 6) & 7;
    int mt = (idx >> 9) & 1;
    int k  = idx >> 10;
    int oc = mt*16 + (l & 15);
    int c0 = cs*32 + (l >> 4)*8;
    short* dst = Ap + (size_t)idx*8;
    #pragma unroll
    for (int i = 0; i < 8; i++) {
        float v = (oc < 27) ? w[((size_t)(oc*256 + c0 + i)*3 + k/3)*3 + (k % 3)] : 0.f;
        dst[i] = (short)f2bf(v);
    }
}

// K1: 3x3 conv featT -> off27 via MFMA on a 3-row strip.
__global__ __launch_bounds__(256, 3) void conv3x3_kernel(
        const unsigned short* __restrict__ featT, const short* __restrict__ Ap,
        const float* __restrict__ bias, float* __restrict__ off27) {
    __shared__ __align__(16) short S[3*66*CST];   // 52.6 KB
    int orig = blockIdx.x;                        // 512 blocks
    int blk = (orig & 7)*64 + (orig >> 3);        // XCD swizzle
    int b = blk >> 6, row = blk & 63;
    int t = threadIdx.x;
    int l = t & 63, wv = t >> 6;

    f32x4 acc[2];
    acc[0] = (f32x4){0.f,0.f,0.f,0.f};
    acc[1] = (f32x4){0.f,0.f,0.f,0.f};
    const unsigned short* fb = featT + (size_t)b*HW*256;

    for (int ch = 0; ch < 2; ch++) {
        for (int i = t; i < 3*66*16; i += 256) {
            int cc = i & 15;
            int rp = i >> 4;
            int r = rp / 66, px_s = rp - r*66;
            int yy = row + r - 1;
            int xx = px_s - 1;
            uint4 v = (uint4){0u,0u,0u,0u};
            if ((unsigned)yy < 64u && (unsigned)xx < 64u)
                v = *(const uint4*)(fb + ((size_t)(yy*64 + xx))*256 + ch*128 + cc*8);
            *(uint4*)(&S[(r*66 + px_s)*CST + cc*8]) = v;
        }
        __syncthreads();
        #pragma unroll
        for (int k = 0; k < 9; k++) {
            int ky = k/3, kx = k%3;
            const short* srow = S + (ky*66 + wv*16 + (l & 15) + kx)*CST + (l >> 4)*8;
            #pragma unroll
            for (int csl = 0; csl < 4; csl++) {
                bf16x8 bfrag = *(const bf16x8*)(srow + csl*32);
                int cs = ch*4 + csl;
                const short* ap = Ap + ((size_t)((k*2)*8 + cs)*64 + l)*8;
                bf16x8 a0 = *(const bf16x8*)ap;
                bf16x8 a1 = *(const bf16x8*)(ap + 8*64*8);
                acc[0] = __builtin_amdgcn_mfma_f32_16x16x32_bf16(a0, bfrag, acc[0], 0, 0, 0);
                acc[1] = __builtin_amdgcn_mfma_f32_16x16x32_bf16(a1, bfrag, acc[1], 0, 0, 0);
            }
        }
        __syncthreads();
    }
    #pragma unroll
    for (int mt = 0; mt < 2; mt++)
        #pragma unroll
        for (int r = 0; r < 4; r++) {
            int oc = mt*16 + (l >> 4)*4 + r;
            if (oc < 27)
                off27[((size_t)(b*27 + oc))*HW + row*64 + wv*16 + (l & 15)]
                    = acc[mt][r] + bias[oc];
        }
}

// K1b: pack dcn_w into MFMA fragment order, bf16 (A operand).
__global__ void wpack_kernel(const float* __restrict__ w, short* __restrict__ Wp) {
    int idx = blockIdx.x*256 + threadIdx.x;   // 9*8*16*64 = 73728
    if (idx >= 9*8*16*64) return;
    int l  = idx & 63;
    int ot = (idx >> 6) & 15;
    int cs = (idx >> 10) & 7;
    int k  = idx >> 13;
    int oc = ot*16 + (l & 15);
    int c0 = cs*32 + (l >> 4)*8;
    short* dst = Wp + (size_t)idx*8;
    #pragma unroll
    for (int i = 0; i < 8; i++) {
        float v = w[((size_t)(oc*256 + c0 + i)*3 + k/3)*3 + (k % 3)];
        dst[i] = (short)f2bf(v);
    }
}

// K1c: pack the four 1x1-conv weights into MFMA A-fragment order (320 oc).
__global__ void wpack4_kernel(const float* __restrict__ so_w, const float* __restrict__ sc_w,
        const float* __restrict__ uw_w, const float* __restrict__ uo_w,
        short* __restrict__ Wc) {
    int idx = blockIdx.x*256 + threadIdx.x;   // 8*20*64 = 10240
    if (idx >= 8*20*64) return;
    int l  = idx & 63;
    int ot = (idx >> 6) % 20;
    int cs = idx / (64*20);
    int g  = ot*16 + (l & 15);
    int c0 = cs*32 + (l >> 4)*8;
    const float* src = nullptr; int oc = 0;
    if (g < 136)      { src = so_w; oc = g; }
    else if (g < 187) { src = sc_w; oc = g - 136; }
    else if (g < 238) { src = uw_w; oc = g - 187; }
    else if (g < 289) { src = uo_w; oc = g - 238; }
    short* dst = Wc + (size_t)idx*8;
    #pragma unroll
    for (int i = 0; i < 8; i++)
        dst[i] = src ? (short)f2bf(src[(size_t)oc*256 + c0 + i]) : (short)0;
}

// K2: fused DCNv2. BM=64 px (one row), 512 thr / 8 waves, grid 512.
__global__ __launch_bounds__(512, 4) void dcn_kernel(
        const unsigned short* __restrict__ featT, const float* __restrict__ off27,
        const short* __restrict__ Wp, float* __restrict__ dcn_out) {
    __shared__ __align__(16) short S[64*SLD];   // 33.8 KB

    int orig = blockIdx.x;                 // 512 blocks
    int blk  = (orig & 7)*64 + (orig >> 3);   // XCD swizzle: xcd == batch
    int b   = blk >> 6;
    int row = blk & 63;

    int t   = threadIdx.x;
    int pxh = t >> 4;
    int cl  = t & 15;
    int l   = t & 63, wv = t >> 6;

    f32x4 acc[2][4];
    #pragma unroll
    for (int i = 0; i < 2; i++)
        #pragma unroll
        for (int j = 0; j < 4; j++) acc[i][j] = (f32x4){0.f,0.f,0.f,0.f};

    const unsigned short* fT = featT + (size_t)b*HW*256;
    const float* offb = off27 + (size_t)b*27*HW;

    for (int k = 0; k < 9; k++) {
        int kx = k % 3 - 1, ky = k / 3 - 1;
        #pragma unroll
        for (int pp = 0; pp < 2; pp++) {
            int px = pp*32 + pxh;
            int p  = row*64 + px;
            float dyv = offb[(size_t)k*HW + p];
            float dxv = offb[(size_t)(9 + k)*HW + p];
            float mk  = offb[(size_t)(18 + k)*HW + p];
            float m = 1.f/(1.f + expf(-mk));
            Bil bl = bilin((float)(px + kx) + dxv, (float)(row + ky) + dyv);
            float w00 = bl.w00*m, w01 = bl.w01*m, w10 = bl.w10*m, w11 = bl.w11*m;
            #pragma unroll
            for (int cp = 0; cp < 2; cp++) {
                int c0 = cp*128 + cl*8;
                uint4 u00 = *(const uint4*)(fT + (size_t)bl.i00*256 + c0);
                uint4 u01 = *(const uint4*)(fT + (size_t)bl.i01*256 + c0);
                uint4 u10 = *(const uint4*)(fT + (size_t)bl.i10*256 + c0);
                uint4 u11 = *(const uint4*)(fT + (size_t)bl.i11*256 + c0);
                const unsigned* a00 = (const unsigned*)&u00;
                const unsigned* a01 = (const unsigned*)&u01;
                const unsigned* a10 = (const unsigned*)&u10;
                const unsigned* a11 = (const unsigned*)&u11;
                uint4 outp;
                unsigned* op = (unsigned*)&outp;
                #pragma unroll
                for (int q = 0; q < 4; q++) {
                    float vlo = w00*bflo(a00[q]) + w01*bflo(a01[q])
                              + w10*bflo(a10[q]) + w11*bflo(a11[q]);
                    float vhi = w00*bfhi(a00[q]) + w01*bfhi(a01[q])
                              + w10*bfhi(a10[q]) + w11*bfhi(a11[q]);
                    op[q] = cvt_pk_bf16(vlo, vhi);
                }
                *(uint4*)(S + px*SLD + c0) = outp;
            }
        }
        __syncthreads();

        const short* wpk = Wp + (size_t)k*8*16*64*8;
        for (int cs = 0; cs < 8; cs++) {
            bf16x8 wa[2];
            #pragma unroll
            for (int mt = 0; mt < 2; mt++)
                wa[mt] = *(const bf16x8*)(wpk + ((size_t)((cs*16 + (wv*2 + mt))*64 + l))*8);
            bf16x8 sb[4];
            #pragma unroll
            for (int pt = 0; pt < 4; pt++)
                sb[pt] = *(const bf16x8*)(S + (pt*16 + (l & 15))*SLD
                                            + cs*32 + (l >> 4)*8);
            #pragma unroll
            for (int mt = 0; mt < 2; mt++)
                #pragma unroll
                for (int pt = 0; pt < 4; pt++)
                    acc[mt][pt] = __builtin_amdgcn_mfma_f32_16x16x32_bf16(
                        wa[mt], sb[pt], acc[mt][pt], 0, 0, 0);
        }
        __syncthreads();
    }

    #pragma unroll
    for (int mt = 0; mt < 2; mt++)
        #pragma unroll
        for (int pt = 0; pt < 4; pt++)
            #pragma unroll
            for (int r = 0; r < 4; r++) {
                int oc = wv*32 + mt*16 + (l >> 4)*4 + r;
                int px = pt*16 + (l & 15);
                dcn_out[((size_t)(b*256 + oc))*HW + row*64 + px] = acc[mt][pt][r];
            }
}

// K3: GroupNorm partial sums: 1024 blocks, 2 channels each.
__global__ __launch_bounds__(256) void gn_partial_kernel(
        const float* __restrict__ dcn, float* __restrict__ partial) {
    int blk = blockIdx.x;
    const float4* base = (const float4*)(dcn + (size_t)blk*2*HW);
    float s = 0.f, s2 = 0.f;
    #pragma unroll
    for (int j = 0; j < 8; j++) {
        float4 v = base[threadIdx.x + j*256];
        s  += v.x + v.y + v.z + v.w;
        s2 += v.x*v.x + v.y*v.y + v.z*v.z + v.w*v.w;
    }
    __shared__ float rs[256], rs2[256];
    rs[threadIdx.x] = s; rs2[threadIdx.x] = s2; __syncthreads();
    for (int o = 128; o > 0; o >>= 1) {
        if (threadIdx.x < o) { rs[threadIdx.x] += rs[threadIdx.x+o]; rs2[threadIdx.x] += rs2[threadIdx.x+o]; }
        __syncthreads();
    }
    if (threadIdx.x == 0) { partial[blk*2] = rs[0]; partial[blk*2+1] = rs2[0]; }
}

// K5: fused GN-apply + residual (-> out_feat) + 1x1 convs + offset blend.
// Outputs packed px-major records: SO[b][j][p][8] (samp_off) and
// UC[b][j][p][8] = {u0,u1,u2,c0,c1,c2,-,-} (blended offset + conf).
__global__ __launch_bounds__(512, 2) void fused_tail_kernel(
        const float* __restrict__ feat, const float* __restrict__ dcn,
        const float* __restrict__ partial, const float* __restrict__ gn_g,
        const float* __restrict__ gn_b, const short* __restrict__ Wc,
        const float* __restrict__ so_b, const float* __restrict__ sc_b,
        const float* __restrict__ uw_b, const float* __restrict__ uo_b,
        const float* __restrict__ prev_off,
        float* __restrict__ out_feat, float* __restrict__ SO,
        float* __restrict__ UC) {
    __shared__ __align__(16) short S[64*SLD];   // 33.8 KB; overlaid by U after GEMM
    __shared__ float gstat[32][2];
    float* U = (float*)S;                       // [102][64] floats

    int orig = blockIdx.x;                      // 512 blocks
    int blk = (orig & 7)*64 + (orig >> 3);      // XCD swizzle
    int b = blk >> 6, row = blk & 63;
    int t = threadIdx.x;

    if (t < 32) {
        const float* pp = partial + (size_t)(b*32 + t)*8;
        float s  = pp[0] + pp[2] + pp[4] + pp[6];
        float s2 = pp[1] + pp[3] + pp[5] + pp[7];
        float inv = 1.f/(8.f*HW);
        float mu = s*inv;
        float var = s2*inv - mu*mu;
        gstat[t][0] = mu;
        gstat[t][1] = rsqrtf(var + 1e-5f);
    }
    __syncthreads();

    int x = t & 63, cq = t >> 6;
    int l = t & 63, wv = t >> 6;
    const float* fb = feat + (size_t)b*CC*HW + row*64;
    const float* db = dcn  + (size_t)b*CC*HW + row*64;
    float* ob = out_feat + (size_t)b*CC*HW + row*64;
    #pragma unroll
    for (int j = 0; j < 8; j++) {
        int c0 = cq*32 + j*4;
        float fv[4];
        #pragma unroll
        for (int q = 0; q < 4; q++) {
            int c = c0 + q;
            float mu = gstat[c >> 3][0], rstd = gstat[c >> 3][1];
            float v = (db[(size_t)c*HW + x] - mu)*rstd*gn_g[c] + gn_b[c];
            fv[q] = fb[(size_t)c*HW + x] + fmaxf(v, 0.f);
            ob[(size_t)c*HW + x] = fv[q];
        }
        uint2 pk;
        pk.x = cvt_pk_bf16(fv[0], fv[1]);
        pk.y = cvt_pk_bf16(fv[2], fv[3]);
        *(uint2*)(S + x*SLD + c0) = pk;
    }
    __syncthreads();

    f32x4 acc[3][4];
    #pragma unroll
    for (int j = 0; j < 3; j++)
        #pragma unroll
        for (int pt = 0; pt < 4; pt++) acc[j][pt] = (f32x4){0.f,0.f,0.f,0.f};

    for (int cs = 0; cs < 8; cs++) {
        bf16x8 bg[4];
        #pragma unroll
        for (int pt = 0; pt < 4; pt++)
            bg[pt] = *(const bf16x8*)(S + (pt*16 + (l & 15))*SLD
                                        + cs*32 + (l >> 4)*8);
        #pragma unroll
        for (int j = 0; j < 3; j++) {
            int tile = wv + j*8;
            if (tile < 20) {
                bf16x8 a = *(const bf16x8*)(Wc + ((size_t)(cs*20 + tile)*64 + l)*8);
                #pragma unroll
                for (int pt = 0; pt < 4; pt++)
                    acc[j][pt] = __builtin_amdgcn_mfma_f32_16x16x32_bf16(
                        a, bg[pt], acc[j][pt], 0, 0, 0);
            }
        }
    }
    __syncthreads();   // S dead; U live

    #pragma unroll
    for (int j = 0; j < 3; j++) {
        int tile = wv + j*8;
        if (tile < 20) {
            #pragma unroll
            for (int pt = 0; pt < 4; pt++) {
                int px = pt*16 + (l & 15);
                int p = row*64 + px;
                #pragma unroll
                for (int r = 0; r < 4; r++) {
                    int oc = tile*16 + (l >> 4)*4 + r;
                    float v = acc[j][pt][r];
                    if (oc < 136) {
                        // SO record: joint oc>>3, channel oc&7
                        SO[(((size_t)(b*JJ + (oc >> 3))*HW) + p)*8 + (oc & 7)] = v + so_b[oc];
                    } else if (oc < 187) {
                        int o2 = oc - 136;
                        int jj = o2/3, d = o2 - jj*3;
                        UC[(((size_t)(b*JJ + jj)*HW) + p)*8 + 3 + d] = v + sc_b[o2];
                    } else if (oc < 238) {
                        U[(oc-187)*64 + px] = v + uw_b[oc-187];
                    } else if (oc < 289) {
                        U[(51 + oc-238)*64 + px] = v + uo_b[oc-238];
                    }
                }
            }
        }
    }
    __syncthreads();

    const float* pb = prev_off + (size_t)b*51*HW + row*64;
    for (int i = t; i < 51*64; i += 512) {
        int dful = i >> 6, px = i & 63;
        int jj = dful/3, d = dful - jj*3;
        int p = row*64 + px;
        float owv = 1.f/(1.f + expf(-U[dful*64 + px]));
        float blend = (1.f - owv)*pb[(size_t)dful*HW + px] + owv*U[(51 + dful)*64 + px];
        UC[(((size_t)(b*JJ + jj)*HW) + p)*8 + d] = blend;
    }
}

// K7: fused sampling + softmax-weighted sum -> new_off (output 1).
// Packed px-major inputs: ~77 fat loads/thread instead of 234 scalar.
__global__ __launch_bounds__(256) void final_kernel(
        const float* __restrict__ UC, const float* __restrict__ SO,
        float* __restrict__ out_off) {
    int orig = blockIdx.x;                   // 0..2175
    int wg = (orig & 7)*272 + (orig >> 3);   // 272 = 17*16 per batch
    int b = wg / 272;
    int rem = wg - b*272;
    int j = rem >> 4;
    int p = (rem & 15)*256 + threadIdx.x;
    int y = p >> 6, x = p & 63;
    const float* ucb = UC + (size_t)(b*JJ + j)*HW*8;
    const float* sob = SO + (size_t)(b*JJ + j)*HW*8;

    float4 own = *(const float4*)(ucb + (size_t)p*8);
    float offx = own.x, offy = own.y;
    F8 sod = ld8(sob + (size_t)p*8);
    const float* sodp = (const float*)&sod;

    Bil bl = bilin((float)x + offx, (float)y + offy);
    float s8[8];
    gsample8(sob, bl, s8);

    float sall[8][2];
    #pragma unroll
    for (int h = 0; h < 4; h++) {
        sall[h][0]   = s8[2*h]   + offx;
        sall[h][1]   = s8[2*h+1] + offy;
        sall[4+h][0] = sodp[2*h];
        sall[4+h][1] = sodp[2*h+1];
    }

    float sv[8][3], lg[8][3];
    #pragma unroll
    for (int n = 0; n < 8; n++) {
        Bil b2 = bilin((float)x + sall[n][0], (float)y + sall[n][1]);
        float v8[8];
        gsample8(ucb, b2, v8);
        #pragma unroll
        for (int d = 0; d < 3; d++) {
            sv[n][d] = v8[d];
            lg[n][d] = v8[3 + d];
        }
        sv[n][0] += sall[n][0];
        sv[n][1] += sall[n][1];
    }
    #pragma unroll
    for (int d = 0; d < 3; d++) {
        float m = lg[0][d];
        #pragma unroll
        for (int n = 1; n < 8; n++) m = fmaxf(m, lg[n][d]);
        float den = 0.f, num = 0.f;
        #pragma unroll
        for (int n = 0; n < 8; n++) {
            float e = expf(lg[n][d]-m);
            den += e; num += e*sv[n][d];
        }
        out_off[((size_t)b*51 + j*3 + d)*HW + p] = num/den;
    }
}

extern "C" void kernel_launch(void* const* d_in, const int* in_sizes, int n_in,
                              void* d_out, int out_size, void* d_ws, size_t ws_size,
                              hipStream_t stream) {
    const float* feat       = (const float*)d_in[0];
    const float* prev_off   = (const float*)d_in[1];
    const float* dcn_off_w  = (const float*)d_in[2];
    const float* dcn_off_b  = (const float*)d_in[3];
    const float* dcn_w      = (const float*)d_in[4];
    const float* gn_g       = (const float*)d_in[5];
    const float* gn_b       = (const float*)d_in[6];
    const float* so_w       = (const float*)d_in[7];
    const float* so_b       = (const float*)d_in[8];
    const float* sc_w       = (const float*)d_in[9];
    const float* sc_b       = (const float*)d_in[10];
    const float* uw_w       = (const float*)d_in[11];
    const float* uw_b       = (const float*)d_in[12];
    const float* uo_w       = (const float*)d_in[13];
    const float* uo_b       = (const float*)d_in[14];

    float* ws = (float*)d_ws;
    float* off27     = ws;                       // 884736 floats
    float* Wt        = off27 + 884736;           // pack region
    short* Wp        = (short*)Wt;               // 589824 shorts (dcn weights)
    short* Ap        = Wp + 589824;              // 73728 shorts (conv3x3 weights)
    short* Wc        = Ap + 73728;               // 81920 shorts (1x1 weights)
    float* dcn       = Wt + 589824;              // 8388608
    float* partial   = dcn + 8388608;            // 2048
    float* SO        = partial + 2048;           // 4456448 (8*17*4096*8)
    float* UC        = SO + 4456448;             // 4456448

    // featT aliases SO (dead after dcn_kernel; SO written by fused_tail)
    unsigned short* featT = (unsigned short*)SO;

    float* out_feat = (float*)d_out;             // 8388608
    float* out_off  = out_feat + 8388608;        // 1671168

    // K0: NCHW f32 -> NHWC bf16 transpose
    nhwc_kernel<<<dim3(BB*64), dim3(256), 0, stream>>>(feat, featT);
    // packs
    cpack_kernel<<<dim3(36), dim3(256), 0, stream>>>(dcn_off_w, Ap);
    wpack_kernel<<<dim3(288), dim3(256), 0, stream>>>(dcn_w, Wp);
    wpack4_kernel<<<dim3(40), dim3(256), 0, stream>>>(so_w, sc_w, uw_w, uo_w, Wc);
    // K1: offset conv (3x3, MFMA)
    conv3x3_kernel<<<dim3(BB*64), dim3(256), 0, stream>>>(featT, Ap, dcn_off_b, off27);
    // K2: DCN (MFMA)
    dcn_kernel<<<dim3(BB*64), dim3(512), 0, stream>>>(featT, off27, Wp, dcn);
    // K3: GroupNorm partials
    gn_partial_kernel<<<dim3(1024), dim3(256), 0, stream>>>(dcn, partial);
    // K5: fused GN + residual + 1x1 convs + offset blend -> packed SO/UC
    fused_tail_kernel<<<dim3(512), dim3(512), 0, stream>>>(feat, dcn, partial,
        gn_g, gn_b, Wc, so_b, sc_b, uw_b, uo_b, prev_off,
        out_feat, SO, UC);
    // K7: fused double grid-sample + softmax reduction (packed gathers)
    final_kernel<<<dim3(2176), dim3(256), 0, stream>>>(UC, SO, out_off);
}

// Round 9
// 192.821 us; speedup vs baseline: 6.5245x; 1.0080x over previous
//
#include <hip/hip_runtime.h>
#include <hip/hip_bf16.h>
#include <math.h>

// Problem constants: B=8, C=256, H=W=64, J=17, Hd=4, dim=3
#define HH 64
#define WW 64
#define HW 4096
#define CC 256
#define BB 8
#define JJ 17

typedef __attribute__((ext_vector_type(8))) short bf16x8;
typedef __attribute__((ext_vector_type(4))) float f32x4;

#define SLD 266    // padded LDS row stride in shorts: 133 dwords == 5 mod 32 (bank-safe)
#define CST 136    // conv3x3: strip c-stride in shorts (128 c + 8 pad)
#define TLD 266    // transpose LDS stride in shorts

struct Bil { int i00,i01,i10,i11; float w00,w01,w10,w11; };

__device__ inline Bil bilin(float sx, float sy) {
    float x0f = floorf(sx), y0f = floorf(sy);
    float wx1 = sx - x0f, wy1 = sy - y0f;
    float wx0 = 1.f - wx1, wy0 = 1.f - wy1;
    int x0 = (int)x0f, y0 = (int)y0f;
    int x1 = x0 + 1, y1 = y0 + 1;
    bool vx0 = (unsigned)x0 < (unsigned)WW;
    bool vx1 = (unsigned)x1 < (unsigned)WW;
    bool vy0 = (unsigned)y0 < (unsigned)HH;
    bool vy1 = (unsigned)y1 < (unsigned)HH;
    int x0c = min(max(x0,0),WW-1), x1c = min(max(x1,0),WW-1);
    int y0c = min(max(y0,0),HH-1), y1c = min(max(y1,0),HH-1);
    Bil b;
    b.i00 = y0c*WW + x0c; b.i01 = y0c*WW + x1c;
    b.i10 = y1c*WW + x0c; b.i11 = y1c*WW + x1c;
    b.w00 = wx0*wy0*((vx0&&vy0)?1.f:0.f);
    b.w01 = wx1*wy0*((vx1&&vy0)?1.f:0.f);
    b.w10 = wx0*wy1*((vx0&&vy1)?1.f:0.f);
    b.w11 = wx1*wy1*((vx1&&vy1)?1.f:0.f);
    return b;
}

__device__ inline unsigned short f2bf(float f) {
    unsigned u = __float_as_uint(f);
    unsigned r = (u + 0x7fffu + ((u >> 16) & 1u)) >> 16;
    return (unsigned short)r;
}
__device__ inline unsigned cvt_pk_bf16(float lo, float hi) {
    unsigned r;
    asm("v_cvt_pk_bf16_f32 %0, %1, %2" : "=v"(r) : "v"(lo), "v"(hi));
    return r;
}
__device__ inline float bflo(unsigned u) { return __uint_as_float(u << 16); }
__device__ inline float bfhi(unsigned u) { return __uint_as_float(u & 0xFFFF0000u); }
__device__ inline float bf2f(unsigned short us) { return __uint_as_float(((unsigned)us) << 16); }

struct F8 { float4 a, b; };
__device__ inline F8 ld8(const float* p) {
    F8 r; r.a = *(const float4*)p; r.b = *(const float4*)(p + 4); return r;
}
__device__ inline void gsample8(const float* base, const Bil& bl, float out[8]) {
    F8 v00 = ld8(base + (size_t)bl.i00*8);
    F8 v01 = ld8(base + (size_t)bl.i01*8);
    F8 v10 = ld8(base + (size_t)bl.i10*8);
    F8 v11 = ld8(base + (size_t)bl.i11*8);
    const float* p00 = (const float*)&v00;
    const float* p01 = (const float*)&v01;
    const float* p10 = (const float*)&v10;
    const float* p11 = (const float*)&v11;
    #pragma unroll
    for (int i = 0; i < 8; i++)
        out[i] = bl.w00*p00[i] + bl.w01*p01[i] + bl.w10*p10[i] + bl.w11*p11[i];
}

// K0: transpose feat (NCHW f32) -> featT (N,px,c) bf16.
__global__ __launch_bounds__(256) void nhwc_kernel(
        const float* __restrict__ feat, unsigned short* __restrict__ featT) {
    __shared__ unsigned short T[64*TLD];   // 34 KB
    int b = blockIdx.x >> 6, p0 = (blockIdx.x & 63)*64;
    int t = threadIdx.x;
    int x = t & 63, c4 = t >> 6;
    const float* fb = feat + (size_t)b*CC*HW + p0;
    #pragma unroll 4
    for (int cp = 0; cp < 256; cp += 4) {
        int c = cp + c4;
        T[x*TLD + c] = f2bf(fb[(size_t)c*HW + x]);
    }
    __syncthreads();
    int xq = t >> 5, cl = t & 31;
    unsigned short* dst = featT + ((size_t)b*HW + p0)*256;
    #pragma unroll
    for (int w = 0; w < 8; w++) {
        int xr = w*8 + xq;
        *(uint4*)(dst + (size_t)xr*256 + cl*8) = *(const uint4*)(T + xr*TLD + cl*8);
    }
}

// K1a: pack dcn_off_w into MFMA A-fragment order, bf16.
__global__ void cpack_kernel(const float* __restrict__ w, short* __restrict__ Ap) {
    int idx = blockIdx.x*256 + threadIdx.x;   // 9216
    if (idx >= 9*2*8*64) return;
    int l  = idx & 63;
    int cs = (idx >> 6) & 7;
    int mt = (idx >> 9) & 1;
    int k  = idx >> 10;
    int oc = mt*16 + (l & 15);
    int c0 = cs*32 + (l >> 4)*8;
    short* dst = Ap + (size_t)idx*8;
    #pragma unroll
    for (int i = 0; i < 8; i++) {
        float v = (oc < 27) ? w[((size_t)(oc*256 + c0 + i)*3 + k/3)*3 + (k % 3)] : 0.f;
        dst[i] = (short)f2bf(v);
    }
}

// K1: 3x3 conv featT -> off27 via MFMA on a 3-row strip.
__global__ __launch_bounds__(256, 3) void conv3x3_kernel(
        const unsigned short* __restrict__ featT, const short* __restrict__ Ap,
        const float* __restrict__ bias, float* __restrict__ off27) {
    __shared__ __align__(16) short S[3*66*CST];   // 52.6 KB
    int orig = blockIdx.x;                        // 512 blocks
    int blk = (orig & 7)*64 + (orig >> 3);        // XCD swizzle
    int b = blk >> 6, row = blk & 63;
    int t = threadIdx.x;
    int l = t & 63, wv = t >> 6;

    f32x4 acc[2];
    acc[0] = (f32x4){0.f,0.f,0.f,0.f};
    acc[1] = (f32x4){0.f,0.f,0.f,0.f};
    const unsigned short* fb = featT + (size_t)b*HW*256;

    for (int ch = 0; ch < 2; ch++) {
        for (int i = t; i < 3*66*16; i += 256) {
            int cc = i & 15;
            int rp = i >> 4;
            int r = rp / 66, px_s = rp - r*66;
            int yy = row + r - 1;
            int xx = px_s - 1;
            uint4 v = (uint4){0u,0u,0u,0u};
            if ((unsigned)yy < 64u && (unsigned)xx < 64u)
                v = *(const uint4*)(fb + ((size_t)(yy*64 + xx))*256 + ch*128 + cc*8);
            *(uint4*)(&S[(r*66 + px_s)*CST + cc*8]) = v;
        }
        __syncthreads();
        #pragma unroll
        for (int k = 0; k < 9; k++) {
            int ky = k/3, kx = k%3;
            const short* srow = S + (ky*66 + wv*16 + (l & 15) + kx)*CST + (l >> 4)*8;
            #pragma unroll
            for (int csl = 0; csl < 4; csl++) {
                bf16x8 bfrag = *(const bf16x8*)(srow + csl*32);
                int cs = ch*4 + csl;
                const short* ap = Ap + ((size_t)((k*2)*8 + cs)*64 + l)*8;
                bf16x8 a0 = *(const bf16x8*)ap;
                bf16x8 a1 = *(const bf16x8*)(ap + 8*64*8);
                acc[0] = __builtin_amdgcn_mfma_f32_16x16x32_bf16(a0, bfrag, acc[0], 0, 0, 0);
                acc[1] = __builtin_amdgcn_mfma_f32_16x16x32_bf16(a1, bfrag, acc[1], 0, 0, 0);
            }
        }
        __syncthreads();
    }
    #pragma unroll
    for (int mt = 0; mt < 2; mt++)
        #pragma unroll
        for (int r = 0; r < 4; r++) {
            int oc = mt*16 + (l >> 4)*4 + r;
            if (oc < 27)
                off27[((size_t)(b*27 + oc))*HW + row*64 + wv*16 + (l & 15)]
                    = acc[mt][r] + bias[oc];
        }
}

// K1b: pack dcn_w into MFMA fragment order, bf16 (A operand).
__global__ void wpack_kernel(const float* __restrict__ w, short* __restrict__ Wp) {
    int idx = blockIdx.x*256 + threadIdx.x;   // 73728
    if (idx >= 9*8*16*64) return;
    int l  = idx & 63;
    int ot = (idx >> 6) & 15;
    int cs = (idx >> 10) & 7;
    int k  = idx >> 13;
    int oc = ot*16 + (l & 15);
    int c0 = cs*32 + (l >> 4)*8;
    short* dst = Wp + (size_t)idx*8;
    #pragma unroll
    for (int i = 0; i < 8; i++) {
        float v = w[((size_t)(oc*256 + c0 + i)*3 + k/3)*3 + (k % 3)];
        dst[i] = (short)f2bf(v);
    }
}

// K1c: pack the four 1x1-conv weights into MFMA A-fragment order (320 oc).
__global__ void wpack4_kernel(const float* __restrict__ so_w, const float* __restrict__ sc_w,
        const float* __restrict__ uw_w, const float* __restrict__ uo_w,
        short* __restrict__ Wc) {
    int idx = blockIdx.x*256 + threadIdx.x;   // 10240
    if (idx >= 8*20*64) return;
    int l  = idx & 63;
    int ot = (idx >> 6) % 20;
    int cs = idx / (64*20);
    int g  = ot*16 + (l & 15);
    int c0 = cs*32 + (l >> 4)*8;
    const float* src = nullptr; int oc = 0;
    if (g < 136)      { src = so_w; oc = g; }
    else if (g < 187) { src = sc_w; oc = g - 136; }
    else if (g < 238) { src = uw_w; oc = g - 187; }
    else if (g < 289) { src = uo_w; oc = g - 238; }
    short* dst = Wc + (size_t)idx*8;
    #pragma unroll
    for (int i = 0; i < 8; i++)
        dst[i] = src ? (short)f2bf(src[(size_t)oc*256 + c0 + i]) : (short)0;
}

// K2: fused DCNv2. BM=64 px (one row), 512 thr / 8 waves, grid 512.
// Output stored as bf16 (ushort).
__global__ __launch_bounds__(512, 4) void dcn_kernel(
        const unsigned short* __restrict__ featT, const float* __restrict__ off27,
        const short* __restrict__ Wp, unsigned short* __restrict__ dcn16) {
    __shared__ __align__(16) short S[64*SLD];   // 34 KB

    int orig = blockIdx.x;                 // 512 blocks
    int blk  = (orig & 7)*64 + (orig >> 3);   // XCD swizzle: xcd == batch
    int b   = blk >> 6;
    int row = blk & 63;

    int t   = threadIdx.x;
    int pxh = t >> 4;
    int cl  = t & 15;
    int l   = t & 63, wv = t >> 6;

    f32x4 acc[2][4];
    #pragma unroll
    for (int i = 0; i < 2; i++)
        #pragma unroll
        for (int j = 0; j < 4; j++) acc[i][j] = (f32x4){0.f,0.f,0.f,0.f};

    const unsigned short* fT = featT + (size_t)b*HW*256;
    const float* offb = off27 + (size_t)b*27*HW;

    for (int k = 0; k < 9; k++) {
        int kx = k % 3 - 1, ky = k / 3 - 1;
        #pragma unroll
        for (int pp = 0; pp < 2; pp++) {
            int px = pp*32 + pxh;
            int p  = row*64 + px;
            float dyv = offb[(size_t)k*HW + p];
            float dxv = offb[(size_t)(9 + k)*HW + p];
            float mk  = offb[(size_t)(18 + k)*HW + p];
            float m = 1.f/(1.f + expf(-mk));
            Bil bl = bilin((float)(px + kx) + dxv, (float)(row + ky) + dyv);
            float w00 = bl.w00*m, w01 = bl.w01*m, w10 = bl.w10*m, w11 = bl.w11*m;
            #pragma unroll
            for (int cp = 0; cp < 2; cp++) {
                int c0 = cp*128 + cl*8;
                uint4 u00 = *(const uint4*)(fT + (size_t)bl.i00*256 + c0);
                uint4 u01 = *(const uint4*)(fT + (size_t)bl.i01*256 + c0);
                uint4 u10 = *(const uint4*)(fT + (size_t)bl.i10*256 + c0);
                uint4 u11 = *(const uint4*)(fT + (size_t)bl.i11*256 + c0);
                const unsigned* a00 = (const unsigned*)&u00;
                const unsigned* a01 = (const unsigned*)&u01;
                const unsigned* a10 = (const unsigned*)&u10;
                const unsigned* a11 = (const unsigned*)&u11;
                uint4 outp;
                unsigned* op = (unsigned*)&outp;
                #pragma unroll
                for (int q = 0; q < 4; q++) {
                    float vlo = w00*bflo(a00[q]) + w01*bflo(a01[q])
                              + w10*bflo(a10[q]) + w11*bflo(a11[q]);
                    float vhi = w00*bfhi(a00[q]) + w01*bfhi(a01[q])
                              + w10*bfhi(a10[q]) + w11*bfhi(a11[q]);
                    op[q] = cvt_pk_bf16(vlo, vhi);
                }
                *(uint4*)(S + px*SLD + c0) = outp;
            }
        }
        __syncthreads();

        const short* wpk = Wp + (size_t)k*8*16*64*8;
        for (int cs = 0; cs < 8; cs++) {
            bf16x8 wa[2];
            #pragma unroll
            for (int mt = 0; mt < 2; mt++)
                wa[mt] = *(const bf16x8*)(wpk + ((size_t)((cs*16 + (wv*2 + mt))*64 + l))*8);
            bf16x8 sb[4];
            #pragma unroll
            for (int pt = 0; pt < 4; pt++)
                sb[pt] = *(const bf16x8*)(S + (pt*16 + (l & 15))*SLD
                                            + cs*32 + (l >> 4)*8);
            #pragma unroll
            for (int mt = 0; mt < 2; mt++)
                #pragma unroll
                for (int pt = 0; pt < 4; pt++)
                    acc[mt][pt] = __builtin_amdgcn_mfma_f32_16x16x32_bf16(
                        wa[mt], sb[pt], acc[mt][pt], 0, 0, 0);
        }
        __syncthreads();
    }

    #pragma unroll
    for (int mt = 0; mt < 2; mt++)
        #pragma unroll
        for (int pt = 0; pt < 4; pt++)
            #pragma unroll
            for (int r = 0; r < 4; r++) {
                int oc = wv*32 + mt*16 + (l >> 4)*4 + r;
                int px = pt*16 + (l & 15);
                dcn16[((size_t)(b*256 + oc))*HW + row*64 + px] = f2bf(acc[mt][pt][r]);
            }
}

// K3: GroupNorm partial sums from bf16 dcn: 1024 blocks, 2 channels each.
__global__ __launch_bounds__(256) void gn_partial_kernel(
        const unsigned short* __restrict__ dcn16, float* __restrict__ partial) {
    int blk = blockIdx.x;
    const uint4* base = (const uint4*)(dcn16 + (size_t)blk*2*HW);  // 8192 ushorts = 1024 uint4
    float s = 0.f, s2 = 0.f;
    #pragma unroll
    for (int j = 0; j < 4; j++) {
        uint4 v = base[threadIdx.x + j*256];
        const unsigned* u = (const unsigned*)&v;
        #pragma unroll
        for (int q = 0; q < 4; q++) {
            float lo = bflo(u[q]), hi = bfhi(u[q]);
            s += lo + hi; s2 += lo*lo + hi*hi;
        }
    }
    __shared__ float rs[256], rs2[256];
    rs[threadIdx.x] = s; rs2[threadIdx.x] = s2; __syncthreads();
    for (int o = 128; o > 0; o >>= 1) {
        if (threadIdx.x < o) { rs[threadIdx.x] += rs[threadIdx.x+o]; rs2[threadIdx.x] += rs2[threadIdx.x+o]; }
        __syncthreads();
    }
    if (threadIdx.x == 0) { partial[blk*2] = rs[0]; partial[blk*2+1] = rs2[0]; }
}

// K5: fused GN-apply + residual (-> out_feat) + 1x1 convs + offset blend.
__global__ __launch_bounds__(512, 2) void fused_tail_kernel(
        const float* __restrict__ feat, const unsigned short* __restrict__ dcn16,
        const float* __restrict__ partial, const float* __restrict__ gn_g,
        const float* __restrict__ gn_b, const short* __restrict__ Wc,
        const float* __restrict__ so_b, const float* __restrict__ sc_b,
        const float* __restrict__ uw_b, const float* __restrict__ uo_b,
        const float* __restrict__ prev_off,
        float* __restrict__ out_feat, float* __restrict__ SO,
        float* __restrict__ UC) {
    __shared__ __align__(16) short S[64*SLD];   // 34 KB; overlaid by U after GEMM
    __shared__ float gstat[32][2];
    float* U = (float*)S;                       // [102][64] floats

    int orig = blockIdx.x;                      // 512 blocks
    int blk = (orig & 7)*64 + (orig >> 3);      // XCD swizzle
    int b = blk >> 6, row = blk & 63;
    int t = threadIdx.x;

    if (t < 32) {
        const float* pp = partial + (size_t)(b*32 + t)*8;
        float s  = pp[0] + pp[2] + pp[4] + pp[6];
        float s2 = pp[1] + pp[3] + pp[5] + pp[7];
        float inv = 1.f/(8.f*HW);
        float mu = s*inv;
        float var = s2*inv - mu*mu;
        gstat[t][0] = mu;
        gstat[t][1] = rsqrtf(var + 1e-5f);
    }
    __syncthreads();

    int x = t & 63, cq = t >> 6;
    int l = t & 63, wv = t >> 6;
    const float* fb = feat + (size_t)b*CC*HW + row*64;
    const unsigned short* db = dcn16 + (size_t)b*CC*HW + row*64;
    float* ob = out_feat + (size_t)b*CC*HW + row*64;
    #pragma unroll
    for (int j = 0; j < 8; j++) {
        int c0 = cq*32 + j*4;
        float fv[4];
        #pragma unroll
        for (int q = 0; q < 4; q++) {
            int c = c0 + q;
            float mu = gstat[c >> 3][0], rstd = gstat[c >> 3][1];
            float v = (bf2f(db[(size_t)c*HW + x]) - mu)*rstd*gn_g[c] + gn_b[c];
            fv[q] = fb[(size_t)c*HW + x] + fmaxf(v, 0.f);
            ob[(size_t)c*HW + x] = fv[q];
        }
        uint2 pk;
        pk.x = cvt_pk_bf16(fv[0], fv[1]);
        pk.y = cvt_pk_bf16(fv[2], fv[3]);
        *(uint2*)(S + x*SLD + c0) = pk;
    }
    __syncthreads();

    f32x4 acc[3][4];
    #pragma unroll
    for (int j = 0; j < 3; j++)
        #pragma unroll
        for (int pt = 0; pt < 4; pt++) acc[j][pt] = (f32x4){0.f,0.f,0.f,0.f};

    for (int cs = 0; cs < 8; cs++) {
        bf16x8 bg[4];
        #pragma unroll
        for (int pt = 0; pt < 4; pt++)
            bg[pt] = *(const bf16x8*)(S + (pt*16 + (l & 15))*SLD
                                        + cs*32 + (l >> 4)*8);
        #pragma unroll
        for (int j = 0; j < 3; j++) {
            int tile = wv + j*8;
            if (tile < 20) {
                bf16x8 a = *(const bf16x8*)(Wc + ((size_t)(cs*20 + tile)*64 + l)*8);
                #pragma unroll
                for (int pt = 0; pt < 4; pt++)
                    acc[j][pt] = __builtin_amdgcn_mfma_f32_16x16x32_bf16(
                        a, bg[pt], acc[j][pt], 0, 0, 0);
            }
        }
    }
    __syncthreads();   // S dead; U live

    #pragma unroll
    for (int j = 0; j < 3; j++) {
        int tile = wv + j*8;
        if (tile < 20) {
            #pragma unroll
            for (int pt = 0; pt < 4; pt++) {
                int px = pt*16 + (l & 15);
                int p = row*64 + px;
                #pragma unroll
                for (int r = 0; r < 4; r++) {
                    int oc = tile*16 + (l >> 4)*4 + r;
                    float v = acc[j][pt][r];
                    if (oc < 136) {
                        SO[(((size_t)(b*JJ + (oc >> 3))*HW) + p)*8 + (oc & 7)] = v + so_b[oc];
                    } else if (oc < 187) {
                        int o2 = oc - 136;
                        int jj = o2/3, d = o2 - jj*3;
                        UC[(((size_t)(b*JJ + jj)*HW) + p)*8 + 3 + d] = v + sc_b[o2];
                    } else if (oc < 238) {
                        U[(oc-187)*64 + px] = v + uw_b[oc-187];
                    } else if (oc < 289) {
                        U[(51 + oc-238)*64 + px] = v + uo_b[oc-238];
                    }
                }
            }
        }
    }
    __syncthreads();

    const float* pb = prev_off + (size_t)b*51*HW + row*64;
    for (int i = t; i < 51*64; i += 512) {
        int dful = i >> 6, px = i & 63;
        int jj = dful/3, d = dful - jj*3;
        int p = row*64 + px;
        float owv = 1.f/(1.f + expf(-U[dful*64 + px]));
        float blend = (1.f - owv)*pb[(size_t)dful*HW + px] + owv*U[(51 + dful)*64 + px];
        UC[(((size_t)(b*JJ + jj)*HW) + p)*8 + d] = blend;
    }
}

// K7: fused sampling + softmax-weighted sum -> new_off (output 1).
__global__ __launch_bounds__(256) void final_kernel(
        const float* __restrict__ UC, const float* __restrict__ SO,
        float* __restrict__ out_off) {
    int orig = blockIdx.x;                   // 0..2175
    int wg = (orig & 7)*272 + (orig >> 3);   // 272 = 17*16 per batch
    int b = wg / 272;
    int rem = wg - b*272;
    int j = rem >> 4;
    int p = (rem & 15)*256 + threadIdx.x;
    int y = p >> 6, x = p & 63;
    const float* ucb = UC + (size_t)(b*JJ + j)*HW*8;
    const float* sob = SO + (size_t)(b*JJ + j)*HW*8;

    float4 own = *(const float4*)(ucb + (size_t)p*8);
    float offx = own.x, offy = own.y;
    F8 sod = ld8(sob + (size_t)p*8);
    const float* sodp = (const float*)&sod;

    Bil bl = bilin((float)x + offx, (float)y + offy);
    float s8[8];
    gsample8(sob, bl, s8);

    float sall[8][2];
    #pragma unroll
    for (int h = 0; h < 4; h++) {
        sall[h][0]   = s8[2*h]   + offx;
        sall[h][1]   = s8[2*h+1] + offy;
        sall[4+h][0] = sodp[2*h];
        sall[4+h][1] = sodp[2*h+1];
    }

    float sv[8][3], lg[8][3];
    #pragma unroll
    for (int n = 0; n < 8; n++) {
        Bil b2 = bilin((float)x + sall[n][0], (float)y + sall[n][1]);
        float v8[8];
        gsample8(ucb, b2, v8);
        #pragma unroll
        for (int d = 0; d < 3; d++) {
            sv[n][d] = v8[d];
            lg[n][d] = v8[3 + d];
        }
        sv[n][0] += sall[n][0];
        sv[n][1] += sall[n][1];
    }
    #pragma unroll
    for (int d = 0; d < 3; d++) {
        float m = lg[0][d];
        #pragma unroll
        for (int n = 1; n < 8; n++) m = fmaxf(m, lg[n][d]);
        float den = 0.f, num = 0.f;
        #pragma unroll
        for (int n = 0; n < 8; n++) {
            float e = expf(lg[n][d]-m);
            den += e; num += e*sv[n][d];
        }
        out_off[((size_t)b*51 + j*3 + d)*HW + p] = num/den;
    }
}

extern "C" void kernel_launch(void* const* d_in, const int* in_sizes, int n_in,
                              void* d_out, int out_size, void* d_ws, size_t ws_size,
                              hipStream_t stream) {
    const float* feat       = (const float*)d_in[0];
    const float* prev_off   = (const float*)d_in[1];
    const float* dcn_off_w  = (const float*)d_in[2];
    const float* dcn_off_b  = (const float*)d_in[3];
    const float* dcn_w      = (const float*)d_in[4];
    const float* gn_g       = (const float*)d_in[5];
    const float* gn_b       = (const float*)d_in[6];
    const float* so_w       = (const float*)d_in[7];
    const float* so_b       = (const float*)d_in[8];
    const float* sc_w       = (const float*)d_in[9];
    const float* sc_b       = (const float*)d_in[10];
    const float* uw_w       = (const float*)d_in[11];
    const float* uw_b       = (const float*)d_in[12];
    const float* uo_w       = (const float*)d_in[13];
    const float* uo_b       = (const float*)d_in[14];

    float* ws = (float*)d_ws;
    float* off27     = ws;                       // 884736 floats
    float* Wt        = off27 + 884736;           // pack region
    short* Wp        = (short*)Wt;               // 589824 shorts (dcn weights)
    short* Ap        = Wp + 589824;              // 73728 shorts (conv3x3 weights)
    short* Wc        = Ap + 73728;               // 81920 shorts (1x1 weights)
    float* dcnreg    = Wt + 589824;              // 8388608-float region
    unsigned short* dcn16 = (unsigned short*)dcnreg;   // 8.4M ushorts (bf16)
    float* partial   = dcnreg + 8388608;         // 2048
    float* SO        = partial + 2048;           // 4456448 (8*17*4096*8)
    float* UC        = SO + 4456448;             // 4456448

    // featT aliases SO (dead after dcn_kernel; SO written by fused_tail)
    unsigned short* featT = (unsigned short*)SO;

    float* out_feat = (float*)d_out;             // 8388608
    float* out_off  = out_feat + 8388608;        // 1671168

    // K0: NCHW f32 -> NHWC bf16 transpose
    nhwc_kernel<<<dim3(BB*64), dim3(256), 0, stream>>>(feat, featT);
    // packs
    cpack_kernel<<<dim3(36), dim3(256), 0, stream>>>(dcn_off_w, Ap);
    wpack_kernel<<<dim3(288), dim3(256), 0, stream>>>(dcn_w, Wp);
    wpack4_kernel<<<dim3(40), dim3(256), 0, stream>>>(so_w, sc_w, uw_w, uo_w, Wc);
    // K1: offset conv (3x3, MFMA)
    conv3x3_kernel<<<dim3(BB*64), dim3(256), 0, stream>>>(featT, Ap, dcn_off_b, off27);
    // K2: DCN (MFMA, bf16 output)
    dcn_kernel<<<dim3(BB*64), dim3(512), 0, stream>>>(featT, off27, Wp, dcn16);
    // K3: GroupNorm partials (bf16 input)
    gn_partial_kernel<<<dim3(1024), dim3(256), 0, stream>>>(dcn16, partial);
    // K5: fused GN + residual + 1x1 convs + offset blend -> packed SO/UC
    fused_tail_kernel<<<dim3(512), dim3(512), 0, stream>>>(feat, dcn16, partial,
        gn_g, gn_b, Wc, so_b, sc_b, uw_b, uo_b, prev_off,
        out_feat, SO, UC);
    // K7: fused double grid-sample + softmax reduction (packed gathers)
    final_kernel<<<dim3(2176), dim3(256), 0, stream>>>(UC, SO, out_off);
}

// Round 10
// 192.713 us; speedup vs baseline: 6.5282x; 1.0006x over previous
//
#include <hip/hip_runtime.h>
#include <hip/hip_bf16.h>
#include <math.h>

// Problem constants: B=8, C=256, H=W=64, J=17, Hd=4, dim=3
#define HH 64
#define WW 64
#define HW 4096
#define CC 256
#define BB 8
#define JJ 17

typedef __attribute__((ext_vector_type(8))) short bf16x8;
typedef __attribute__((ext_vector_type(4))) float f32x4;

#define SLD 264    // dcn LDS row stride (shorts): 132 dw == 4 mod 32 -> clean 2-way b128 reads
#define SLDF 266   // fused_tail stride (shorts): 133 dw == 5 mod 32 -> 2-way px-major writes
#define CST 136    // conv3x3 strip c-stride in shorts
#define TLD 266    // transpose LDS stride in shorts

struct Bil { int i00,i01,i10,i11; float w00,w01,w10,w11; };

__device__ inline Bil bilin(float sx, float sy) {
    float x0f = floorf(sx), y0f = floorf(sy);
    float wx1 = sx - x0f, wy1 = sy - y0f;
    float wx0 = 1.f - wx1, wy0 = 1.f - wy1;
    int x0 = (int)x0f, y0 = (int)y0f;
    int x1 = x0 + 1, y1 = y0 + 1;
    bool vx0 = (unsigned)x0 < (unsigned)WW;
    bool vx1 = (unsigned)x1 < (unsigned)WW;
    bool vy0 = (unsigned)y0 < (unsigned)HH;
    bool vy1 = (unsigned)y1 < (unsigned)HH;
    int x0c = min(max(x0,0),WW-1), x1c = min(max(x1,0),WW-1);
    int y0c = min(max(y0,0),HH-1), y1c = min(max(y1,0),HH-1);
    Bil b;
    b.i00 = y0c*WW + x0c; b.i01 = y0c*WW + x1c;
    b.i10 = y1c*WW + x0c; b.i11 = y1c*WW + x1c;
    b.w00 = wx0*wy0*((vx0&&vy0)?1.f:0.f);
    b.w01 = wx1*wy0*((vx1&&vy0)?1.f:0.f);
    b.w10 = wx0*wy1*((vx0&&vy1)?1.f:0.f);
    b.w11 = wx1*wy1*((vx1&&vy1)?1.f:0.f);
    return b;
}

__device__ inline unsigned short f2bf(float f) {
    unsigned u = __float_as_uint(f);
    unsigned r = (u + 0x7fffu + ((u >> 16) & 1u)) >> 16;
    return (unsigned short)r;
}
__device__ inline unsigned cvt_pk_bf16(float lo, float hi) {
    unsigned r;
    asm("v_cvt_pk_bf16_f32 %0, %1, %2" : "=v"(r) : "v"(lo), "v"(hi));
    return r;
}
__device__ inline float bflo(unsigned u) { return __uint_as_float(u << 16); }
__device__ inline float bfhi(unsigned u) { return __uint_as_float(u & 0xFFFF0000u); }
__device__ inline float bf2f(unsigned short us) { return __uint_as_float(((unsigned)us) << 16); }

struct F8 { float4 a, b; };
__device__ inline F8 ld8(const float* p) {
    F8 r; r.a = *(const float4*)p; r.b = *(const float4*)(p + 4); return r;
}
__device__ inline void gsample8(const float* base, const Bil& bl, float out[8]) {
    F8 v00 = ld8(base + (size_t)bl.i00*8);
    F8 v01 = ld8(base + (size_t)bl.i01*8);
    F8 v10 = ld8(base + (size_t)bl.i10*8);
    F8 v11 = ld8(base + (size_t)bl.i11*8);
    const float* p00 = (const float*)&v00;
    const float* p01 = (const float*)&v01;
    const float* p10 = (const float*)&v10;
    const float* p11 = (const float*)&v11;
    #pragma unroll
    for (int i = 0; i < 8; i++)
        out[i] = bl.w00*p00[i] + bl.w01*p01[i] + bl.w10*p10[i] + bl.w11*p11[i];
}

// K0: transpose feat (NCHW f32) -> featT (N,px,c) bf16.
__global__ __launch_bounds__(256) void nhwc_kernel(
        const float* __restrict__ feat, unsigned short* __restrict__ featT) {
    __shared__ unsigned short T[64*TLD];   // 34 KB
    int b = blockIdx.x >> 6, p0 = (blockIdx.x & 63)*64;
    int t = threadIdx.x;
    int x = t & 63, c4 = t >> 6;
    const float* fb = feat + (size_t)b*CC*HW + p0;
    #pragma unroll 4
    for (int cp = 0; cp < 256; cp += 4) {
        int c = cp + c4;
        T[x*TLD + c] = f2bf(fb[(size_t)c*HW + x]);
    }
    __syncthreads();
    int xq = t >> 5, cl = t & 31;
    unsigned short* dst = featT + ((size_t)b*HW + p0)*256;
    #pragma unroll
    for (int w = 0; w < 8; w++) {
        int xr = w*8 + xq;
        *(uint4*)(dst + (size_t)xr*256 + cl*8) = *(const uint4*)(T + xr*TLD + cl*8);
    }
}

// K1a: pack dcn_off_w into MFMA A-fragment order, bf16.
__global__ void cpack_kernel(const float* __restrict__ w, short* __restrict__ Ap) {
    int idx = blockIdx.x*256 + threadIdx.x;   // 9216
    if (idx >= 9*2*8*64) return;
    int l  = idx & 63;
    int cs = (idx >> 6) & 7;
    int mt = (idx >> 9) & 1;
    int k  = idx >> 10;
    int oc = mt*16 + (l & 15);
    int c0 = cs*32 + (l >> 4)*8;
    short* dst = Ap + (size_t)idx*8;
    #pragma unroll
    for (int i = 0; i < 8; i++) {
        float v = (oc < 27) ? w[((size_t)(oc*256 + c0 + i)*3 + k/3)*3 + (k % 3)] : 0.f;
        dst[i] = (short)f2bf(v);
    }
}

// K1: 3x3 conv featT -> off27 via MFMA on a 3-row strip.
__global__ __launch_bounds__(256, 3) void conv3x3_kernel(
        const unsigned short* __restrict__ featT, const short* __restrict__ Ap,
        const float* __restrict__ bias, float* __restrict__ off27) {
    __shared__ __align__(16) short S[3*66*CST];   // 52.6 KB
    int orig = blockIdx.x;                        // 512 blocks
    int blk = (orig & 7)*64 + (orig >> 3);        // XCD swizzle
    int b = blk >> 6, row = blk & 63;
    int t = threadIdx.x;
    int l = t & 63, wv = t >> 6;

    f32x4 acc[2];
    acc[0] = (f32x4){0.f,0.f,0.f,0.f};
    acc[1] = (f32x4){0.f,0.f,0.f,0.f};
    const unsigned short* fb = featT + (size_t)b*HW*256;

    for (int ch = 0; ch < 2; ch++) {
        for (int i = t; i < 3*66*16; i += 256) {
            int cc = i & 15;
            int rp = i >> 4;
            int r = rp / 66, px_s = rp - r*66;
            int yy = row + r - 1;
            int xx = px_s - 1;
            uint4 v = (uint4){0u,0u,0u,0u};
            if ((unsigned)yy < 64u && (unsigned)xx < 64u)
                v = *(const uint4*)(fb + ((size_t)(yy*64 + xx))*256 + ch*128 + cc*8);
            *(uint4*)(&S[(r*66 + px_s)*CST + cc*8]) = v;
        }
        __syncthreads();
        #pragma unroll
        for (int k = 0; k < 9; k++) {
            int ky = k/3, kx = k%3;
            const short* srow = S + (ky*66 + wv*16 + (l & 15) + kx)*CST + (l >> 4)*8;
            #pragma unroll
            for (int csl = 0; csl < 4; csl++) {
                bf16x8 bfrag = *(const bf16x8*)(srow + csl*32);
                int cs = ch*4 + csl;
                const short* ap = Ap + ((size_t)((k*2)*8 + cs)*64 + l)*8;
                bf16x8 a0 = *(const bf16x8*)ap;
                bf16x8 a1 = *(const bf16x8*)(ap + 8*64*8);
                acc[0] = __builtin_amdgcn_mfma_f32_16x16x32_bf16(a0, bfrag, acc[0], 0, 0, 0);
                acc[1] = __builtin_amdgcn_mfma_f32_16x16x32_bf16(a1, bfrag, acc[1], 0, 0, 0);
            }
        }
        __syncthreads();
    }
    #pragma unroll
    for (int mt = 0; mt < 2; mt++)
        #pragma unroll
        for (int r = 0; r < 4; r++) {
            int oc = mt*16 + (l >> 4)*4 + r;
            if (oc < 27)
                off27[((size_t)(b*27 + oc))*HW + row*64 + wv*16 + (l & 15)]
                    = acc[mt][r] + bias[oc];
        }
}

// K1b: pack dcn_w into MFMA fragment order, bf16 (A operand).
__global__ void wpack_kernel(const float* __restrict__ w, short* __restrict__ Wp) {
    int idx = blockIdx.x*256 + threadIdx.x;   // 73728
    if (idx >= 9*8*16*64) return;
    int l  = idx & 63;
    int ot = (idx >> 6) & 15;
    int cs = (idx >> 10) & 7;
    int k  = idx >> 13;
    int oc = ot*16 + (l & 15);
    int c0 = cs*32 + (l >> 4)*8;
    short* dst = Wp + (size_t)idx*8;
    #pragma unroll
    for (int i = 0; i < 8; i++) {
        float v = w[((size_t)(oc*256 + c0 + i)*3 + k/3)*3 + (k % 3)];
        dst[i] = (short)f2bf(v);
    }
}

// K1c: pack the four 1x1-conv weights into MFMA A-fragment order (320 oc).
__global__ void wpack4_kernel(const float* __restrict__ so_w, const float* __restrict__ sc_w,
        const float* __restrict__ uw_w, const float* __restrict__ uo_w,
        short* __restrict__ Wc) {
    int idx = blockIdx.x*256 + threadIdx.x;   // 10240
    if (idx >= 8*20*64) return;
    int l  = idx & 63;
    int ot = (idx >> 6) % 20;
    int cs = idx / (64*20);
    int g  = ot*16 + (l & 15);
    int c0 = cs*32 + (l >> 4)*8;
    const float* src = nullptr; int oc = 0;
    if (g < 136)      { src = so_w; oc = g; }
    else if (g < 187) { src = sc_w; oc = g - 136; }
    else if (g < 238) { src = uw_w; oc = g - 187; }
    else if (g < 289) { src = uo_w; oc = g - 238; }
    short* dst = Wc + (size_t)idx*8;
    #pragma unroll
    for (int i = 0; i < 8; i++)
        dst[i] = src ? (short)f2bf(src[(size_t)oc*256 + c0 + i]) : (short)0;
}

// K2: fused DCNv2. 64 px x 256 oc per block, 1024 thr / 16 waves, grid 512
// -> 2 blocks/CU = 32 waves/CU for gather-latency hiding.
__global__ __launch_bounds__(1024, 8) void dcn_kernel(
        const unsigned short* __restrict__ featT, const float* __restrict__ off27,
        const short* __restrict__ Wp, unsigned short* __restrict__ dcn16) {
    __shared__ __align__(16) short S[64*SLD];   // 33.8 KB

    int orig = blockIdx.x;                 // 512 blocks
    int blk  = (orig & 7)*64 + (orig >> 3);   // XCD swizzle: xcd == batch
    int b   = blk >> 6;
    int row = blk & 63;

    int t   = threadIdx.x;
    int px  = t >> 4;          // 0..63: one pixel per 16-lane group
    int cl  = t & 15;          // c-chunk (8 ch)
    int l   = t & 63, wv = t >> 6;   // 16 waves: wv owns oc tile wv*16

    f32x4 acc[4];
    #pragma unroll
    for (int j = 0; j < 4; j++) acc[j] = (f32x4){0.f,0.f,0.f,0.f};

    const unsigned short* fT = featT + (size_t)b*HW*256;
    const float* offb = off27 + (size_t)b*27*HW;
    int p = row*64 + px;

    for (int k = 0; k < 9; k++) {
        int kx = k % 3 - 1, ky = k / 3 - 1;
        float dyv = offb[(size_t)k*HW + p];
        float dxv = offb[(size_t)(9 + k)*HW + p];
        float mk  = offb[(size_t)(18 + k)*HW + p];
        float m = 1.f/(1.f + expf(-mk));
        Bil bl = bilin((float)(px + kx) + dxv, (float)(row + ky) + dyv);
        float w00 = bl.w00*m, w01 = bl.w01*m, w10 = bl.w10*m, w11 = bl.w11*m;
        #pragma unroll
        for (int cp = 0; cp < 2; cp++) {
            int c0 = cp*128 + cl*8;
            uint4 u00 = *(const uint4*)(fT + (size_t)bl.i00*256 + c0);
            uint4 u01 = *(const uint4*)(fT + (size_t)bl.i01*256 + c0);
            uint4 u10 = *(const uint4*)(fT + (size_t)bl.i10*256 + c0);
            uint4 u11 = *(const uint4*)(fT + (size_t)bl.i11*256 + c0);
            const unsigned* a00 = (const unsigned*)&u00;
            const unsigned* a01 = (const unsigned*)&u01;
            const unsigned* a10 = (const unsigned*)&u10;
            const unsigned* a11 = (const unsigned*)&u11;
            uint4 outp;
            unsigned* op = (unsigned*)&outp;
            #pragma unroll
            for (int q = 0; q < 4; q++) {
                float vlo = w00*bflo(a00[q]) + w01*bflo(a01[q])
                          + w10*bflo(a10[q]) + w11*bflo(a11[q]);
                float vhi = w00*bfhi(a00[q]) + w01*bfhi(a01[q])
                          + w10*bfhi(a10[q]) + w11*bfhi(a11[q]);
                op[q] = cvt_pk_bf16(vlo, vhi);
            }
            *(uint4*)(S + px*SLD + c0) = outp;
        }
        __syncthreads();

        const short* wpk = Wp + (size_t)k*8*16*64*8;
        for (int cs = 0; cs < 8; cs++) {
            bf16x8 wa = *(const bf16x8*)(wpk + ((size_t)((cs*16 + wv)*64 + l))*8);
            bf16x8 sb[4];
            #pragma unroll
            for (int pt = 0; pt < 4; pt++)
                sb[pt] = *(const bf16x8*)(S + (pt*16 + (l & 15))*SLD
                                            + cs*32 + (l >> 4)*8);
            #pragma unroll
            for (int pt = 0; pt < 4; pt++)
                acc[pt] = __builtin_amdgcn_mfma_f32_16x16x32_bf16(
                    wa, sb[pt], acc[pt], 0, 0, 0);
        }
        __syncthreads();
    }

    // D: col(l&15)=px-in-tile, row=(l>>4)*4+r=oc-in-tile
    #pragma unroll
    for (int pt = 0; pt < 4; pt++)
        #pragma unroll
        for (int r = 0; r < 4; r++) {
            int oc = wv*16 + (l >> 4)*4 + r;
            int pxo = pt*16 + (l & 15);
            dcn16[((size_t)(b*256 + oc))*HW + row*64 + pxo] = f2bf(acc[pt][r]);
        }
}

// K3: GroupNorm partial sums from bf16 dcn: 1024 blocks, 2 channels each.
__global__ __launch_bounds__(256) void gn_partial_kernel(
        const unsigned short* __restrict__ dcn16, float* __restrict__ partial) {
    int blk = blockIdx.x;
    const uint4* base = (const uint4*)(dcn16 + (size_t)blk*2*HW);
    float s = 0.f, s2 = 0.f;
    #pragma unroll
    for (int j = 0; j < 4; j++) {
        uint4 v = base[threadIdx.x + j*256];
        const unsigned* u = (const unsigned*)&v;
        #pragma unroll
        for (int q = 0; q < 4; q++) {
            float lo = bflo(u[q]), hi = bfhi(u[q]);
            s += lo + hi; s2 += lo*lo + hi*hi;
        }
    }
    __shared__ float rs[256], rs2[256];
    rs[threadIdx.x] = s; rs2[threadIdx.x] = s2; __syncthreads();
    for (int o = 128; o > 0; o >>= 1) {
        if (threadIdx.x < o) { rs[threadIdx.x] += rs[threadIdx.x+o]; rs2[threadIdx.x] += rs2[threadIdx.x+o]; }
        __syncthreads();
    }
    if (threadIdx.x == 0) { partial[blk*2] = rs[0]; partial[blk*2+1] = rs2[0]; }
}

// K5: fused GN-apply + residual (-> out_feat) + 1x1 convs + offset blend.
__global__ __launch_bounds__(512, 2) void fused_tail_kernel(
        const float* __restrict__ feat, const unsigned short* __restrict__ dcn16,
        const float* __restrict__ partial, const float* __restrict__ gn_g,
        const float* __restrict__ gn_b, const short* __restrict__ Wc,
        const float* __restrict__ so_b, const float* __restrict__ sc_b,
        const float* __restrict__ uw_b, const float* __restrict__ uo_b,
        const float* __restrict__ prev_off,
        float* __restrict__ out_feat, float* __restrict__ SO,
        float* __restrict__ UC) {
    __shared__ __align__(16) short S[64*SLDF];  // 34 KB; overlaid by U after GEMM
    __shared__ float gstat[32][2];
    float* U = (float*)S;                       // [102][64] floats

    int orig = blockIdx.x;                      // 512 blocks
    int blk = (orig & 7)*64 + (orig >> 3);      // XCD swizzle
    int b = blk >> 6, row = blk & 63;
    int t = threadIdx.x;

    if (t < 32) {
        const float* pp = partial + (size_t)(b*32 + t)*8;
        float s  = pp[0] + pp[2] + pp[4] + pp[6];
        float s2 = pp[1] + pp[3] + pp[5] + pp[7];
        float inv = 1.f/(8.f*HW);
        float mu = s*inv;
        float var = s2*inv - mu*mu;
        gstat[t][0] = mu;
        gstat[t][1] = rsqrtf(var + 1e-5f);
    }
    __syncthreads();

    int x = t & 63, cq = t >> 6;
    int l = t & 63, wv = t >> 6;
    const float* fb = feat + (size_t)b*CC*HW + row*64;
    const unsigned short* db = dcn16 + (size_t)b*CC*HW + row*64;
    float* ob = out_feat + (size_t)b*CC*HW + row*64;
    #pragma unroll
    for (int j = 0; j < 8; j++) {
        int c0 = cq*32 + j*4;
        float fv[4];
        #pragma unroll
        for (int q = 0; q < 4; q++) {
            int c = c0 + q;
            float mu = gstat[c >> 3][0], rstd = gstat[c >> 3][1];
            float v = (bf2f(db[(size_t)c*HW + x]) - mu)*rstd*gn_g[c] + gn_b[c];
            fv[q] = fb[(size_t)c*HW + x] + fmaxf(v, 0.f);
            ob[(size_t)c*HW + x] = fv[q];
        }
        uint2 pk;
        pk.x = cvt_pk_bf16(fv[0], fv[1]);
        pk.y = cvt_pk_bf16(fv[2], fv[3]);
        *(uint2*)(S + x*SLDF + c0) = pk;
    }
    __syncthreads();

    f32x4 acc[3][4];
    #pragma unroll
    for (int j = 0; j < 3; j++)
        #pragma unroll
        for (int pt = 0; pt < 4; pt++) acc[j][pt] = (f32x4){0.f,0.f,0.f,0.f};

    for (int cs = 0; cs < 8; cs++) {
        bf16x8 bg[4];
        #pragma unroll
        for (int pt = 0; pt < 4; pt++)
            bg[pt] = *(const bf16x8*)(S + (pt*16 + (l & 15))*SLDF
                                        + cs*32 + (l >> 4)*8);
        #pragma unroll
        for (int j = 0; j < 3; j++) {
            int tile = wv + j*8;
            if (tile < 20) {
                bf16x8 a = *(const bf16x8*)(Wc + ((size_t)(cs*20 + tile)*64 + l)*8);
                #pragma unroll
                for (int pt = 0; pt < 4; pt++)
                    acc[j][pt] = __builtin_amdgcn_mfma_f32_16x16x32_bf16(
                        a, bg[pt], acc[j][pt], 0, 0, 0);
            }
        }
    }
    __syncthreads();   // S dead; U live

    #pragma unroll
    for (int j = 0; j < 3; j++) {
        int tile = wv + j*8;
        if (tile < 20) {
            #pragma unroll
            for (int pt = 0; pt < 4; pt++) {
                int px = pt*16 + (l & 15);
                int p = row*64 + px;
                #pragma unroll
                for (int r = 0; r < 4; r++) {
                    int oc = tile*16 + (l >> 4)*4 + r;
                    float v = acc[j][pt][r];
                    if (oc < 136) {
                        SO[(((size_t)(b*JJ + (oc >> 3))*HW) + p)*8 + (oc & 7)] = v + so_b[oc];
                    } else if (oc < 187) {
                        int o2 = oc - 136;
                        int jj = o2/3, d = o2 - jj*3;
                        UC[(((size_t)(b*JJ + jj)*HW) + p)*8 + 3 + d] = v + sc_b[o2];
                    } else if (oc < 238) {
                        U[(oc-187)*64 + px] = v + uw_b[oc-187];
                    } else if (oc < 289) {
                        U[(51 + oc-238)*64 + px] = v + uo_b[oc-238];
                    }
                }
            }
        }
    }
    __syncthreads();

    const float* pb = prev_off + (size_t)b*51*HW + row*64;
    for (int i = t; i < 51*64; i += 512) {
        int dful = i >> 6, px = i & 63;
        int jj = dful/3, d = dful - jj*3;
        int p = row*64 + px;
        float owv = 1.f/(1.f + expf(-U[dful*64 + px]));
        float blend = (1.f - owv)*pb[(size_t)dful*HW + px] + owv*U[(51 + dful)*64 + px];
        UC[(((size_t)(b*JJ + jj)*HW) + p)*8 + d] = blend;
    }
}

// K7: fused sampling + softmax-weighted sum -> new_off (output 1).
__global__ __launch_bounds__(256) void final_kernel(
        const float* __restrict__ UC, const float* __restrict__ SO,
        float* __restrict__ out_off) {
    int orig = blockIdx.x;                   // 0..2175
    int wg = (orig & 7)*272 + (orig >> 3);   // 272 = 17*16 per batch
    int b = wg / 272;
    int rem = wg - b*272;
    int j = rem >> 4;
    int p = (rem & 15)*256 + threadIdx.x;
    int y = p >> 6, x = p & 63;
    const float* ucb = UC + (size_t)(b*JJ + j)*HW*8;
    const float* sob = SO + (size_t)(b*JJ + j)*HW*8;

    float4 own = *(const float4*)(ucb + (size_t)p*8);
    float offx = own.x, offy = own.y;
    F8 sod = ld8(sob + (size_t)p*8);
    const float* sodp = (const float*)&sod;

    Bil bl = bilin((float)x + offx, (float)y + offy);
    float s8[8];
    gsample8(sob, bl, s8);

    float sall[8][2];
    #pragma unroll
    for (int h = 0; h < 4; h++) {
        sall[h][0]   = s8[2*h]   + offx;
        sall[h][1]   = s8[2*h+1] + offy;
        sall[4+h][0] = sodp[2*h];
        sall[4+h][1] = sodp[2*h+1];
    }

    float sv[8][3], lg[8][3];
    #pragma unroll
    for (int n = 0; n < 8; n++) {
        Bil b2 = bilin((float)x + sall[n][0], (float)y + sall[n][1]);
        float v8[8];
        gsample8(ucb, b2, v8);
        #pragma unroll
        for (int d = 0; d < 3; d++) {
            sv[n][d] = v8[d];
            lg[n][d] = v8[3 + d];
        }
        sv[n][0] += sall[n][0];
        sv[n][1] += sall[n][1];
    }
    #pragma unroll
    for (int d = 0; d < 3; d++) {
        float m = lg[0][d];
        #pragma unroll
        for (int n = 1; n < 8; n++) m = fmaxf(m, lg[n][d]);
        float den = 0.f, num = 0.f;
        #pragma unroll
        for (int n = 0; n < 8; n++) {
            float e = expf(lg[n][d]-m);
            den += e; num += e*sv[n][d];
        }
        out_off[((size_t)b*51 + j*3 + d)*HW + p] = num/den;
    }
}

extern "C" void kernel_launch(void* const* d_in, const int* in_sizes, int n_in,
                              void* d_out, int out_size, void* d_ws, size_t ws_size,
                              hipStream_t stream) {
    const float* feat       = (const float*)d_in[0];
    const float* prev_off   = (const float*)d_in[1];
    const float* dcn_off_w  = (const float*)d_in[2];
    const float* dcn_off_b  = (const float*)d_in[3];
    const float* dcn_w      = (const float*)d_in[4];
    const float* gn_g       = (const float*)d_in[5];
    const float* gn_b       = (const float*)d_in[6];
    const float* so_w       = (const float*)d_in[7];
    const float* so_b       = (const float*)d_in[8];
    const float* sc_w       = (const float*)d_in[9];
    const float* sc_b       = (const float*)d_in[10];
    const float* uw_w       = (const float*)d_in[11];
    const float* uw_b       = (const float*)d_in[12];
    const float* uo_w       = (const float*)d_in[13];
    const float* uo_b       = (const float*)d_in[14];

    float* ws = (float*)d_ws;
    float* off27     = ws;                       // 884736 floats
    float* Wt        = off27 + 884736;           // pack region
    short* Wp        = (short*)Wt;               // 589824 shorts (dcn weights)
    short* Ap        = Wp + 589824;              // 73728 shorts (conv3x3 weights)
    short* Wc        = Ap + 73728;               // 81920 shorts (1x1 weights)
    float* dcnreg    = Wt + 589824;              // 8388608-float region
    unsigned short* dcn16 = (unsigned short*)dcnreg;   // 8.4M ushorts (bf16)
    float* partial   = dcnreg + 8388608;         // 2048
    float* SO        = partial + 2048;           // 4456448 (8*17*4096*8)
    float* UC        = SO + 4456448;             // 4456448

    // featT aliases SO (dead after dcn_kernel; SO written by fused_tail)
    unsigned short* featT = (unsigned short*)SO;

    float* out_feat = (float*)d_out;             // 8388608
    float* out_off  = out_feat + 8388608;        // 1671168

    // K0: NCHW f32 -> NHWC bf16 transpose
    nhwc_kernel<<<dim3(BB*64), dim3(256), 0, stream>>>(feat, featT);
    // packs
    cpack_kernel<<<dim3(36), dim3(256), 0, stream>>>(dcn_off_w, Ap);
    wpack_kernel<<<dim3(288), dim3(256), 0, stream>>>(dcn_w, Wp);
    wpack4_kernel<<<dim3(40), dim3(256), 0, stream>>>(so_w, sc_w, uw_w, uo_w, Wc);
    // K1: offset conv (3x3, MFMA)
    conv3x3_kernel<<<dim3(BB*64), dim3(256), 0, stream>>>(featT, Ap, dcn_off_b, off27);
    // K2: DCN (MFMA, 1024 thr, 32 waves/CU)
    dcn_kernel<<<dim3(BB*64), dim3(1024), 0, stream>>>(featT, off27, Wp, dcn16);
    // K3: GroupNorm partials (bf16 input)
    gn_partial_kernel<<<dim3(1024), dim3(256), 0, stream>>>(dcn16, partial);
    // K5: fused GN + residual + 1x1 convs + offset blend -> packed SO/UC
    fused_tail_kernel<<<dim3(512), dim3(512), 0, stream>>>(feat, dcn16, partial,
        gn_g, gn_b, Wc, so_b, sc_b, uw_b, uo_b, prev_off,
        out_feat, SO, UC);
    // K7: fused double grid-sample + softmax reduction (packed gathers)
    final_kernel<<<dim3(2176), dim3(256), 0, stream>>>(UC, SO, out_off);
}

// Round 11
// 190.157 us; speedup vs baseline: 6.6159x; 1.0134x over previous
//
#include <hip/hip_runtime.h>
#include <hip/hip_bf16.h>
#include <math.h>

// Problem constants: B=8, C=256, H=W=64, J=17, Hd=4, dim=3
#define HH 64
#define WW 64
#define HW 4096
#define CC 256
#define BB 8
#define JJ 17

typedef __attribute__((ext_vector_type(8))) short bf16x8;
typedef __attribute__((ext_vector_type(4))) float f32x4;

#define SLDD 136   // dcn half-K stride (shorts): 68 dw == 4 mod 32 (R8-class, benign)
#define SLDF 266   // fused_tail stride (shorts): 133 dw == 5 mod 32
#define CST 136    // conv3x3 strip c-stride in shorts
#define TLD 266    // transpose LDS stride in shorts

struct Bil { int i00,i01,i10,i11; float w00,w01,w10,w11; };

__device__ inline Bil bilin(float sx, float sy) {
    float x0f = floorf(sx), y0f = floorf(sy);
    float wx1 = sx - x0f, wy1 = sy - y0f;
    float wx0 = 1.f - wx1, wy0 = 1.f - wy1;
    int x0 = (int)x0f, y0 = (int)y0f;
    int x1 = x0 + 1, y1 = y0 + 1;
    bool vx0 = (unsigned)x0 < (unsigned)WW;
    bool vx1 = (unsigned)x1 < (unsigned)WW;
    bool vy0 = (unsigned)y0 < (unsigned)HH;
    bool vy1 = (unsigned)y1 < (unsigned)HH;
    int x0c = min(max(x0,0),WW-1), x1c = min(max(x1,0),WW-1);
    int y0c = min(max(y0,0),HH-1), y1c = min(max(y1,0),HH-1);
    Bil b;
    b.i00 = y0c*WW + x0c; b.i01 = y0c*WW + x1c;
    b.i10 = y1c*WW + x0c; b.i11 = y1c*WW + x1c;
    b.w00 = wx0*wy0*((vx0&&vy0)?1.f:0.f);
    b.w01 = wx1*wy0*((vx1&&vy0)?1.f:0.f);
    b.w10 = wx0*wy1*((vx0&&vy1)?1.f:0.f);
    b.w11 = wx1*wy1*((vx1&&vy1)?1.f:0.f);
    return b;
}

__device__ inline unsigned short f2bf(float f) {
    unsigned u = __float_as_uint(f);
    unsigned r = (u + 0x7fffu + ((u >> 16) & 1u)) >> 16;
    return (unsigned short)r;
}
__device__ inline unsigned cvt_pk_bf16(float lo, float hi) {
    unsigned r;
    asm("v_cvt_pk_bf16_f32 %0, %1, %2" : "=v"(r) : "v"(lo), "v"(hi));
    return r;
}
__device__ inline float bflo(unsigned u) { return __uint_as_float(u << 16); }
__device__ inline float bfhi(unsigned u) { return __uint_as_float(u & 0xFFFF0000u); }
__device__ inline float bf2f(unsigned short us) { return __uint_as_float(((unsigned)us) << 16); }

struct F8 { float4 a, b; };
__device__ inline F8 ld8(const float* p) {
    F8 r; r.a = *(const float4*)p; r.b = *(const float4*)(p + 4); return r;
}
__device__ inline void gsample8(const float* base, const Bil& bl, float out[8]) {
    F8 v00 = ld8(base + (size_t)bl.i00*8);
    F8 v01 = ld8(base + (size_t)bl.i01*8);
    F8 v10 = ld8(base + (size_t)bl.i10*8);
    F8 v11 = ld8(base + (size_t)bl.i11*8);
    const float* p00 = (const float*)&v00;
    const float* p01 = (const float*)&v01;
    const float* p10 = (const float*)&v10;
    const float* p11 = (const float*)&v11;
    #pragma unroll
    for (int i = 0; i < 8; i++)
        out[i] = bl.w00*p00[i] + bl.w01*p01[i] + bl.w10*p10[i] + bl.w11*p11[i];
}

// K0: transpose feat (NCHW f32) -> featT (N,px,c) bf16.
__global__ __launch_bounds__(256) void nhwc_kernel(
        const float* __restrict__ feat, unsigned short* __restrict__ featT) {
    __shared__ unsigned short T[64*TLD];   // 34 KB
    int b = blockIdx.x >> 6, p0 = (blockIdx.x & 63)*64;
    int t = threadIdx.x;
    int x = t & 63, c4 = t >> 6;
    const float* fb = feat + (size_t)b*CC*HW + p0;
    #pragma unroll 4
    for (int cp = 0; cp < 256; cp += 4) {
        int c = cp + c4;
        T[x*TLD + c] = f2bf(fb[(size_t)c*HW + x]);
    }
    __syncthreads();
    int xq = t >> 5, cl = t & 31;
    unsigned short* dst = featT + ((size_t)b*HW + p0)*256;
    #pragma unroll
    for (int w = 0; w < 8; w++) {
        int xr = w*8 + xq;
        *(uint4*)(dst + (size_t)xr*256 + cl*8) = *(const uint4*)(T + xr*TLD + cl*8);
    }
}

// K1a: pack dcn_off_w into MFMA A-fragment order, bf16.
__global__ void cpack_kernel(const float* __restrict__ w, short* __restrict__ Ap) {
    int idx = blockIdx.x*256 + threadIdx.x;   // 9216
    if (idx >= 9*2*8*64) return;
    int l  = idx & 63;
    int cs = (idx >> 6) & 7;
    int mt = (idx >> 9) & 1;
    int k  = idx >> 10;
    int oc = mt*16 + (l & 15);
    int c0 = cs*32 + (l >> 4)*8;
    short* dst = Ap + (size_t)idx*8;
    #pragma unroll
    for (int i = 0; i < 8; i++) {
        float v = (oc < 27) ? w[((size_t)(oc*256 + c0 + i)*3 + k/3)*3 + (k % 3)] : 0.f;
        dst[i] = (short)f2bf(v);
    }
}

// K1: 3x3 conv featT -> off27 via MFMA on a 3-row strip.
__global__ __launch_bounds__(256, 3) void conv3x3_kernel(
        const unsigned short* __restrict__ featT, const short* __restrict__ Ap,
        const float* __restrict__ bias, float* __restrict__ off27) {
    __shared__ __align__(16) short S[3*66*CST];   // 52.6 KB
    int orig = blockIdx.x;                        // 512 blocks
    int blk = (orig & 7)*64 + (orig >> 3);        // XCD swizzle
    int b = blk >> 6, row = blk & 63;
    int t = threadIdx.x;
    int l = t & 63, wv = t >> 6;

    f32x4 acc[2];
    acc[0] = (f32x4){0.f,0.f,0.f,0.f};
    acc[1] = (f32x4){0.f,0.f,0.f,0.f};
    const unsigned short* fb = featT + (size_t)b*HW*256;

    for (int ch = 0; ch < 2; ch++) {
        for (int i = t; i < 3*66*16; i += 256) {
            int cc = i & 15;
            int rp = i >> 4;
            int r = rp / 66, px_s = rp - r*66;
            int yy = row + r - 1;
            int xx = px_s - 1;
            uint4 v = (uint4){0u,0u,0u,0u};
            if ((unsigned)yy < 64u && (unsigned)xx < 64u)
                v = *(const uint4*)(fb + ((size_t)(yy*64 + xx))*256 + ch*128 + cc*8);
            *(uint4*)(&S[(r*66 + px_s)*CST + cc*8]) = v;
        }
        __syncthreads();
        #pragma unroll
        for (int k = 0; k < 9; k++) {
            int ky = k/3, kx = k%3;
            const short* srow = S + (ky*66 + wv*16 + (l & 15) + kx)*CST + (l >> 4)*8;
            #pragma unroll
            for (int csl = 0; csl < 4; csl++) {
                bf16x8 bfrag = *(const bf16x8*)(srow + csl*32);
                int cs = ch*4 + csl;
                const short* ap = Ap + ((size_t)((k*2)*8 + cs)*64 + l)*8;
                bf16x8 a0 = *(const bf16x8*)ap;
                bf16x8 a1 = *(const bf16x8*)(ap + 8*64*8);
                acc[0] = __builtin_amdgcn_mfma_f32_16x16x32_bf16(a0, bfrag, acc[0], 0, 0, 0);
                acc[1] = __builtin_amdgcn_mfma_f32_16x16x32_bf16(a1, bfrag, acc[1], 0, 0, 0);
            }
        }
        __syncthreads();
    }
    #pragma unroll
    for (int mt = 0; mt < 2; mt++)
        #pragma unroll
        for (int r = 0; r < 4; r++) {
            int oc = mt*16 + (l >> 4)*4 + r;
            if (oc < 27)
                off27[((size_t)(b*27 + oc))*HW + row*64 + wv*16 + (l & 15)]
                    = acc[mt][r] + bias[oc];
        }
}

// K1b: pack dcn_w into MFMA fragment order, bf16 (A operand).
__global__ void wpack_kernel(const float* __restrict__ w, short* __restrict__ Wp) {
    int idx = blockIdx.x*256 + threadIdx.x;   // 73728
    if (idx >= 9*8*16*64) return;
    int l  = idx & 63;
    int ot = (idx >> 6) & 15;
    int cs = (idx >> 10) & 7;
    int k  = idx >> 13;
    int oc = ot*16 + (l & 15);
    int c0 = cs*32 + (l >> 4)*8;
    short* dst = Wp + (size_t)idx*8;
    #pragma unroll
    for (int i = 0; i < 8; i++) {
        float v = w[((size_t)(oc*256 + c0 + i)*3 + k/3)*3 + (k % 3)];
        dst[i] = (short)f2bf(v);
    }
}

// K1c: pack the four 1x1-conv weights into MFMA A-fragment order (320 oc).
__global__ void wpack4_kernel(const float* __restrict__ so_w, const float* __restrict__ sc_w,
        const float* __restrict__ uw_w, const float* __restrict__ uo_w,
        short* __restrict__ Wc) {
    int idx = blockIdx.x*256 + threadIdx.x;   // 10240
    if (idx >= 8*20*64) return;
    int l  = idx & 63;
    int ot = (idx >> 6) % 20;
    int cs = idx / (64*20);
    int g  = ot*16 + (l & 15);
    int c0 = cs*32 + (l >> 4)*8;
    const float* src = nullptr; int oc = 0;
    if (g < 136)      { src = so_w; oc = g; }
    else if (g < 187) { src = sc_w; oc = g - 136; }
    else if (g < 238) { src = uw_w; oc = g - 187; }
    else if (g < 289) { src = uo_w; oc = g - 238; }
    short* dst = Wc + (size_t)idx*8;
    #pragma unroll
    for (int i = 0; i < 8; i++)
        dst[i] = src ? (short)f2bf(src[(size_t)oc*256 + c0 + i]) : (short)0;
}

// K2: fused DCNv2. 128 px (row pair) x 256 oc per block, 1024 thr / 16 waves,
// grid 256 (1 block/CU). Each wave: 2 oc-tiles x 4 px-tiles. K staged in halves
// (S = [128][SLDD] bf16, 34.8 KB) to stay under the static-LDS cap.
__global__ __launch_bounds__(1024, 4) void dcn_kernel(
        const unsigned short* __restrict__ featT, const float* __restrict__ off27,
        const short* __restrict__ Wp, unsigned short* __restrict__ dcn16) {
    __shared__ __align__(16) short S[128*SLDD];   // 34.8 KB

    int orig = blockIdx.x;                 // 256 blocks
    int blk  = (orig & 7)*32 + (orig >> 3);   // XCD swizzle: xcd == batch
    int b   = blk >> 5;
    int rp  = blk & 31;                    // row pair: rows 2rp, 2rp+1

    int t   = threadIdx.x;
    int pxh = t >> 4;          // 0..63
    int cl  = t & 15;          // c-chunk (8 ch within half)
    int l   = t & 63, wv = t >> 6;        // 16 waves
    int ocp = wv & 7, pxg = wv >> 3;      // 2 oc-tiles {2ocp,2ocp+1}; px-tiles {4pxg..+3}

    f32x4 acc[2][4];
    #pragma unroll
    for (int i = 0; i < 2; i++)
        #pragma unroll
        for (int j = 0; j < 4; j++) acc[i][j] = (f32x4){0.f,0.f,0.f,0.f};

    const unsigned short* fT = featT + (size_t)b*HW*256;
    const float* offb = off27 + (size_t)b*27*HW + rp*128;

    for (int k = 0; k < 9; k++) {
        int kx = k % 3 - 1, ky = k / 3 - 1;
        // per-tap sampling setup for this thread's two pixels (hoisted over halves)
        Bil bl[2]; float w00[2], w01[2], w10[2], w11[2];
        #pragma unroll
        for (int s2 = 0; s2 < 2; s2++) {
            int px_s = s2*64 + pxh;
            float dyv = offb[(size_t)k*HW + px_s];
            float dxv = offb[(size_t)(9 + k)*HW + px_s];
            float mk  = offb[(size_t)(18 + k)*HW + px_s];
            float m = 1.f/(1.f + expf(-mk));
            bl[s2] = bilin((float)((px_s & 63) + kx) + dxv,
                           (float)(2*rp + (px_s >> 6) + ky) + dyv);
            w00[s2] = bl[s2].w00*m; w01[s2] = bl[s2].w01*m;
            w10[s2] = bl[s2].w10*m; w11[s2] = bl[s2].w11*m;
        }
        #pragma unroll
        for (int h = 0; h < 2; h++) {
            // ---- sample half h (128 channels) for both pixels ----
            #pragma unroll
            for (int s2 = 0; s2 < 2; s2++) {
                int px_s = s2*64 + pxh;
                int c0 = h*128 + cl*8;
                uint4 u00 = *(const uint4*)(fT + (size_t)bl[s2].i00*256 + c0);
                uint4 u01 = *(const uint4*)(fT + (size_t)bl[s2].i01*256 + c0);
                uint4 u10 = *(const uint4*)(fT + (size_t)bl[s2].i10*256 + c0);
                uint4 u11 = *(const uint4*)(fT + (size_t)bl[s2].i11*256 + c0);
                const unsigned* a00 = (const unsigned*)&u00;
                const unsigned* a01 = (const unsigned*)&u01;
                const unsigned* a10 = (const unsigned*)&u10;
                const unsigned* a11 = (const unsigned*)&u11;
                uint4 outp;
                unsigned* op = (unsigned*)&outp;
                #pragma unroll
                for (int q = 0; q < 4; q++) {
                    float vlo = w00[s2]*bflo(a00[q]) + w01[s2]*bflo(a01[q])
                              + w10[s2]*bflo(a10[q]) + w11[s2]*bflo(a11[q]);
                    float vhi = w00[s2]*bfhi(a00[q]) + w01[s2]*bfhi(a01[q])
                              + w10[s2]*bfhi(a10[q]) + w11[s2]*bfhi(a11[q]);
                    op[q] = cvt_pk_bf16(vlo, vhi);
                }
                *(uint4*)(S + px_s*SLDD + cl*8) = outp;
            }
            __syncthreads();

            // ---- GEMM over this half's 4 c-slices ----
            #pragma unroll
            for (int csl = 0; csl < 4; csl++) {
                int cs = h*4 + csl;
                bf16x8 wa[2];
                #pragma unroll
                for (int mt = 0; mt < 2; mt++)
                    wa[mt] = *(const bf16x8*)(Wp +
                        ((size_t)((k*8 + cs)*16 + 2*ocp + mt)*64 + l)*8);
                bf16x8 sb[4];
                #pragma unroll
                for (int pt = 0; pt < 4; pt++)
                    sb[pt] = *(const bf16x8*)(S + (pxg*64 + pt*16 + (l & 15))*SLDD
                                                + csl*32 + (l >> 4)*8);
                #pragma unroll
                for (int mt = 0; mt < 2; mt++)
                    #pragma unroll
                    for (int pt = 0; pt < 4; pt++)
                        acc[mt][pt] = __builtin_amdgcn_mfma_f32_16x16x32_bf16(
                            wa[mt], sb[pt], acc[mt][pt], 0, 0, 0);
            }
            __syncthreads();
        }
    }

    // D: col(l&15)=px-in-tile, row=(l>>4)*4+r=oc-in-tile
    #pragma unroll
    for (int mt = 0; mt < 2; mt++)
        #pragma unroll
        for (int pt = 0; pt < 4; pt++)
            #pragma unroll
            for (int r = 0; r < 4; r++) {
                int oc = (2*ocp + mt)*16 + (l >> 4)*4 + r;
                int px_s = pxg*64 + pt*16 + (l & 15);
                dcn16[((size_t)(b*256 + oc))*HW + rp*128 + px_s] = f2bf(acc[mt][pt][r]);
            }
}

// K3: GroupNorm partial sums from bf16 dcn: 1024 blocks, 2 channels each.
__global__ __launch_bounds__(256) void gn_partial_kernel(
        const unsigned short* __restrict__ dcn16, float* __restrict__ partial) {
    int blk = blockIdx.x;
    const uint4* base = (const uint4*)(dcn16 + (size_t)blk*2*HW);
    float s = 0.f, s2 = 0.f;
    #pragma unroll
    for (int j = 0; j < 4; j++) {
        uint4 v = base[threadIdx.x + j*256];
        const unsigned* u = (const unsigned*)&v;
        #pragma unroll
        for (int q = 0; q < 4; q++) {
            float lo = bflo(u[q]), hi = bfhi(u[q]);
            s += lo + hi; s2 += lo*lo + hi*hi;
        }
    }
    __shared__ float rs[256], rs2[256];
    rs[threadIdx.x] = s; rs2[threadIdx.x] = s2; __syncthreads();
    for (int o = 128; o > 0; o >>= 1) {
        if (threadIdx.x < o) { rs[threadIdx.x] += rs[threadIdx.x+o]; rs2[threadIdx.x] += rs2[threadIdx.x+o]; }
        __syncthreads();
    }
    if (threadIdx.x == 0) { partial[blk*2] = rs[0]; partial[blk*2+1] = rs2[0]; }
}

// K5: fused GN-apply + residual (-> out_feat) + 1x1 convs + offset blend.
__global__ __launch_bounds__(512, 2) void fused_tail_kernel(
        const float* __restrict__ feat, const unsigned short* __restrict__ dcn16,
        const float* __restrict__ partial, const float* __restrict__ gn_g,
        const float* __restrict__ gn_b, const short* __restrict__ Wc,
        const float* __restrict__ so_b, const float* __restrict__ sc_b,
        const float* __restrict__ uw_b, const float* __restrict__ uo_b,
        const float* __restrict__ prev_off,
        float* __restrict__ out_feat, float* __restrict__ SO,
        float* __restrict__ UC) {
    __shared__ __align__(16) short S[64*SLDF];  // 34 KB; overlaid by U after GEMM
    __shared__ float gstat[32][2];
    float* U = (float*)S;                       // [102][64] floats

    int orig = blockIdx.x;                      // 512 blocks
    int blk = (orig & 7)*64 + (orig >> 3);      // XCD swizzle
    int b = blk >> 6, row = blk & 63;
    int t = threadIdx.x;

    if (t < 32) {
        const float* pp = partial + (size_t)(b*32 + t)*8;
        float s  = pp[0] + pp[2] + pp[4] + pp[6];
        float s2 = pp[1] + pp[3] + pp[5] + pp[7];
        float inv = 1.f/(8.f*HW);
        float mu = s*inv;
        float var = s2*inv - mu*mu;
        gstat[t][0] = mu;
        gstat[t][1] = rsqrtf(var + 1e-5f);
    }
    __syncthreads();

    int x = t & 63, cq = t >> 6;
    int l = t & 63, wv = t >> 6;
    const float* fb = feat + (size_t)b*CC*HW + row*64;
    const unsigned short* db = dcn16 + (size_t)b*CC*HW + row*64;
    float* ob = out_feat + (size_t)b*CC*HW + row*64;
    #pragma unroll
    for (int j = 0; j < 8; j++) {
        int c0 = cq*32 + j*4;
        float fv[4];
        #pragma unroll
        for (int q = 0; q < 4; q++) {
            int c = c0 + q;
            float mu = gstat[c >> 3][0], rstd = gstat[c >> 3][1];
            float v = (bf2f(db[(size_t)c*HW + x]) - mu)*rstd*gn_g[c] + gn_b[c];
            fv[q] = fb[(size_t)c*HW + x] + fmaxf(v, 0.f);
            ob[(size_t)c*HW + x] = fv[q];
        }
        uint2 pk;
        pk.x = cvt_pk_bf16(fv[0], fv[1]);
        pk.y = cvt_pk_bf16(fv[2], fv[3]);
        *(uint2*)(S + x*SLDF + c0) = pk;
    }
    __syncthreads();

    f32x4 acc[3][4];
    #pragma unroll
    for (int j = 0; j < 3; j++)
        #pragma unroll
        for (int pt = 0; pt < 4; pt++) acc[j][pt] = (f32x4){0.f,0.f,0.f,0.f};

    for (int cs = 0; cs < 8; cs++) {
        bf16x8 bg[4];
        #pragma unroll
        for (int pt = 0; pt < 4; pt++)
            bg[pt] = *(const bf16x8*)(S + (pt*16 + (l & 15))*SLDF
                                        + cs*32 + (l >> 4)*8);
        #pragma unroll
        for (int j = 0; j < 3; j++) {
            int tile = wv + j*8;
            if (tile < 20) {
                bf16x8 a = *(const bf16x8*)(Wc + ((size_t)(cs*20 + tile)*64 + l)*8);
                #pragma unroll
                for (int pt = 0; pt < 4; pt++)
                    acc[j][pt] = __builtin_amdgcn_mfma_f32_16x16x32_bf16(
                        a, bg[pt], acc[j][pt], 0, 0, 0);
            }
        }
    }
    __syncthreads();   // S dead; U live

    #pragma unroll
    for (int j = 0; j < 3; j++) {
        int tile = wv + j*8;
        if (tile < 20) {
            #pragma unroll
            for (int pt = 0; pt < 4; pt++) {
                int px = pt*16 + (l & 15);
                int p = row*64 + px;
                #pragma unroll
                for (int r = 0; r < 4; r++) {
                    int oc = tile*16 + (l >> 4)*4 + r;
                    float v = acc[j][pt][r];
                    if (oc < 136) {
                        SO[(((size_t)(b*JJ + (oc >> 3))*HW) + p)*8 + (oc & 7)] = v + so_b[oc];
                    } else if (oc < 187) {
                        int o2 = oc - 136;
                        int jj = o2/3, d = o2 - jj*3;
                        UC[(((size_t)(b*JJ + jj)*HW) + p)*8 + 3 + d] = v + sc_b[o2];
                    } else if (oc < 238) {
                        U[(oc-187)*64 + px] = v + uw_b[oc-187];
                    } else if (oc < 289) {
                        U[(51 + oc-238)*64 + px] = v + uo_b[oc-238];
                    }
                }
            }
        }
    }
    __syncthreads();

    const float* pb = prev_off + (size_t)b*51*HW + row*64;
    for (int i = t; i < 51*64; i += 512) {
        int dful = i >> 6, px = i & 63;
        int jj = dful/3, d = dful - jj*3;
        int p = row*64 + px;
        float owv = 1.f/(1.f + expf(-U[dful*64 + px]));
        float blend = (1.f - owv)*pb[(size_t)dful*HW + px] + owv*U[(51 + dful)*64 + px];
        UC[(((size_t)(b*JJ + jj)*HW) + p)*8 + d] = blend;
    }
}

// K7: fused sampling + softmax-weighted sum -> new_off (output 1).
__global__ __launch_bounds__(256) void final_kernel(
        const float* __restrict__ UC, const float* __restrict__ SO,
        float* __restrict__ out_off) {
    int orig = blockIdx.x;                   // 0..2175
    int wg = (orig & 7)*272 + (orig >> 3);   // 272 = 17*16 per batch
    int b = wg / 272;
    int rem = wg - b*272;
    int j = rem >> 4;
    int p = (rem & 15)*256 + threadIdx.x;
    int y = p >> 6, x = p & 63;
    const float* ucb = UC + (size_t)(b*JJ + j)*HW*8;
    const float* sob = SO + (size_t)(b*JJ + j)*HW*8;

    float4 own = *(const float4*)(ucb + (size_t)p*8);
    float offx = own.x, offy = own.y;
    F8 sod = ld8(sob + (size_t)p*8);
    const float* sodp = (const float*)&sod;

    Bil bl = bilin((float)x + offx, (float)y + offy);
    float s8[8];
    gsample8(sob, bl, s8);

    float sall[8][2];
    #pragma unroll
    for (int h = 0; h < 4; h++) {
        sall[h][0]   = s8[2*h]   + offx;
        sall[h][1]   = s8[2*h+1] + offy;
        sall[4+h][0] = sodp[2*h];
        sall[4+h][1] = sodp[2*h+1];
    }

    float sv[8][3], lg[8][3];
    #pragma unroll
    for (int n = 0; n < 8; n++) {
        Bil b2 = bilin((float)x + sall[n][0], (float)y + sall[n][1]);
        float v8[8];
        gsample8(ucb, b2, v8);
        #pragma unroll
        for (int d = 0; d < 3; d++) {
            sv[n][d] = v8[d];
            lg[n][d] = v8[3 + d];
        }
        sv[n][0] += sall[n][0];
        sv[n][1] += sall[n][1];
    }
    #pragma unroll
    for (int d = 0; d < 3; d++) {
        float m = lg[0][d];
        #pragma unroll
        for (int n = 1; n < 8; n++) m = fmaxf(m, lg[n][d]);
        float den = 0.f, num = 0.f;
        #pragma unroll
        for (int n = 0; n < 8; n++) {
            float e = expf(lg[n][d]-m);
            den += e; num += e*sv[n][d];
        }
        out_off[((size_t)b*51 + j*3 + d)*HW + p] = num/den;
    }
}

extern "C" void kernel_launch(void* const* d_in, const int* in_sizes, int n_in,
                              void* d_out, int out_size, void* d_ws, size_t ws_size,
                              hipStream_t stream) {
    const float* feat       = (const float*)d_in[0];
    const float* prev_off   = (const float*)d_in[1];
    const float* dcn_off_w  = (const float*)d_in[2];
    const float* dcn_off_b  = (const float*)d_in[3];
    const float* dcn_w      = (const float*)d_in[4];
    const float* gn_g       = (const float*)d_in[5];
    const float* gn_b       = (const float*)d_in[6];
    const float* so_w       = (const float*)d_in[7];
    const float* so_b       = (const float*)d_in[8];
    const float* sc_w       = (const float*)d_in[9];
    const float* sc_b       = (const float*)d_in[10];
    const float* uw_w       = (const float*)d_in[11];
    const float* uw_b       = (const float*)d_in[12];
    const float* uo_w       = (const float*)d_in[13];
    const float* uo_b       = (const float*)d_in[14];

    float* ws = (float*)d_ws;
    float* off27     = ws;                       // 884736 floats
    float* Wt        = off27 + 884736;           // pack region
    short* Wp        = (short*)Wt;               // 589824 shorts (dcn weights)
    short* Ap        = Wp + 589824;              // 73728 shorts (conv3x3 weights)
    short* Wc        = Ap + 73728;               // 81920 shorts (1x1 weights)
    float* dcnreg    = Wt + 589824;              // 8388608-float region
    unsigned short* dcn16 = (unsigned short*)dcnreg;   // 8.4M ushorts (bf16)
    float* partial   = dcnreg + 8388608;         // 2048
    float* SO        = partial + 2048;           // 4456448 (8*17*4096*8)
    float* UC        = SO + 4456448;             // 4456448

    // featT aliases SO (dead after dcn_kernel; SO written by fused_tail)
    unsigned short* featT = (unsigned short*)SO;

    float* out_feat = (float*)d_out;             // 8388608
    float* out_off  = out_feat + 8388608;        // 1671168

    // K0: NCHW f32 -> NHWC bf16 transpose
    nhwc_kernel<<<dim3(BB*64), dim3(256), 0, stream>>>(feat, featT);
    // packs
    cpack_kernel<<<dim3(36), dim3(256), 0, stream>>>(dcn_off_w, Ap);
    wpack_kernel<<<dim3(288), dim3(256), 0, stream>>>(dcn_w, Wp);
    wpack4_kernel<<<dim3(40), dim3(256), 0, stream>>>(so_w, sc_w, uw_w, uo_w, Wc);
    // K1: offset conv (3x3, MFMA)
    conv3x3_kernel<<<dim3(BB*64), dim3(256), 0, stream>>>(featT, Ap, dcn_off_b, off27);
    // K2: DCN (MFMA, 128-px blocks, 1024 thr, half-K staged)
    dcn_kernel<<<dim3(BB*32), dim3(1024), 0, stream>>>(featT, off27, Wp, dcn16);
    // K3: GroupNorm partials (bf16 input)
    gn_partial_kernel<<<dim3(1024), dim3(256), 0, stream>>>(dcn16, partial);
    // K5: fused GN + residual + 1x1 convs + offset blend -> packed SO/UC
    fused_tail_kernel<<<dim3(512), dim3(512), 0, stream>>>(feat, dcn16, partial,
        gn_g, gn_b, Wc, so_b, sc_b, uw_b, uo_b, prev_off,
        out_feat, SO, UC);
    // K7: fused double grid-sample + softmax reduction (packed gathers)
    final_kernel<<<dim3(2176), dim3(256), 0, stream>>>(UC, SO, out_off);
}